// Round 18
// baseline (589.990 us; speedup 1.0000x reference)
//
#include <hip/hip_runtime.h>
#include <math.h>

#define NN 10000
#define NE 100000
#define NGR 64
#define NT 5
#define FD 75
#define FOUT 15
#define NLAY 4
#define MAXB 1792

typedef __bf16 bf16;
typedef __bf16 bf16x8 __attribute__((ext_vector_type(8)));
typedef float f32x4 __attribute__((ext_vector_type(4)));

__device__ inline unsigned pk2(float a, float b) {
  bf16 x = (bf16)a, y = (bf16)b;
  unsigned short ux, uy;
  __builtin_memcpy(&ux, &x, 2); __builtin_memcpy(&uy, &y, 2);
  return (unsigned)ux | ((unsigned)uy << 16);
}

// ---------------------------------------------------------------- small prep

__global__ __launch_bounds__(256) void k_node_emb(const float* __restrict__ x,
    const float* __restrict__ w, const float* __restrict__ b, bf16* __restrict__ hbf) {
  int idx = blockIdx.x * 256 + threadIdx.x;
  if (idx >= NN * FD) return;
  int n = idx / FD, f = idx - n * FD;
  float acc = b[f];
#pragma unroll
  for (int k = 0; k < 14; ++k) acc += x[n * 14 + k] * w[k * FD + f];
  hbf[n * 80 + f] = (bf16)acc;
}

__global__ __launch_bounds__(256) void k_hpad(bf16* __restrict__ hbf) {
  int idx = blockIdx.x * 256 + threadIdx.x;
  if (idx >= NN * 5) return;
  int n = idx / 5, f = 75 + idx % 5;
  hbf[n * 80 + f] = (bf16)0.f;
}

__global__ __launch_bounds__(256) void k_edge4(const float* __restrict__ eattr,
    bf16* __restrict__ eabf4) {
  int idx = blockIdx.x * 256 + threadIdx.x;
  if (idx >= NE * 8) return;
  int e = idx >> 3, c = idx & 7;
  eabf4[idx] = (c < 4) ? (bf16)eattr[e * 4 + c] : (bf16)0.f;
}

__global__ __launch_bounds__(256) void k_count(const int* __restrict__ dst, int* __restrict__ deg) {
  int e = blockIdx.x * 256 + threadIdx.x;
  if (e < NE) atomicAdd(&deg[dst[e]], 1);
}

__global__ __launch_bounds__(1024) void k_scan(const int* __restrict__ deg, int* __restrict__ rowptr) {
  __shared__ int buf[1024];
  __shared__ int carry;
  int tid = threadIdx.x;
  if (tid == 0) carry = 0;
  __syncthreads();
  for (int base = 0; base < NN; base += 1024) {
    int i = base + tid;
    int v = (i < NN) ? deg[i] : 0;
    buf[tid] = v;
    __syncthreads();
    for (int off = 1; off < 1024; off <<= 1) {
      int t = (tid >= off) ? buf[tid - off] : 0;
      __syncthreads();
      buf[tid] += t;
      __syncthreads();
    }
    int inc = buf[tid];
    int tot = buf[1023];
    if (i < NN) rowptr[i + 1] = carry + inc;
    __syncthreads();
    if (tid == 0) carry += tot;
    __syncthreads();
  }
  if (tid == 0) rowptr[0] = 0;
}

__global__ __launch_bounds__(256) void k_scl(const int* __restrict__ deg, float* __restrict__ scl,
                                             float* __restrict__ iscl, float inv_avg_log) {
  int n = blockIdx.x * 256 + threadIdx.x;
  if (n >= NN) return;
  float c1 = fmaxf((float)deg[n], 1.f);
  float s = logf(c1 + 1.f) * inv_avg_log;
  scl[n] = s;
  iscl[n] = 1.f / s;
}

__global__ __launch_bounds__(256) void k_scatter(const int* __restrict__ dst, const int* __restrict__ rowptr,
    int* __restrict__ cursor, int* __restrict__ eids) {
  int e = blockIdx.x * 256 + threadIdx.x;
  if (e >= NE) return;
  int d = dst[e];
  int pos = rowptr[d] + atomicAdd(&cursor[d], 1);
  eids[pos] = e;
}

__global__ __launch_bounds__(256) void k_next(const int* __restrict__ rowptr, int* __restrict__ nxt) {
  int n = blockIdx.x * 256 + threadIdx.x;
  if (n >= NN) return;
  int base = rowptr[n];
  int lo = n + 1, hi = min(n + 128, NN);
  while (lo < hi) {
    int mid = (lo + hi + 1) >> 1;
    if (rowptr[mid] - base <= 128) lo = mid; else hi = mid - 1;
  }
  nxt[n] = lo;
}

__global__ __launch_bounds__(1024) void k_walk(const int* __restrict__ nxt,
    int* __restrict__ bstart, int* __restrict__ nblk) {
  __shared__ int lnx[NN];
  int tid = threadIdx.x;
  for (int i = tid; i < NN; i += 1024) lnx[i] = nxt[i];
  __syncthreads();
  if (tid == 0) {
    int b = 0, n = 0;
    while (n < NN && b < MAXB) { bstart[b++] = n; n = lnx[n]; }
    bstart[b] = NN;
    nblk[0] = b;
  }
}

// ---------------------------------------------------------------- weight prep (batched across layers)

__global__ __launch_bounds__(256) void k_W12(const float* __restrict__ ew,
    const float* __restrict__ ebias, const float* __restrict__ ee_wA, const float* __restrict__ ee_bA,
    float* __restrict__ W12A, float* __restrict__ bcombA) {
  const int l = blockIdx.y;
  const float* ee_w = ee_wA + (size_t)l * 50 * FD;
  const float* ee_b = ee_bA + (size_t)l * FD;
  int idx = blockIdx.x * 256 + threadIdx.x;
  if (idx >= 375) return;
  if (idx < 300) {
    int d = idx / 75, o = idx - d * 75;
    float v = 0.f;
    for (int j = 0; j < 50; ++j) v += ew[d * 50 + j] * ee_w[j * 75 + o];
    W12A[(size_t)l * 300 + idx] = v;
  } else {
    int o = idx - 300;
    float v = ee_b[o];
    for (int j = 0; j < 50; ++j) v += ebias[j] * ee_w[j * 75 + o];
    bcombA[(size_t)l * 80 + o] = v;
  }
}

__global__ __launch_bounds__(256) void k_combine(const float* __restrict__ pre_wA,
    const float* __restrict__ pre_bA, const float* __restrict__ W12A, const float* __restrict__ bcombA,
    bf16* __restrict__ WctA, float* __restrict__ bcA) {
  const int l = blockIdx.y;
  const float* pre_w = pre_wA + (size_t)l * NT * 225 * FD;
  const float* pre_b = pre_bA + (size_t)l * NT * FD;
  const float* W12   = W12A + (size_t)l * 300;
  const float* bcomb = bcombA + (size_t)l * 80;
  bf16* Wct = WctA + (size_t)l * 384 * 192;
  float* bc = bcA + (size_t)l * 384;
  int idx = blockIdx.x * 256 + threadIdx.x;
  if (idx >= 384 * 192) return;
  int c = idx / 192, s = idx - c * 192;
  int t = c / 75, g = c - t * 75;
  int chunk = s >> 6, within = s & 63, sblk = within >> 3, elem = within & 7;
  int lb = sblk ^ (c & 7);
  int k = chunk * 64 + lb * 8 + elem;
  float v = 0.f;
  if (c < 375) {
    if (k < 75)                    v = pre_w[(t * 225 + k) * 75 + g];
    else if (k >= 80 && k < 155)   v = pre_w[(t * 225 + 75 + (k - 80)) * 75 + g];
    else if (k >= 160 && k < 164) {
      int d = k - 160;
      float a = 0.f;
      for (int f2 = 0; f2 < 75; ++f2) a += W12[d * 75 + f2] * pre_w[(t * 225 + 150 + f2) * 75 + g];
      v = a;
    }
  }
  Wct[c * 192 + s] = (bf16)v;
  if (s == 0) {
    float a = 0.f;
    if (c < 375) {
      a = pre_b[t * 75 + g];
      for (int f2 = 0; f2 < 75; ++f2) a += bcomb[f2] * pre_w[(t * 225 + 150 + f2) * 75 + g];
    }
    bc[c] = a;
  }
}

__global__ __launch_bounds__(256) void k_PL(const float* __restrict__ pwA,
    const float* __restrict__ lwA, float* __restrict__ PLA) {
  const int l = blockIdx.y;
  const float* pw = pwA + (size_t)l * NT * 975 * FOUT;
  const float* lw = lwA + (size_t)l * FD * FD;
  float* PL = PLA + (size_t)l * 5 * 975 * 80;
  int idx = blockIdx.x * 256 + threadIdx.x;
  if (idx >= 5 * 975 * 80) return;
  int t = idx / (975 * 80), rem = idx - t * 975 * 80;
  int row = rem / 80, o = rem - row * 80;
  float v = 0.f;
  if (o < 75) {
#pragma unroll
    for (int j = 0; j < 15; ++j)
      v += pw[((size_t)t * 975 + row) * 15 + j] * lw[(t * 15 + j) * 75 + o];
  }
  PL[idx] = v;
}

__global__ __launch_bounds__(256) void k_combine2b(const float* __restrict__ PLA,
    bf16* __restrict__ Wct2A) {
  const int l = blockIdx.y;
  const float* PL = PLA + (size_t)l * 5 * 975 * 80;
  bf16* Wct2 = Wct2A + (size_t)l * 256 * 1664;
  int idx = blockIdx.x * 256 + threadIdx.x;
  if (idx >= 256 * 1664) return;
  int c = idx / 1664, s = idx - c * 1664;
  int chunk = s >> 6, within = s & 63, sblk = within >> 3, elem = within & 7;
  int lb = sblk ^ (c & 7);
  int k = chunk * 64 + lb * 8 + elem;
  int g2 = c / 80, o = c - g2 * 80;
  float val = 0.f;
  if (c < 240 && o < 75) {
    if (k < 75) {
      if (g2 == 0) {
#pragma unroll
        for (int t = 0; t < 5; ++t) val += PL[(t * 975 + k) * 80 + o];
      }
    } else if (k >= 80 && k < 1616) {
      int q = k - 80;
      int si = q / 384, cc = q - si * 384;
      if (cc < 375) {
        int t = cc / 75, g = cc - t * 75;
        int row = 75 + g2 * 300 + si * 75 + g;
        val = PL[((size_t)t * 975 + row) * 80 + o];
      }
    }
  }
  Wct2[(size_t)c * 1664 + s] = (bf16)val;
}

__global__ __launch_bounds__(128) void k_zbias(const float* __restrict__ pbA,
    const float* __restrict__ lwA, const float* __restrict__ lbA, float* __restrict__ zbA) {
  const int l = blockIdx.y;
  const float* pb = pbA + (size_t)l * NT * FOUT;
  const float* lw = lwA + (size_t)l * FD * FD;
  const float* lb = lbA + (size_t)l * FD;
  float* zb = zbA + (size_t)l * 80;
  int o = threadIdx.x;
  if (o >= 80) return;
  float val = 0.f;
  if (o < 75) {
    val = lb[o];
    for (int t = 0; t < 5; ++t)
      for (int j = 0; j < 15; ++j)
        val += pb[t * 15 + j] * lw[(t * 15 + j) * 75 + o];
  }
  zb[o] = val;
}

// ---------------------------------------------------------------- fused pre-GEMM + aggregation
// A-operand DIRECT from global; B double-buffered in LDS. 6 barriers. K=192.

#define LOADB(ntb_, c_) do {                                                      \
    const bf16* wp_ = Wct + (size_t)((ntb_) + sr) * 192 + (c_) * 64 + slb * 8;    \
    pq0 = *(const uint4*)(wp_ + 0 * 6144);                                        \
    pq1 = *(const uint4*)(wp_ + 1 * 6144);                                        \
    pq2 = *(const uint4*)(wp_ + 2 * 6144);                                        \
    pq3 = *(const uint4*)(wp_ + 3 * 6144); } while (0)

#define STOREB(BS_) do {                                          \
    *(uint4*)((BS_) + (0 * 32 + sr) * 128 + (slb << 4)) = pq0;    \
    *(uint4*)((BS_) + (1 * 32 + sr) * 128 + (slb << 4)) = pq1;    \
    *(uint4*)((BS_) + (2 * 32 + sr) * 128 + (slb << 4)) = pq2;    \
    *(uint4*)((BS_) + (3 * 32 + sr) * 128 + (slb << 4)) = pq3; } while (0)

#define DO_KK(BS_, KB_, A0_, A1_, A2_, A3_) do {                         \
    bf16x8 af0 = *(const bf16x8*)(A0_);                                  \
    bf16x8 af1 = *(const bf16x8*)(A1_);                                  \
    bf16x8 af2 = *(const bf16x8*)(A2_);                                  \
    bf16x8 af3 = *(const bf16x8*)(A3_);                                  \
    const unsigned char* bp_ = (BS_) + (((KB_) ^ (l15 & 7)) << 4) + wc * 8192 + l15 * 128; \
    bf16x8 bv0 = *(const bf16x8*)(bp_ + 0 * 2048);                       \
    bf16x8 bv1 = *(const bf16x8*)(bp_ + 1 * 2048);                       \
    bf16x8 bv2 = *(const bf16x8*)(bp_ + 2 * 2048);                       \
    bf16x8 bv3 = *(const bf16x8*)(bp_ + 3 * 2048);                       \
    acc[0][0] = __builtin_amdgcn_mfma_f32_16x16x32_bf16(af0, bv0, acc[0][0], 0, 0, 0); \
    acc[1][0] = __builtin_amdgcn_mfma_f32_16x16x32_bf16(af1, bv0, acc[1][0], 0, 0, 0); \
    acc[2][0] = __builtin_amdgcn_mfma_f32_16x16x32_bf16(af2, bv0, acc[2][0], 0, 0, 0); \
    acc[3][0] = __builtin_amdgcn_mfma_f32_16x16x32_bf16(af3, bv0, acc[3][0], 0, 0, 0); \
    acc[0][1] = __builtin_amdgcn_mfma_f32_16x16x32_bf16(af0, bv1, acc[0][1], 0, 0, 0); \
    acc[1][1] = __builtin_amdgcn_mfma_f32_16x16x32_bf16(af1, bv1, acc[1][1], 0, 0, 0); \
    acc[2][1] = __builtin_amdgcn_mfma_f32_16x16x32_bf16(af2, bv1, acc[2][1], 0, 0, 0); \
    acc[3][1] = __builtin_amdgcn_mfma_f32_16x16x32_bf16(af3, bv1, acc[3][1], 0, 0, 0); \
    acc[0][2] = __builtin_amdgcn_mfma_f32_16x16x32_bf16(af0, bv2, acc[0][2], 0, 0, 0); \
    acc[1][2] = __builtin_amdgcn_mfma_f32_16x16x32_bf16(af1, bv2, acc[1][2], 0, 0, 0); \
    acc[2][2] = __builtin_amdgcn_mfma_f32_16x16x32_bf16(af2, bv2, acc[2][2], 0, 0, 0); \
    acc[3][2] = __builtin_amdgcn_mfma_f32_16x16x32_bf16(af3, bv2, acc[3][2], 0, 0, 0); \
    acc[0][3] = __builtin_amdgcn_mfma_f32_16x16x32_bf16(af0, bv3, acc[0][3], 0, 0, 0); \
    acc[1][3] = __builtin_amdgcn_mfma_f32_16x16x32_bf16(af1, bv3, acc[1][3], 0, 0, 0); \
    acc[2][3] = __builtin_amdgcn_mfma_f32_16x16x32_bf16(af2, bv3, acc[2][3], 0, 0, 0); \
    acc[3][3] = __builtin_amdgcn_mfma_f32_16x16x32_bf16(af3, bv3, acc[3][3], 0, 0, 0); \
  } while (0)

__global__ __launch_bounds__(256) void k_pre_fused(
    const bf16* __restrict__ hbf, const int* __restrict__ eids,
    const int* __restrict__ srcA, const int* __restrict__ dstA,
    const int* __restrict__ rowptr, const int* __restrict__ bstart, const int* __restrict__ nblk,
    const bf16* __restrict__ Wct, const float* __restrict__ bc,
    bf16* __restrict__ aggbf2, unsigned eoff_base) {
  __shared__ __align__(16) unsigned char smem[33792];   // Bs dbuf 32K; m_lds overlays
  unsigned char* Bs0 = smem;
  unsigned char* Bs1 = smem + 16384;
  bf16* m_lds = (bf16*)smem;                             // [128][132] bf16
  __shared__ unsigned dOffL[128], sOffL[128], eOffL[128];
  __shared__ int nodeRows[129];
  __shared__ int nq[5];

  const int b = blockIdx.x;
  if (b >= nblk[0]) return;
  const int ntb = blockIdx.y * 128;
  const int tid = threadIdx.x;
  const int n0b = bstart[b], n1b = bstart[b + 1];
  const int rbase = rowptr[n0b];
  const int nrows = rowptr[n1b] - rbase;     // <= 128
  const int nnod = n1b - n0b;                // <= 128

  if (tid == 0) { nq[0] = 0; nq[1] = 0; nq[2] = 0; nq[3] = 0; nq[4] = nnod; }
  if (tid < 128) {
    int e = (tid < nrows) ? eids[rbase + tid] : 0;
    dOffL[tid] = (unsigned)(dstA[e] * 160);
    sOffL[tid] = (unsigned)(srcA[e] * 160);
    eOffL[tid] = eoff_base + (unsigned)(e * 16);
  }
  if (tid <= nnod) nodeRows[tid] = rowptr[n0b + tid] - rbase;
  __syncthreads();
  if (tid < nnod) {
#pragma unroll
    for (int q = 1; q <= 3; ++q) {
      int target = (nrows * q) >> 2;
      if (nodeRows[tid] < target && nodeRows[tid + 1] >= target) nq[q] = tid + 1;
    }
  }

  const int lane = tid & 63;
  const int wave = tid >> 6;
  const int wr = wave >> 1, wc = wave & 1;
  const int l15 = lane & 15, l4 = lane >> 4;
  const int sr = tid >> 3, slb = tid & 7;

  const unsigned char* hb = (const unsigned char*)hbf;
  const int ar = wr * 64 + l15;
  const unsigned dof0 = dOffL[ar], dof1 = dOffL[ar + 16], dof2 = dOffL[ar + 32], dof3 = dOffL[ar + 48];
  const unsigned sof0 = sOffL[ar], sof1 = sOffL[ar + 16], sof2 = sOffL[ar + 32], sof3 = sOffL[ar + 48];
  const unsigned eof0 = eOffL[ar], eof1 = eOffL[ar + 16], eof2 = eOffL[ar + 32], eof3 = eOffL[ar + 48];

  f32x4 acc[4][4];
  f32x4 zv = {0.f, 0.f, 0.f, 0.f};
#pragma unroll
  for (int i = 0; i < 4; ++i)
#pragma unroll
    for (int j = 0; j < 4; ++j) acc[i][j] = zv;

  uint4 pq0, pq1, pq2, pq3;
  LOADB(ntb, 0);

  // ---- chunk 0: A = dst elems [0,64)
  STOREB(Bs0);
  __syncthreads();
  LOADB(ntb, 1);
  DO_KK(Bs0, l4,     hb + dof0 + l4 * 16, hb + dof1 + l4 * 16, hb + dof2 + l4 * 16, hb + dof3 + l4 * 16);
  DO_KK(Bs0, 4 + l4, hb + dof0 + 64 + l4 * 16, hb + dof1 + 64 + l4 * 16, hb + dof2 + 64 + l4 * 16, hb + dof3 + 64 + l4 * 16);

  // ---- chunk 1: A = dst tail [64,80) | src [0,48)
  STOREB(Bs1);
  __syncthreads();
  LOADB(ntb, 2);
  {
    unsigned o0 = (l4 < 2) ? (dof0 + 128 + l4 * 16) : (sof0 + (l4 - 2) * 16);
    unsigned o1 = (l4 < 2) ? (dof1 + 128 + l4 * 16) : (sof1 + (l4 - 2) * 16);
    unsigned o2 = (l4 < 2) ? (dof2 + 128 + l4 * 16) : (sof2 + (l4 - 2) * 16);
    unsigned o3 = (l4 < 2) ? (dof3 + 128 + l4 * 16) : (sof3 + (l4 - 2) * 16);
    DO_KK(Bs1, l4, hb + o0, hb + o1, hb + o2, hb + o3);
  }
  DO_KK(Bs1, 4 + l4, hb + sof0 + 32 + l4 * 16, hb + sof1 + 32 + l4 * 16, hb + sof2 + 32 + l4 * 16, hb + sof3 + 32 + l4 * 16);

  // ---- chunk 2: A = src tail [48,80) | eattr4
  STOREB(Bs0);
  __syncthreads();
  DO_KK(Bs0, l4, hb + sof0 + 96 + l4 * 16, hb + sof1 + 96 + l4 * 16, hb + sof2 + 96 + l4 * 16, hb + sof3 + 96 + l4 * 16);
  DO_KK(Bs0, 4 + l4, hb + eof0 + l4 * 16, hb + eof1 + l4 * 16, hb + eof2 + l4 * 16, hb + eof3 + l4 * 16);
  __syncthreads();

  // bias + write tile into the overlay
  float bcv[4];
#pragma unroll
  for (int j = 0; j < 4; ++j) bcv[j] = bc[ntb + wc * 64 + j * 16 + l15];
#pragma unroll
  for (int i = 0; i < 4; ++i) {
    int R = wr * 64 + i * 16 + l4 * 4;
#pragma unroll
    for (int j = 0; j < 4; ++j) {
      int col = wc * 64 + j * 16 + l15;
#pragma unroll
      for (int q = 0; q < 4; ++q)
        m_lds[(R + q) * 132 + col] = (bf16)(acc[i][j][q] + bcv[j]);
    }
  }
  __syncthreads();

  // aggregate: thread = (col-pair 0..63, row-quartile 0..3); u32 reads = 2 bf16 cols
  {
    const int cp = tid & 63;
    const int qq = tid >> 6;
    const unsigned char* mb = (const unsigned char*)m_lds;
    for (int i = nq[qq]; i < nq[qq + 1]; ++i) {
      int ra = nodeRows[i], rb2 = nodeRows[i + 1];
      float s0 = 0.f, q0 = 0.f, a0 = INFINITY, b0 = -INFINITY;
      float s1 = 0.f, q1 = 0.f, a1 = INFINITY, b1 = -INFINITY;
      for (int r = ra; r < rb2; ++r) {
        unsigned u = *(const unsigned*)(mb + r * 264 + cp * 4);
        float v0 = __uint_as_float(u << 16);
        float v1 = __uint_as_float(u & 0xffff0000u);
        s0 += v0; q0 += v0 * v0; a0 = fminf(a0, v0); b0 = fmaxf(b0, v0);
        s1 += v1; q1 += v1 * v1; a1 = fminf(a1, v1); b1 = fmaxf(b1, v1);
      }
      int d = rb2 - ra;
      float inv = 1.f / ((d > 0) ? (float)d : 1.f);
      float m0 = s0 * inv, m1 = s1 * inv;
      float sd0 = sqrtf(fmaxf(q0 * inv - m0 * m0, 0.f) + 1e-5f);
      float sd1 = sqrtf(fmaxf(q1 * inv - m1 * m1, 0.f) + 1e-5f);
      if (d == 0) { a0 = 0.f; b0 = 0.f; a1 = 0.f; b1 = 0.f; }
      bf16* ag = aggbf2 + (size_t)(n0b + i) * 1536 + ntb + cp * 2;
      *(unsigned*)(ag)        = pk2(m0, m1);
      *(unsigned*)(ag + 384)  = pk2(a0, a1);
      *(unsigned*)(ag + 768)  = pk2(b0, b1);
      *(unsigned*)(ag + 1152) = pk2(sd0, sd1);
    }
  }
}

// ---------------------------------------------------------------- post GEMM + epilogue + BN stats
// v2: A-direct from global (logical row = [hbf(80)|aggbf2(1536)|pad]), 64-row tiles.
// grid (157, 2). B single-buffered with named-reg prefetch. 26 barriers per 64 rows.

#define LOADPB(c_) do {                                                 \
    int ko_ = (c_) * 128 + slb * 8;                                     \
    pb0 = *(const uint4*)(pc0 + ko_);                                   \
    pb1 = *(const uint4*)(pc0 + ko_ + 64);                              \
    pb2 = *(const uint4*)(pc1 + ko_);                                   \
    pb3 = *(const uint4*)(pc1 + ko_ + 64);                              \
    pb4 = *(const uint4*)(pc2 + ko_);                                   \
    pb5 = *(const uint4*)(pc2 + ko_ + 64);                              \
    pb6 = *(const uint4*)(pc3 + ko_);                                   \
    pb7 = *(const uint4*)(pc3 + ko_ + 64);                              \
  } while (0)

#define PAPTR(hb_, ab_, ok_, off_) ((ok_) ? ((off_) < 80 ? (hb_) + (off_) : \
    ((off_) < 1616 ? (ab_) + (off_) : zerobuf)) : zerobuf)

__global__ __launch_bounds__(256) void k_post4(const bf16* __restrict__ hbf,
    const bf16* __restrict__ aggbf2, const bf16* __restrict__ Wct2,
    const float* __restrict__ zb, const float* __restrict__ scl, const float* __restrict__ iscl,
    const bf16* __restrict__ zerobuf, float* __restrict__ z, float* __restrict__ stat_raw_l) {
  __shared__ __align__(16) unsigned char smem[33792];   // Bs 32K; Ps [64][132]f32 overlays
  unsigned char* Bs = smem;
  float* Ps = (float*)smem;
  __shared__ float sclS[64], isclS[64];
  const int n0 = blockIdx.x * 64;
  const int y  = blockIdx.y;
  const int tid = threadIdx.x;
  const int lane = tid & 63, wave = tid >> 6;
  const int l15 = lane & 15, l4 = lane >> 4;
  const int sr = tid >> 3, slb = tid & 7;

  const bf16 *pc0, *pc1, *pc2, *pc3;
  {
    int c0 = sr, c1 = sr + 32, c2 = sr + 64, c3 = sr + 96;
    int l0 = (c0 / 40) * 80 + y * 40 + (c0 % 40);
    int l1 = (c1 / 40) * 80 + y * 40 + (c1 % 40);
    int l2 = (c2 / 40) * 80 + y * 40 + (c2 % 40);
    int l3 = (c3 < 120) ? ((c3 / 40) * 80 + y * 40 + (c3 % 40)) : 0;
    pc0 = Wct2 + (size_t)l0 * 1664;
    pc1 = Wct2 + (size_t)l1 * 1664;
    pc2 = Wct2 + (size_t)l2 * 1664;
    pc3 = Wct2 + (size_t)l3 * 1664;
  }
  if (tid < 64) {
    int n = n0 + tid;
    sclS[tid] = (n < NN) ? scl[n] : 0.f;
    isclS[tid] = (n < NN) ? iscl[n] : 0.f;
  }

  // A-direct per-lane row bases: rows i*16+l15, i=0..3
  const int na0 = n0 + 0 * 16 + l15, na1 = n0 + 1 * 16 + l15;
  const int na2 = n0 + 2 * 16 + l15, na3 = n0 + 3 * 16 + l15;
  const bool ok0 = na0 < NN, ok1 = na1 < NN, ok2 = na2 < NN, ok3 = na3 < NN;
  const bf16* hb0 = hbf + na0 * 80;
  const bf16* hb1 = hbf + na1 * 80;
  const bf16* hb2 = hbf + na2 * 80;
  const bf16* hb3 = hbf + na3 * 80;
  const bf16* ab0 = aggbf2 + (size_t)na0 * 1536 - 80;
  const bf16* ab1 = aggbf2 + (size_t)na1 * 1536 - 80;
  const bf16* ab2 = aggbf2 + (size_t)na2 * 1536 - 80;
  const bf16* ab3 = aggbf2 + (size_t)na3 * 1536 - 80;

  f32x4 acc[4][2];
  f32x4 zvv = {0.f, 0.f, 0.f, 0.f};
#pragma unroll
  for (int i = 0; i < 4; ++i)
#pragma unroll
    for (int j = 0; j < 2; ++j) acc[i][j] = zvv;

  uint4 pb0, pb1, pb2, pb3, pb4, pb5, pb6, pb7;
  LOADPB(0);
  for (int c = 0; c < 13; ++c) {
    *(uint4*)(Bs + (sr)      * 256 + (slb << 4)) = pb0;
    *(uint4*)(Bs + (sr)      * 256 + (slb << 4) + 128) = pb1;
    *(uint4*)(Bs + (sr + 32) * 256 + (slb << 4)) = pb2;
    *(uint4*)(Bs + (sr + 32) * 256 + (slb << 4) + 128) = pb3;
    *(uint4*)(Bs + (sr + 64) * 256 + (slb << 4)) = pb4;
    *(uint4*)(Bs + (sr + 64) * 256 + (slb << 4) + 128) = pb5;
    *(uint4*)(Bs + (sr + 96) * 256 + (slb << 4)) = pb6;
    *(uint4*)(Bs + (sr + 96) * 256 + (slb << 4) + 128) = pb7;
    __syncthreads();
    if (c < 12) LOADPB(c + 1);
#pragma unroll
    for (int kk = 0; kk < 4; ++kk) {
      int kb = kk * 4 + l4;
      int off = c * 128 + kb * 8;
      bf16x8 af0 = *(const bf16x8*)PAPTR(hb0, ab0, ok0, off);
      bf16x8 af1 = *(const bf16x8*)PAPTR(hb1, ab1, ok1, off);
      bf16x8 af2 = *(const bf16x8*)PAPTR(hb2, ab2, ok2, off);
      bf16x8 af3 = *(const bf16x8*)PAPTR(hb3, ab3, ok3, off);
      bf16x8 bv0, bv1;
      {
        int cidx0 = wave * 32 + l15;
        int cidx1 = wave * 32 + 16 + l15;
        bv0 = *(const bf16x8*)(Bs + cidx0 * 256 + (((kb & 8) | ((kb & 7) ^ (cidx0 & 7))) << 4));
        bv1 = *(const bf16x8*)(Bs + cidx1 * 256 + (((kb & 8) | ((kb & 7) ^ (cidx1 & 7))) << 4));
      }
      acc[0][0] = __builtin_amdgcn_mfma_f32_16x16x32_bf16(af0, bv0, acc[0][0], 0, 0, 0);
      acc[1][0] = __builtin_amdgcn_mfma_f32_16x16x32_bf16(af1, bv0, acc[1][0], 0, 0, 0);
      acc[2][0] = __builtin_amdgcn_mfma_f32_16x16x32_bf16(af2, bv0, acc[2][0], 0, 0, 0);
      acc[3][0] = __builtin_amdgcn_mfma_f32_16x16x32_bf16(af3, bv0, acc[3][0], 0, 0, 0);
      acc[0][1] = __builtin_amdgcn_mfma_f32_16x16x32_bf16(af0, bv1, acc[0][1], 0, 0, 0);
      acc[1][1] = __builtin_amdgcn_mfma_f32_16x16x32_bf16(af1, bv1, acc[1][1], 0, 0, 0);
      acc[2][1] = __builtin_amdgcn_mfma_f32_16x16x32_bf16(af2, bv1, acc[2][1], 0, 0, 0);
      acc[3][1] = __builtin_amdgcn_mfma_f32_16x16x32_bf16(af3, bv1, acc[3][1], 0, 0, 0);
    }
    __syncthreads();
  }

  // P -> Ps overlay (Bs dead)
#pragma unroll
  for (int i = 0; i < 4; ++i) {
#pragma unroll
    for (int j = 0; j < 2; ++j) {
      int cidx = wave * 32 + j * 16 + l15;
#pragma unroll
      for (int q = 0; q < 4; ++q)
        Ps[(i * 16 + l4 * 4 + q) * 132 + cidx] = acc[i][j][q];
    }
  }
  __syncthreads();

  // epilogue: 64 rows x 40 f = 2560 = 10 per thread (static unroll -> registers)
  float vv[10];
  int rrA[10], ffA[10];
#pragma unroll
  for (int t = 0; t < 10; ++t) {
    int idx = tid + t * 256;
    int rr = idx / 40, ff = idx - rr * 40;
    rrA[t] = rr; ffA[t] = ff;
    int n_ = n0 + rr, zc = y * 40 + ff;
    float v = 0.f;
    if (n_ < NN && zc < 75) {
      v = Ps[rr * 132 + ff] + sclS[rr] * Ps[rr * 132 + 40 + ff]
        + isclS[rr] * Ps[rr * 132 + 80 + ff] + zb[zc];
      z[n_ * 75 + zc] = v;
    }
    vv[t] = v;
  }
  __syncthreads();
#pragma unroll
  for (int t = 0; t < 10; ++t) Ps[rrA[t] * 132 + ffA[t]] = vv[t];
  __syncthreads();
  if (tid < 40) {
    int zc = y * 40 + tid;
    if (zc < 75) {
      float s = 0.f, s2 = 0.f;
#pragma unroll
      for (int r = 0; r < 64; ++r) {
        float v = Ps[r * 132 + tid];
        s += v; s2 += v * v;
      }
      atomicAdd(&stat_raw_l[zc], s);
      atomicAdd(&stat_raw_l[75 + zc], s2);
    }
  }
}

// bnapply; on last layer (outF != null) also fused global_add_pool via atomics
__global__ __launch_bounds__(256) void k_bnapply(const float* __restrict__ z,
    const float* __restrict__ stat_raw, const float* __restrict__ g, const float* __restrict__ b,
    float* __restrict__ outF, bf16* __restrict__ hbf,
    const int* __restrict__ batch, float* __restrict__ gpool) {
  int idx = blockIdx.x * 256 + threadIdx.x;
  if (idx >= NN * FD) return;
  int n = idx / FD, f = idx - n * FD;
  float mu = stat_raw[f] * (1.f / NN);
  float var = stat_raw[75 + f] * (1.f / NN) - mu * mu;
  var = fmaxf(var, 0.f);
  float rs = 1.f / sqrtf(var + 1e-5f);
  float v = (z[idx] - mu) * rs * g[f] + b[f];
  v = fmaxf(v, 0.f);
  if (outF) {
    outF[idx] = v;
    atomicAdd(&gpool[batch[n] * FD + f], v);
  }
  hbf[n * 80 + f] = (bf16)v;
}

// parallel MLP head: one block per graph, 128 threads
__global__ __launch_bounds__(128) void k_mlp2(const float* __restrict__ gpool,
    const float* __restrict__ w1, const float* __restrict__ b1,
    const float* __restrict__ w2, const float* __restrict__ b2,
    const float* __restrict__ w3, const float* __restrict__ b3,
    float* __restrict__ out) {
  __shared__ float G[75];
  __shared__ float H1[50];
  __shared__ float H2[25];
  const int gr = blockIdx.x;
  const int tid = threadIdx.x;
  if (tid < 75) G[tid] = gpool[gr * FD + tid];
  __syncthreads();
  if (tid < 50) {
    float a = b1[tid];
    for (int k = 0; k < 75; ++k) a += G[k] * w1[k * 50 + tid];
    H1[tid] = fmaxf(a, 0.f);
  }
  __syncthreads();
  if (tid < 25) {
    float a = b2[tid];
    for (int k = 0; k < 50; ++k) a += H1[k] * w2[k * 25 + tid];
    H2[tid] = fmaxf(a, 0.f);
  }
  __syncthreads();
  if (tid == 0) {
    float a = b3[0];
    for (int k = 0; k < 25; ++k) a += H2[k] * w3[k];
    out[gr] = a;
  }
}

// ---------------------------------------------------------------- host

extern "C" void kernel_launch(void* const* d_in, const int* in_sizes, int n_in,
                              void* d_out, int out_size, void* d_ws, size_t ws_size,
                              hipStream_t stream) {
  (void)in_sizes; (void)n_in; (void)out_size; (void)ws_size;
  const float* x      = (const float*)d_in[0];
  const int*   eidx   = (const int*)  d_in[1];
  const float* eattr  = (const float*)d_in[2];
  const int*   batch  = (const int*)  d_in[3];
  const float* nw     = (const float*)d_in[4];
  const float* nb     = (const float*)d_in[5];
  const float* ew     = (const float*)d_in[6];
  const float* ebias  = (const float*)d_in[7];
  const float* ee_w   = (const float*)d_in[8];
  const float* ee_b   = (const float*)d_in[9];
  const float* pre_w  = (const float*)d_in[10];
  const float* pre_b  = (const float*)d_in[11];
  const float* post_w = (const float*)d_in[12];
  const float* post_b = (const float*)d_in[13];
  const float* lin_w  = (const float*)d_in[14];
  const float* lin_b  = (const float*)d_in[15];
  const float* bn_g   = (const float*)d_in[16];
  const float* bn_b   = (const float*)d_in[17];
  const float* w1 = (const float*)d_in[18];
  const float* b1 = (const float*)d_in[19];
  const float* w2 = (const float*)d_in[20];
  const float* b2 = (const float*)d_in[21];
  const float* w3 = (const float*)d_in[22];
  const float* b3 = (const float*)d_in[23];

  const int* srcA = eidx;
  const int* dstA = eidx + NE;

  char* base = (char*)d_ws;
  size_t off = 0;
  auto alloc = [&](size_t bytes) -> char* {
    char* p = base + off;
    off = (off + bytes + 255) & ~(size_t)255;
    return p;
  };
  bf16*  hbf    = (bf16*) alloc((size_t)NN * 80 * 2);
  bf16*  eabf4  = (bf16*) alloc((size_t)NE * 8 * 2 + 64);
  bf16*  aggbf2 = (bf16*) alloc((size_t)NN * 1536 * 2);
  float* z      = (float*)alloc((size_t)NN * FD * 4);
  bf16*  WctA   = (bf16*) alloc((size_t)NLAY * 384 * 192 * 2);
  float* bcA    = (float*)alloc((size_t)NLAY * 384 * 4);
  bf16*  Wct2A  = (bf16*) alloc((size_t)NLAY * 256 * 1664 * 2);
  float* zbA    = (float*)alloc((size_t)NLAY * 80 * 4);
  float* PLA    = (float*)alloc((size_t)NLAY * 5 * 975 * 80 * 4);
  float* W12A   = (float*)alloc((size_t)NLAY * 300 * 4);
  float* bcombA = (float*)alloc((size_t)NLAY * 80 * 4);
  float* scl    = (float*)alloc(NN * 4);
  float* iscl   = (float*)alloc(NN * 4);
  int*   deg    = (int*)alloc(NN * 4);
  int*   rowptr = (int*)alloc((NN + 1) * 4);
  int*   cursor = (int*)alloc(NN * 4);
  int*   eids   = (int*)alloc(NE * 4);
  int*   nxt    = (int*)alloc(NN * 4);
  int*   bstart = (int*)alloc((MAXB + 1) * 4);
  int*   nblk   = (int*)alloc(16);
  float* stat_all = (float*)alloc((size_t)NLAY * 160 * 4);
  float* gpool  = (float*)alloc(NGR * FD * 4);
  bf16*  zerobuf = (bf16*)alloc(256);

  const unsigned eoff_base = (unsigned)((char*)eabf4 - (char*)hbf);

  static const int DEG_TAB[71] = {1, 72, 201, 816, 1790, 3756, 6923, 12768, 20286, 31710,
    51623, 82296, 124280, 177576, 251115, 326064, 395760, 456840, 506179, 516200, 507003,
    493746, 489256, 453936, 420025, 411320, 427761, 420700, 420500, 426780, 414284, 407008,
    394053, 360910, 322245, 313704, 282902, 270940, 237783, 209000, 193766, 177870, 162110,
    144848, 121230, 112700, 93483, 88512, 72275, 80700, 68799, 56784, 42665, 30996, 25630,
    12936, 9804, 8584, 5251, 3480, 3111, 2728, 1890, 1472, 1235, 330, 201, 68, 69, 0, 71};
  double num = 0.0, den = 0.0;
  for (int i = 0; i < 71; ++i) { num += log((double)i + 1.0) * DEG_TAB[i]; den += DEG_TAB[i]; }
  float inv_avg_log = (float)(den / num);

  hipMemsetAsync(deg, 0, NN * 4, stream);
  hipMemsetAsync(cursor, 0, NN * 4, stream);
  hipMemsetAsync(gpool, 0, NGR * FD * 4, stream);
  hipMemsetAsync(stat_all, 0, (size_t)NLAY * 160 * 4, stream);
  hipMemsetAsync(zerobuf, 0, 256, stream);

  // graph prep
  k_node_emb<<<(NN * FD + 255) / 256, 256, 0, stream>>>(x, nw, nb, hbf);
  k_hpad<<<(NN * 5 + 255) / 256, 256, 0, stream>>>(hbf);
  k_edge4<<<(NE * 8 + 255) / 256, 256, 0, stream>>>(eattr, eabf4);
  k_count<<<(NE + 255) / 256, 256, 0, stream>>>(dstA, deg);
  k_scan<<<1, 1024, 0, stream>>>(deg, rowptr);
  k_scl<<<(NN + 255) / 256, 256, 0, stream>>>(deg, scl, iscl, inv_avg_log);
  k_scatter<<<(NE + 255) / 256, 256, 0, stream>>>(dstA, rowptr, cursor, eids);
  k_next<<<(NN + 255) / 256, 256, 0, stream>>>(rowptr, nxt);
  k_walk<<<1, 1024, 0, stream>>>(nxt, bstart, nblk);

  // weight prep, all layers batched
  {
    dim3 gw(2, NLAY);
    k_W12<<<gw, 256, 0, stream>>>(ew, ebias, ee_w, ee_b, W12A, bcombA);
    dim3 gc((384 * 192 + 255) / 256, NLAY);
    k_combine<<<gc, 256, 0, stream>>>(pre_w, pre_b, W12A, bcombA, WctA, bcA);
    dim3 gp((5 * 975 * 80 + 255) / 256, NLAY);
    k_PL<<<gp, 256, 0, stream>>>(post_w, lin_w, PLA);
    dim3 g2((256 * 1664 + 255) / 256, NLAY);
    k_combine2b<<<g2, 256, 0, stream>>>(PLA, Wct2A);
    dim3 gz(1, NLAY);
    k_zbias<<<gz, 128, 0, stream>>>(post_b, lin_w, lin_b, zbA);
  }

  float* outp = (float*)d_out;
  for (int l = 0; l < NLAY; ++l) {
    dim3 gpref(MAXB, 3);
    k_pre_fused<<<gpref, 256, 0, stream>>>(hbf, eids, srcA, dstA, rowptr, bstart, nblk,
        WctA + (size_t)l * 384 * 192, bcA + (size_t)l * 384, aggbf2, eoff_base);
    dim3 gpost((NN + 63) / 64, 2);
    k_post4<<<gpost, 256, 0, stream>>>(hbf, aggbf2, Wct2A + (size_t)l * 256 * 1664,
        zbA + (size_t)l * 80, scl, iscl, zerobuf, z, stat_all + (size_t)l * 160);
    float* wdst = (l == NLAY - 1) ? (outp + NGR) : nullptr;
    k_bnapply<<<(NN * FD + 255) / 256, 256, 0, stream>>>(z, stat_all + (size_t)l * 160,
        bn_g + (size_t)l * FD, bn_b + (size_t)l * FD, wdst, hbf, batch, gpool);
  }

  k_mlp2<<<NGR, 128, 0, stream>>>(gpool, w1, b1, w2, b2, w3, b3, outp);
}

// Round 19
// 567.585 us; speedup vs baseline: 1.0395x; 1.0395x over previous
//
#include <hip/hip_runtime.h>
#include <math.h>

#define NN 10000
#define NE 100000
#define NGR 64
#define NT 5
#define FD 75
#define FOUT 15
#define NLAY 4
#define MAXB 1792

typedef __bf16 bf16;
typedef __bf16 bf16x8 __attribute__((ext_vector_type(8)));
typedef float f32x4 __attribute__((ext_vector_type(4)));

__device__ inline unsigned pk2(float a, float b) {
  bf16 x = (bf16)a, y = (bf16)b;
  unsigned short ux, uy;
  __builtin_memcpy(&ux, &x, 2); __builtin_memcpy(&uy, &y, 2);
  return (unsigned)ux | ((unsigned)uy << 16);
}

// ---------------------------------------------------------------- small prep

__global__ __launch_bounds__(256) void k_node_emb(const float* __restrict__ x,
    const float* __restrict__ w, const float* __restrict__ b, bf16* __restrict__ hbf) {
  int idx = blockIdx.x * 256 + threadIdx.x;
  if (idx >= NN * FD) return;
  int n = idx / FD, f = idx - n * FD;
  float acc = b[f];
#pragma unroll
  for (int k = 0; k < 14; ++k) acc += x[n * 14 + k] * w[k * FD + f];
  hbf[n * 80 + f] = (bf16)acc;
}

__global__ __launch_bounds__(256) void k_hpad(bf16* __restrict__ hbf) {
  int idx = blockIdx.x * 256 + threadIdx.x;
  if (idx >= NN * 5) return;
  int n = idx / 5, f = 75 + idx % 5;
  hbf[n * 80 + f] = (bf16)0.f;
}

__global__ __launch_bounds__(256) void k_edge4(const float* __restrict__ eattr,
    bf16* __restrict__ eabf4) {
  int idx = blockIdx.x * 256 + threadIdx.x;
  if (idx >= NE * 8) return;
  int e = idx >> 3, c = idx & 7;
  eabf4[idx] = (c < 4) ? (bf16)eattr[e * 4 + c] : (bf16)0.f;
}

__global__ __launch_bounds__(256) void k_count(const int* __restrict__ dst, int* __restrict__ deg) {
  int e = blockIdx.x * 256 + threadIdx.x;
  if (e < NE) atomicAdd(&deg[dst[e]], 1);
}

__global__ __launch_bounds__(1024) void k_scan(const int* __restrict__ deg, int* __restrict__ rowptr) {
  __shared__ int buf[1024];
  __shared__ int carry;
  int tid = threadIdx.x;
  if (tid == 0) carry = 0;
  __syncthreads();
  for (int base = 0; base < NN; base += 1024) {
    int i = base + tid;
    int v = (i < NN) ? deg[i] : 0;
    buf[tid] = v;
    __syncthreads();
    for (int off = 1; off < 1024; off <<= 1) {
      int t = (tid >= off) ? buf[tid - off] : 0;
      __syncthreads();
      buf[tid] += t;
      __syncthreads();
    }
    int inc = buf[tid];
    int tot = buf[1023];
    if (i < NN) rowptr[i + 1] = carry + inc;
    __syncthreads();
    if (tid == 0) carry += tot;
    __syncthreads();
  }
  if (tid == 0) rowptr[0] = 0;
}

__global__ __launch_bounds__(256) void k_scl(const int* __restrict__ deg, float* __restrict__ scl,
                                             float* __restrict__ iscl, float inv_avg_log) {
  int n = blockIdx.x * 256 + threadIdx.x;
  if (n >= NN) return;
  float c1 = fmaxf((float)deg[n], 1.f);
  float s = logf(c1 + 1.f) * inv_avg_log;
  scl[n] = s;
  iscl[n] = 1.f / s;
}

__global__ __launch_bounds__(256) void k_scatter(const int* __restrict__ dst, const int* __restrict__ rowptr,
    int* __restrict__ cursor, int* __restrict__ eids) {
  int e = blockIdx.x * 256 + threadIdx.x;
  if (e >= NE) return;
  int d = dst[e];
  int pos = rowptr[d] + atomicAdd(&cursor[d], 1);
  eids[pos] = e;
}

__global__ __launch_bounds__(256) void k_next(const int* __restrict__ rowptr, int* __restrict__ nxt) {
  int n = blockIdx.x * 256 + threadIdx.x;
  if (n >= NN) return;
  int base = rowptr[n];
  int lo = n + 1, hi = min(n + 128, NN);
  while (lo < hi) {
    int mid = (lo + hi + 1) >> 1;
    if (rowptr[mid] - base <= 128) lo = mid; else hi = mid - 1;
  }
  nxt[n] = lo;
}

__global__ __launch_bounds__(1024) void k_walk(const int* __restrict__ nxt,
    int* __restrict__ bstart, int* __restrict__ nblk) {
  __shared__ int lnx[NN];
  int tid = threadIdx.x;
  for (int i = tid; i < NN; i += 1024) lnx[i] = nxt[i];
  __syncthreads();
  if (tid == 0) {
    int b = 0, n = 0;
    while (n < NN && b < MAXB) { bstart[b++] = n; n = lnx[n]; }
    bstart[b] = NN;
    nblk[0] = b;
  }
}

// ---------------------------------------------------------------- weight prep (batched across layers)

__global__ __launch_bounds__(256) void k_W12(const float* __restrict__ ew,
    const float* __restrict__ ebias, const float* __restrict__ ee_wA, const float* __restrict__ ee_bA,
    float* __restrict__ W12A, float* __restrict__ bcombA) {
  const int l = blockIdx.y;
  const float* ee_w = ee_wA + (size_t)l * 50 * FD;
  const float* ee_b = ee_bA + (size_t)l * FD;
  int idx = blockIdx.x * 256 + threadIdx.x;
  if (idx >= 375) return;
  if (idx < 300) {
    int d = idx / 75, o = idx - d * 75;
    float v = 0.f;
    for (int j = 0; j < 50; ++j) v += ew[d * 50 + j] * ee_w[j * 75 + o];
    W12A[(size_t)l * 300 + idx] = v;
  } else {
    int o = idx - 300;
    float v = ee_b[o];
    for (int j = 0; j < 50; ++j) v += ebias[j] * ee_w[j * 75 + o];
    bcombA[(size_t)l * 80 + o] = v;
  }
}

__global__ __launch_bounds__(256) void k_combine(const float* __restrict__ pre_wA,
    const float* __restrict__ pre_bA, const float* __restrict__ W12A, const float* __restrict__ bcombA,
    bf16* __restrict__ WctA, float* __restrict__ bcA) {
  const int l = blockIdx.y;
  const float* pre_w = pre_wA + (size_t)l * NT * 225 * FD;
  const float* pre_b = pre_bA + (size_t)l * NT * FD;
  const float* W12   = W12A + (size_t)l * 300;
  const float* bcomb = bcombA + (size_t)l * 80;
  bf16* Wct = WctA + (size_t)l * 384 * 192;
  float* bc = bcA + (size_t)l * 384;
  int idx = blockIdx.x * 256 + threadIdx.x;
  if (idx >= 384 * 192) return;
  int c = idx / 192, s = idx - c * 192;
  int t = c / 75, g = c - t * 75;
  int chunk = s >> 6, within = s & 63, sblk = within >> 3, elem = within & 7;
  int lb = sblk ^ (c & 7);
  int k = chunk * 64 + lb * 8 + elem;
  float v = 0.f;
  if (c < 375) {
    if (k < 75)                    v = pre_w[(t * 225 + k) * 75 + g];
    else if (k >= 80 && k < 155)   v = pre_w[(t * 225 + 75 + (k - 80)) * 75 + g];
    else if (k >= 160 && k < 164) {
      int d = k - 160;
      float a = 0.f;
      for (int f2 = 0; f2 < 75; ++f2) a += W12[d * 75 + f2] * pre_w[(t * 225 + 150 + f2) * 75 + g];
      v = a;
    }
  }
  Wct[c * 192 + s] = (bf16)v;
  if (s == 0) {
    float a = 0.f;
    if (c < 375) {
      a = pre_b[t * 75 + g];
      for (int f2 = 0; f2 < 75; ++f2) a += bcomb[f2] * pre_w[(t * 225 + 150 + f2) * 75 + g];
    }
    bc[c] = a;
  }
}

__global__ __launch_bounds__(256) void k_PL(const float* __restrict__ pwA,
    const float* __restrict__ lwA, float* __restrict__ PLA) {
  const int l = blockIdx.y;
  const float* pw = pwA + (size_t)l * NT * 975 * FOUT;
  const float* lw = lwA + (size_t)l * FD * FD;
  float* PL = PLA + (size_t)l * 5 * 975 * 80;
  int idx = blockIdx.x * 256 + threadIdx.x;
  if (idx >= 5 * 975 * 80) return;
  int t = idx / (975 * 80), rem = idx - t * 975 * 80;
  int row = rem / 80, o = rem - row * 80;
  float v = 0.f;
  if (o < 75) {
#pragma unroll
    for (int j = 0; j < 15; ++j)
      v += pw[((size_t)t * 975 + row) * 15 + j] * lw[(t * 15 + j) * 75 + o];
  }
  PL[idx] = v;
}

__global__ __launch_bounds__(256) void k_combine2b(const float* __restrict__ PLA,
    bf16* __restrict__ Wct2A) {
  const int l = blockIdx.y;
  const float* PL = PLA + (size_t)l * 5 * 975 * 80;
  bf16* Wct2 = Wct2A + (size_t)l * 256 * 1664;
  int idx = blockIdx.x * 256 + threadIdx.x;
  if (idx >= 256 * 1664) return;
  int c = idx / 1664, s = idx - c * 1664;
  int chunk = s >> 6, within = s & 63, sblk = within >> 3, elem = within & 7;
  int lb = sblk ^ (c & 7);
  int k = chunk * 64 + lb * 8 + elem;
  int g2 = c / 80, o = c - g2 * 80;
  float val = 0.f;
  if (c < 240 && o < 75) {
    if (k < 75) {
      if (g2 == 0) {
#pragma unroll
        for (int t = 0; t < 5; ++t) val += PL[(t * 975 + k) * 80 + o];
      }
    } else if (k >= 80 && k < 1616) {
      int q = k - 80;
      int si = q / 384, cc = q - si * 384;
      if (cc < 375) {
        int t = cc / 75, g = cc - t * 75;
        int row = 75 + g2 * 300 + si * 75 + g;
        val = PL[((size_t)t * 975 + row) * 80 + o];
      }
    }
  }
  Wct2[(size_t)c * 1664 + s] = (bf16)val;
}

__global__ __launch_bounds__(128) void k_zbias(const float* __restrict__ pbA,
    const float* __restrict__ lwA, const float* __restrict__ lbA, float* __restrict__ zbA) {
  const int l = blockIdx.y;
  const float* pb = pbA + (size_t)l * NT * FOUT;
  const float* lw = lwA + (size_t)l * FD * FD;
  const float* lb = lbA + (size_t)l * FD;
  float* zb = zbA + (size_t)l * 80;
  int o = threadIdx.x;
  if (o >= 80) return;
  float val = 0.f;
  if (o < 75) {
    val = lb[o];
    for (int t = 0; t < 5; ++t)
      for (int j = 0; j < 15; ++j)
        val += pb[t * 15 + j] * lw[(t * 15 + j) * 75 + o];
  }
  zb[o] = val;
}

// ---------------------------------------------------------------- fused pre-GEMM + aggregation
// A-operand DIRECT from global; B double-buffered in LDS. 6 barriers. K=192.

#define LOADB(ntb_, c_) do {                                                      \
    const bf16* wp_ = Wct + (size_t)((ntb_) + sr) * 192 + (c_) * 64 + slb * 8;    \
    pq0 = *(const uint4*)(wp_ + 0 * 6144);                                        \
    pq1 = *(const uint4*)(wp_ + 1 * 6144);                                        \
    pq2 = *(const uint4*)(wp_ + 2 * 6144);                                        \
    pq3 = *(const uint4*)(wp_ + 3 * 6144); } while (0)

#define STOREB(BS_) do {                                          \
    *(uint4*)((BS_) + (0 * 32 + sr) * 128 + (slb << 4)) = pq0;    \
    *(uint4*)((BS_) + (1 * 32 + sr) * 128 + (slb << 4)) = pq1;    \
    *(uint4*)((BS_) + (2 * 32 + sr) * 128 + (slb << 4)) = pq2;    \
    *(uint4*)((BS_) + (3 * 32 + sr) * 128 + (slb << 4)) = pq3; } while (0)

#define DO_KK(BS_, KB_, A0_, A1_, A2_, A3_) do {                         \
    bf16x8 af0 = *(const bf16x8*)(A0_);                                  \
    bf16x8 af1 = *(const bf16x8*)(A1_);                                  \
    bf16x8 af2 = *(const bf16x8*)(A2_);                                  \
    bf16x8 af3 = *(const bf16x8*)(A3_);                                  \
    const unsigned char* bp_ = (BS_) + (((KB_) ^ (l15 & 7)) << 4) + wc * 8192 + l15 * 128; \
    bf16x8 bv0 = *(const bf16x8*)(bp_ + 0 * 2048);                       \
    bf16x8 bv1 = *(const bf16x8*)(bp_ + 1 * 2048);                       \
    bf16x8 bv2 = *(const bf16x8*)(bp_ + 2 * 2048);                       \
    bf16x8 bv3 = *(const bf16x8*)(bp_ + 3 * 2048);                       \
    acc[0][0] = __builtin_amdgcn_mfma_f32_16x16x32_bf16(af0, bv0, acc[0][0], 0, 0, 0); \
    acc[1][0] = __builtin_amdgcn_mfma_f32_16x16x32_bf16(af1, bv0, acc[1][0], 0, 0, 0); \
    acc[2][0] = __builtin_amdgcn_mfma_f32_16x16x32_bf16(af2, bv0, acc[2][0], 0, 0, 0); \
    acc[3][0] = __builtin_amdgcn_mfma_f32_16x16x32_bf16(af3, bv0, acc[3][0], 0, 0, 0); \
    acc[0][1] = __builtin_amdgcn_mfma_f32_16x16x32_bf16(af0, bv1, acc[0][1], 0, 0, 0); \
    acc[1][1] = __builtin_amdgcn_mfma_f32_16x16x32_bf16(af1, bv1, acc[1][1], 0, 0, 0); \
    acc[2][1] = __builtin_amdgcn_mfma_f32_16x16x32_bf16(af2, bv1, acc[2][1], 0, 0, 0); \
    acc[3][1] = __builtin_amdgcn_mfma_f32_16x16x32_bf16(af3, bv1, acc[3][1], 0, 0, 0); \
    acc[0][2] = __builtin_amdgcn_mfma_f32_16x16x32_bf16(af0, bv2, acc[0][2], 0, 0, 0); \
    acc[1][2] = __builtin_amdgcn_mfma_f32_16x16x32_bf16(af1, bv2, acc[1][2], 0, 0, 0); \
    acc[2][2] = __builtin_amdgcn_mfma_f32_16x16x32_bf16(af2, bv2, acc[2][2], 0, 0, 0); \
    acc[3][2] = __builtin_amdgcn_mfma_f32_16x16x32_bf16(af3, bv2, acc[3][2], 0, 0, 0); \
    acc[0][3] = __builtin_amdgcn_mfma_f32_16x16x32_bf16(af0, bv3, acc[0][3], 0, 0, 0); \
    acc[1][3] = __builtin_amdgcn_mfma_f32_16x16x32_bf16(af1, bv3, acc[1][3], 0, 0, 0); \
    acc[2][3] = __builtin_amdgcn_mfma_f32_16x16x32_bf16(af2, bv3, acc[2][3], 0, 0, 0); \
    acc[3][3] = __builtin_amdgcn_mfma_f32_16x16x32_bf16(af3, bv3, acc[3][3], 0, 0, 0); \
  } while (0)

__global__ __launch_bounds__(256) void k_pre_fused(
    const bf16* __restrict__ hbf, const int* __restrict__ eids,
    const int* __restrict__ srcA, const int* __restrict__ dstA,
    const int* __restrict__ rowptr, const int* __restrict__ bstart, const int* __restrict__ nblk,
    const bf16* __restrict__ Wct, const float* __restrict__ bc,
    bf16* __restrict__ aggbf2, unsigned eoff_base) {
  __shared__ __align__(16) unsigned char smem[33792];   // Bs dbuf 32K; m_lds overlays
  unsigned char* Bs0 = smem;
  unsigned char* Bs1 = smem + 16384;
  bf16* m_lds = (bf16*)smem;                             // [128][132] bf16
  __shared__ unsigned dOffL[128], sOffL[128], eOffL[128];
  __shared__ int nodeRows[129];
  __shared__ int nq[5];

  const int b = blockIdx.x;
  if (b >= nblk[0]) return;
  const int ntb = blockIdx.y * 128;
  const int tid = threadIdx.x;
  const int n0b = bstart[b], n1b = bstart[b + 1];
  const int rbase = rowptr[n0b];
  const int nrows = rowptr[n1b] - rbase;     // <= 128
  const int nnod = n1b - n0b;                // <= 128

  if (tid == 0) { nq[0] = 0; nq[1] = 0; nq[2] = 0; nq[3] = 0; nq[4] = nnod; }
  if (tid < 128) {
    int e = (tid < nrows) ? eids[rbase + tid] : 0;
    dOffL[tid] = (unsigned)(dstA[e] * 160);
    sOffL[tid] = (unsigned)(srcA[e] * 160);
    eOffL[tid] = eoff_base + (unsigned)(e * 16);
  }
  if (tid <= nnod) nodeRows[tid] = rowptr[n0b + tid] - rbase;
  __syncthreads();
  if (tid < nnod) {
#pragma unroll
    for (int q = 1; q <= 3; ++q) {
      int target = (nrows * q) >> 2;
      if (nodeRows[tid] < target && nodeRows[tid + 1] >= target) nq[q] = tid + 1;
    }
  }

  const int lane = tid & 63;
  const int wave = tid >> 6;
  const int wr = wave >> 1, wc = wave & 1;
  const int l15 = lane & 15, l4 = lane >> 4;
  const int sr = tid >> 3, slb = tid & 7;

  const unsigned char* hb = (const unsigned char*)hbf;
  const int ar = wr * 64 + l15;
  const unsigned dof0 = dOffL[ar], dof1 = dOffL[ar + 16], dof2 = dOffL[ar + 32], dof3 = dOffL[ar + 48];
  const unsigned sof0 = sOffL[ar], sof1 = sOffL[ar + 16], sof2 = sOffL[ar + 32], sof3 = sOffL[ar + 48];
  const unsigned eof0 = eOffL[ar], eof1 = eOffL[ar + 16], eof2 = eOffL[ar + 32], eof3 = eOffL[ar + 48];

  f32x4 acc[4][4];
  f32x4 zv = {0.f, 0.f, 0.f, 0.f};
#pragma unroll
  for (int i = 0; i < 4; ++i)
#pragma unroll
    for (int j = 0; j < 4; ++j) acc[i][j] = zv;

  uint4 pq0, pq1, pq2, pq3;
  LOADB(ntb, 0);

  // ---- chunk 0: A = dst elems [0,64)
  STOREB(Bs0);
  __syncthreads();
  LOADB(ntb, 1);
  DO_KK(Bs0, l4,     hb + dof0 + l4 * 16, hb + dof1 + l4 * 16, hb + dof2 + l4 * 16, hb + dof3 + l4 * 16);
  DO_KK(Bs0, 4 + l4, hb + dof0 + 64 + l4 * 16, hb + dof1 + 64 + l4 * 16, hb + dof2 + 64 + l4 * 16, hb + dof3 + 64 + l4 * 16);

  // ---- chunk 1: A = dst tail [64,80) | src [0,48)
  STOREB(Bs1);
  __syncthreads();
  LOADB(ntb, 2);
  {
    unsigned o0 = (l4 < 2) ? (dof0 + 128 + l4 * 16) : (sof0 + (l4 - 2) * 16);
    unsigned o1 = (l4 < 2) ? (dof1 + 128 + l4 * 16) : (sof1 + (l4 - 2) * 16);
    unsigned o2 = (l4 < 2) ? (dof2 + 128 + l4 * 16) : (sof2 + (l4 - 2) * 16);
    unsigned o3 = (l4 < 2) ? (dof3 + 128 + l4 * 16) : (sof3 + (l4 - 2) * 16);
    DO_KK(Bs1, l4, hb + o0, hb + o1, hb + o2, hb + o3);
  }
  DO_KK(Bs1, 4 + l4, hb + sof0 + 32 + l4 * 16, hb + sof1 + 32 + l4 * 16, hb + sof2 + 32 + l4 * 16, hb + sof3 + 32 + l4 * 16);

  // ---- chunk 2: A = src tail [48,80) | eattr4
  STOREB(Bs0);
  __syncthreads();
  DO_KK(Bs0, l4, hb + sof0 + 96 + l4 * 16, hb + sof1 + 96 + l4 * 16, hb + sof2 + 96 + l4 * 16, hb + sof3 + 96 + l4 * 16);
  DO_KK(Bs0, 4 + l4, hb + eof0 + l4 * 16, hb + eof1 + l4 * 16, hb + eof2 + l4 * 16, hb + eof3 + l4 * 16);
  __syncthreads();

  // bias + write tile into the overlay
  float bcv[4];
#pragma unroll
  for (int j = 0; j < 4; ++j) bcv[j] = bc[ntb + wc * 64 + j * 16 + l15];
#pragma unroll
  for (int i = 0; i < 4; ++i) {
    int R = wr * 64 + i * 16 + l4 * 4;
#pragma unroll
    for (int j = 0; j < 4; ++j) {
      int col = wc * 64 + j * 16 + l15;
#pragma unroll
      for (int q = 0; q < 4; ++q)
        m_lds[(R + q) * 132 + col] = (bf16)(acc[i][j][q] + bcv[j]);
    }
  }
  __syncthreads();

  // aggregate: thread = (col-pair 0..63, row-quartile 0..3); u32 reads = 2 bf16 cols
  {
    const int cp = tid & 63;
    const int qq = tid >> 6;
    const unsigned char* mb = (const unsigned char*)m_lds;
    for (int i = nq[qq]; i < nq[qq + 1]; ++i) {
      int ra = nodeRows[i], rb2 = nodeRows[i + 1];
      float s0 = 0.f, q0 = 0.f, a0 = INFINITY, b0 = -INFINITY;
      float s1 = 0.f, q1 = 0.f, a1 = INFINITY, b1 = -INFINITY;
      for (int r = ra; r < rb2; ++r) {
        unsigned u = *(const unsigned*)(mb + r * 264 + cp * 4);
        float v0 = __uint_as_float(u << 16);
        float v1 = __uint_as_float(u & 0xffff0000u);
        s0 += v0; q0 += v0 * v0; a0 = fminf(a0, v0); b0 = fmaxf(b0, v0);
        s1 += v1; q1 += v1 * v1; a1 = fminf(a1, v1); b1 = fmaxf(b1, v1);
      }
      int d = rb2 - ra;
      float inv = 1.f / ((d > 0) ? (float)d : 1.f);
      float m0 = s0 * inv, m1 = s1 * inv;
      float sd0 = sqrtf(fmaxf(q0 * inv - m0 * m0, 0.f) + 1e-5f);
      float sd1 = sqrtf(fmaxf(q1 * inv - m1 * m1, 0.f) + 1e-5f);
      if (d == 0) { a0 = 0.f; b0 = 0.f; a1 = 0.f; b1 = 0.f; }
      bf16* ag = aggbf2 + (size_t)(n0b + i) * 1536 + ntb + cp * 2;
      *(unsigned*)(ag)        = pk2(m0, m1);
      *(unsigned*)(ag + 384)  = pk2(a0, a1);
      *(unsigned*)(ag + 768)  = pk2(b0, b1);
      *(unsigned*)(ag + 1152) = pk2(sd0, sd1);
    }
  }
}

// ---------------------------------------------------------------- post GEMM + epilogue + BN stats
// v3: 32-row tiles (grid 313x2, 626 blocks) + A-direct from global. B staged only.

#define LOADPB(c_) do {                                                 \
    int ko_ = (c_) * 128 + slb * 8;                                     \
    pb0 = *(const uint4*)(pc0 + ko_);                                   \
    pb1 = *(const uint4*)(pc0 + ko_ + 64);                              \
    pb2 = *(const uint4*)(pc1 + ko_);                                   \
    pb3 = *(const uint4*)(pc1 + ko_ + 64);                              \
    pb4 = *(const uint4*)(pc2 + ko_);                                   \
    pb5 = *(const uint4*)(pc2 + ko_ + 64);                              \
    pb6 = *(const uint4*)(pc3 + ko_);                                   \
    pb7 = *(const uint4*)(pc3 + ko_ + 64);                              \
  } while (0)

#define PAPTR(hb_, ab_, ok_, off_) ((ok_) ? ((off_) < 80 ? (hb_) + (off_) : \
    ((off_) < 1616 ? (ab_) + (off_) : zerobuf)) : zerobuf)

__global__ __launch_bounds__(256) void k_post4(const bf16* __restrict__ hbf,
    const bf16* __restrict__ aggbf2, const bf16* __restrict__ Wct2,
    const float* __restrict__ zb, const float* __restrict__ scl, const float* __restrict__ iscl,
    const bf16* __restrict__ zerobuf, float* __restrict__ z, float* __restrict__ stat_raw_l) {
  __shared__ __align__(16) unsigned char smem[32768];   // Bs 32K; Ps [32][132]f32 overlays
  unsigned char* Bs = smem;
  float* Ps = (float*)smem;
  __shared__ float sclS[32], isclS[32];
  const int n0 = blockIdx.x * 32;
  const int y  = blockIdx.y;
  const int tid = threadIdx.x;
  const int lane = tid & 63, wave = tid >> 6;
  const int l15 = lane & 15, l4 = lane >> 4;
  const int sr = tid >> 3, slb = tid & 7;

  const bf16 *pc0, *pc1, *pc2, *pc3;
  {
    int c0 = sr, c1 = sr + 32, c2 = sr + 64, c3 = sr + 96;
    int l0 = (c0 / 40) * 80 + y * 40 + (c0 % 40);
    int l1 = (c1 / 40) * 80 + y * 40 + (c1 % 40);
    int l2 = (c2 / 40) * 80 + y * 40 + (c2 % 40);
    int l3 = (c3 < 120) ? ((c3 / 40) * 80 + y * 40 + (c3 % 40)) : 0;
    pc0 = Wct2 + (size_t)l0 * 1664;
    pc1 = Wct2 + (size_t)l1 * 1664;
    pc2 = Wct2 + (size_t)l2 * 1664;
    pc3 = Wct2 + (size_t)l3 * 1664;
  }
  if (tid < 32) {
    int n = n0 + tid;
    sclS[tid] = (n < NN) ? scl[n] : 0.f;
    isclS[tid] = (n < NN) ? iscl[n] : 0.f;
  }

  // A-direct per-lane row bases: rows i*16+l15, i=0..1
  const int na0 = n0 + l15, na1 = n0 + 16 + l15;
  const bool ok0 = na0 < NN, ok1 = na1 < NN;
  const bf16* hb0 = hbf + na0 * 80;
  const bf16* hb1 = hbf + na1 * 80;
  const bf16* ab0 = aggbf2 + (size_t)na0 * 1536 - 80;
  const bf16* ab1 = aggbf2 + (size_t)na1 * 1536 - 80;

  f32x4 acc[2][2];
  f32x4 zvv = {0.f, 0.f, 0.f, 0.f};
#pragma unroll
  for (int i = 0; i < 2; ++i)
#pragma unroll
    for (int j = 0; j < 2; ++j) acc[i][j] = zvv;

  uint4 pb0, pb1, pb2, pb3, pb4, pb5, pb6, pb7;
  LOADPB(0);
  for (int c = 0; c < 13; ++c) {
    *(uint4*)(Bs + (sr)      * 256 + (slb << 4)) = pb0;
    *(uint4*)(Bs + (sr)      * 256 + (slb << 4) + 128) = pb1;
    *(uint4*)(Bs + (sr + 32) * 256 + (slb << 4)) = pb2;
    *(uint4*)(Bs + (sr + 32) * 256 + (slb << 4) + 128) = pb3;
    *(uint4*)(Bs + (sr + 64) * 256 + (slb << 4)) = pb4;
    *(uint4*)(Bs + (sr + 64) * 256 + (slb << 4) + 128) = pb5;
    *(uint4*)(Bs + (sr + 96) * 256 + (slb << 4)) = pb6;
    *(uint4*)(Bs + (sr + 96) * 256 + (slb << 4) + 128) = pb7;
    __syncthreads();
    if (c < 12) LOADPB(c + 1);
#pragma unroll
    for (int kk = 0; kk < 4; ++kk) {
      int kb = kk * 4 + l4;
      int off = c * 128 + kb * 8;
      bf16x8 af0 = *(const bf16x8*)PAPTR(hb0, ab0, ok0, off);
      bf16x8 af1 = *(const bf16x8*)PAPTR(hb1, ab1, ok1, off);
      bf16x8 bv0, bv1;
      {
        int cidx0 = wave * 32 + l15;
        int cidx1 = wave * 32 + 16 + l15;
        bv0 = *(const bf16x8*)(Bs + cidx0 * 256 + (((kb & 8) | ((kb & 7) ^ (cidx0 & 7))) << 4));
        bv1 = *(const bf16x8*)(Bs + cidx1 * 256 + (((kb & 8) | ((kb & 7) ^ (cidx1 & 7))) << 4));
      }
      acc[0][0] = __builtin_amdgcn_mfma_f32_16x16x32_bf16(af0, bv0, acc[0][0], 0, 0, 0);
      acc[1][0] = __builtin_amdgcn_mfma_f32_16x16x32_bf16(af1, bv0, acc[1][0], 0, 0, 0);
      acc[0][1] = __builtin_amdgcn_mfma_f32_16x16x32_bf16(af0, bv1, acc[0][1], 0, 0, 0);
      acc[1][1] = __builtin_amdgcn_mfma_f32_16x16x32_bf16(af1, bv1, acc[1][1], 0, 0, 0);
    }
    __syncthreads();
  }

  // P -> Ps overlay (Bs dead)
#pragma unroll
  for (int i = 0; i < 2; ++i) {
#pragma unroll
    for (int j = 0; j < 2; ++j) {
      int cidx = wave * 32 + j * 16 + l15;
#pragma unroll
      for (int q = 0; q < 4; ++q)
        Ps[(i * 16 + l4 * 4 + q) * 132 + cidx] = acc[i][j][q];
    }
  }
  __syncthreads();

  // epilogue: 32 rows x 40 f = 1280 = 5 per thread
  float v0_, v1_, v2_, v3_, v4_;
  int r0_, r1_, r2_, r3_, r4_, f0_, f1_, f2_, f3_, f4_;
#define EPI(t_, vv_, rr_, ff_) do {                                           \
    int idx_ = tid + (t_) * 256;                                              \
    rr_ = idx_ / 40; ff_ = idx_ - rr_ * 40;                                   \
    int n_ = n0 + rr_, zc_ = y * 40 + ff_;                                    \
    float v_ = 0.f;                                                           \
    if (n_ < NN && zc_ < 75) {                                                \
      v_ = Ps[rr_ * 132 + ff_] + sclS[rr_] * Ps[rr_ * 132 + 40 + ff_]         \
         + isclS[rr_] * Ps[rr_ * 132 + 80 + ff_] + zb[zc_];                   \
      z[n_ * 75 + zc_] = v_;                                                  \
    }                                                                         \
    vv_ = v_;                                                                 \
  } while (0)
  EPI(0, v0_, r0_, f0_); EPI(1, v1_, r1_, f1_); EPI(2, v2_, r2_, f2_);
  EPI(3, v3_, r3_, f3_); EPI(4, v4_, r4_, f4_);
#undef EPI
  __syncthreads();
  Ps[r0_ * 132 + f0_] = v0_;
  Ps[r1_ * 132 + f1_] = v1_;
  Ps[r2_ * 132 + f2_] = v2_;
  Ps[r3_ * 132 + f3_] = v3_;
  Ps[r4_ * 132 + f4_] = v4_;
  __syncthreads();
  if (tid < 40) {
    int zc = y * 40 + tid;
    if (zc < 75) {
      float s = 0.f, s2 = 0.f;
#pragma unroll
      for (int r = 0; r < 32; ++r) {
        float v = Ps[r * 132 + tid];
        s += v; s2 += v * v;
      }
      atomicAdd(&stat_raw_l[zc], s);
      atomicAdd(&stat_raw_l[75 + zc], s2);
    }
  }
}

// bnapply; on last layer (outF != null) also fused global_add_pool via atomics
__global__ __launch_bounds__(256) void k_bnapply(const float* __restrict__ z,
    const float* __restrict__ stat_raw, const float* __restrict__ g, const float* __restrict__ b,
    float* __restrict__ outF, bf16* __restrict__ hbf,
    const int* __restrict__ batch, float* __restrict__ gpool) {
  int idx = blockIdx.x * 256 + threadIdx.x;
  if (idx >= NN * FD) return;
  int n = idx / FD, f = idx - n * FD;
  float mu = stat_raw[f] * (1.f / NN);
  float var = stat_raw[75 + f] * (1.f / NN) - mu * mu;
  var = fmaxf(var, 0.f);
  float rs = 1.f / sqrtf(var + 1e-5f);
  float v = (z[idx] - mu) * rs * g[f] + b[f];
  v = fmaxf(v, 0.f);
  if (outF) {
    outF[idx] = v;
    atomicAdd(&gpool[batch[n] * FD + f], v);
  }
  hbf[n * 80 + f] = (bf16)v;
}

// parallel MLP head: one block per graph, 128 threads
__global__ __launch_bounds__(128) void k_mlp2(const float* __restrict__ gpool,
    const float* __restrict__ w1, const float* __restrict__ b1,
    const float* __restrict__ w2, const float* __restrict__ b2,
    const float* __restrict__ w3, const float* __restrict__ b3,
    float* __restrict__ out) {
  __shared__ float G[75];
  __shared__ float H1[50];
  __shared__ float H2[25];
  const int gr = blockIdx.x;
  const int tid = threadIdx.x;
  if (tid < 75) G[tid] = gpool[gr * FD + tid];
  __syncthreads();
  if (tid < 50) {
    float a = b1[tid];
    for (int k = 0; k < 75; ++k) a += G[k] * w1[k * 50 + tid];
    H1[tid] = fmaxf(a, 0.f);
  }
  __syncthreads();
  if (tid < 25) {
    float a = b2[tid];
    for (int k = 0; k < 50; ++k) a += H1[k] * w2[k * 25 + tid];
    H2[tid] = fmaxf(a, 0.f);
  }
  __syncthreads();
  if (tid == 0) {
    float a = b3[0];
    for (int k = 0; k < 25; ++k) a += H2[k] * w3[k];
    out[gr] = a;
  }
}

// ---------------------------------------------------------------- host

extern "C" void kernel_launch(void* const* d_in, const int* in_sizes, int n_in,
                              void* d_out, int out_size, void* d_ws, size_t ws_size,
                              hipStream_t stream) {
  (void)in_sizes; (void)n_in; (void)out_size; (void)ws_size;
  const float* x      = (const float*)d_in[0];
  const int*   eidx   = (const int*)  d_in[1];
  const float* eattr  = (const float*)d_in[2];
  const int*   batch  = (const int*)  d_in[3];
  const float* nw     = (const float*)d_in[4];
  const float* nb     = (const float*)d_in[5];
  const float* ew     = (const float*)d_in[6];
  const float* ebias  = (const float*)d_in[7];
  const float* ee_w   = (const float*)d_in[8];
  const float* ee_b   = (const float*)d_in[9];
  const float* pre_w  = (const float*)d_in[10];
  const float* pre_b  = (const float*)d_in[11];
  const float* post_w = (const float*)d_in[12];
  const float* post_b = (const float*)d_in[13];
  const float* lin_w  = (const float*)d_in[14];
  const float* lin_b  = (const float*)d_in[15];
  const float* bn_g   = (const float*)d_in[16];
  const float* bn_b   = (const float*)d_in[17];
  const float* w1 = (const float*)d_in[18];
  const float* b1 = (const float*)d_in[19];
  const float* w2 = (const float*)d_in[20];
  const float* b2 = (const float*)d_in[21];
  const float* w3 = (const float*)d_in[22];
  const float* b3 = (const float*)d_in[23];

  const int* srcA = eidx;
  const int* dstA = eidx + NE;

  char* base = (char*)d_ws;
  size_t off = 0;
  auto alloc = [&](size_t bytes) -> char* {
    char* p = base + off;
    off = (off + bytes + 255) & ~(size_t)255;
    return p;
  };
  bf16*  hbf    = (bf16*) alloc((size_t)NN * 80 * 2);
  bf16*  eabf4  = (bf16*) alloc((size_t)NE * 8 * 2 + 64);
  bf16*  aggbf2 = (bf16*) alloc((size_t)NN * 1536 * 2);
  float* z      = (float*)alloc((size_t)NN * FD * 4);
  bf16*  WctA   = (bf16*) alloc((size_t)NLAY * 384 * 192 * 2);
  float* bcA    = (float*)alloc((size_t)NLAY * 384 * 4);
  bf16*  Wct2A  = (bf16*) alloc((size_t)NLAY * 256 * 1664 * 2);
  float* zbA    = (float*)alloc((size_t)NLAY * 80 * 4);
  float* PLA    = (float*)alloc((size_t)NLAY * 5 * 975 * 80 * 4);
  float* W12A   = (float*)alloc((size_t)NLAY * 300 * 4);
  float* bcombA = (float*)alloc((size_t)NLAY * 80 * 4);
  float* scl    = (float*)alloc(NN * 4);
  float* iscl   = (float*)alloc(NN * 4);
  int*   deg    = (int*)alloc(NN * 4);
  int*   rowptr = (int*)alloc((NN + 1) * 4);
  int*   cursor = (int*)alloc(NN * 4);
  int*   eids   = (int*)alloc(NE * 4);
  int*   nxt    = (int*)alloc(NN * 4);
  int*   bstart = (int*)alloc((MAXB + 1) * 4);
  int*   nblk   = (int*)alloc(16);
  float* stat_all = (float*)alloc((size_t)NLAY * 160 * 4);
  float* gpool  = (float*)alloc(NGR * FD * 4);
  bf16*  zerobuf = (bf16*)alloc(3392);   // >= 1616*2 so PAPTR's +off stays in-bounds

  const unsigned eoff_base = (unsigned)((char*)eabf4 - (char*)hbf);

  static const int DEG_TAB[71] = {1, 72, 201, 816, 1790, 3756, 6923, 12768, 20286, 31710,
    51623, 82296, 124280, 177576, 251115, 326064, 395760, 456840, 506179, 516200, 507003,
    493746, 489256, 453936, 420025, 411320, 427761, 420700, 420500, 426780, 414284, 407008,
    394053, 360910, 322245, 313704, 282902, 270940, 237783, 209000, 193766, 177870, 162110,
    144848, 121230, 112700, 93483, 88512, 72275, 80700, 68799, 56784, 42665, 30996, 25630,
    12936, 9804, 8584, 5251, 3480, 3111, 2728, 1890, 1472, 1235, 330, 201, 68, 69, 0, 71};
  double num = 0.0, den = 0.0;
  for (int i = 0; i < 71; ++i) { num += log((double)i + 1.0) * DEG_TAB[i]; den += DEG_TAB[i]; }
  float inv_avg_log = (float)(den / num);

  hipMemsetAsync(deg, 0, NN * 4, stream);
  hipMemsetAsync(cursor, 0, NN * 4, stream);
  hipMemsetAsync(gpool, 0, NGR * FD * 4, stream);
  hipMemsetAsync(stat_all, 0, (size_t)NLAY * 160 * 4, stream);
  hipMemsetAsync(zerobuf, 0, 3392, stream);

  // graph prep
  k_node_emb<<<(NN * FD + 255) / 256, 256, 0, stream>>>(x, nw, nb, hbf);
  k_hpad<<<(NN * 5 + 255) / 256, 256, 0, stream>>>(hbf);
  k_edge4<<<(NE * 8 + 255) / 256, 256, 0, stream>>>(eattr, eabf4);
  k_count<<<(NE + 255) / 256, 256, 0, stream>>>(dstA, deg);
  k_scan<<<1, 1024, 0, stream>>>(deg, rowptr);
  k_scl<<<(NN + 255) / 256, 256, 0, stream>>>(deg, scl, iscl, inv_avg_log);
  k_scatter<<<(NE + 255) / 256, 256, 0, stream>>>(dstA, rowptr, cursor, eids);
  k_next<<<(NN + 255) / 256, 256, 0, stream>>>(rowptr, nxt);
  k_walk<<<1, 1024, 0, stream>>>(nxt, bstart, nblk);

  // weight prep, all layers batched
  {
    dim3 gw(2, NLAY);
    k_W12<<<gw, 256, 0, stream>>>(ew, ebias, ee_w, ee_b, W12A, bcombA);
    dim3 gc((384 * 192 + 255) / 256, NLAY);
    k_combine<<<gc, 256, 0, stream>>>(pre_w, pre_b, W12A, bcombA, WctA, bcA);
    dim3 gp((5 * 975 * 80 + 255) / 256, NLAY);
    k_PL<<<gp, 256, 0, stream>>>(post_w, lin_w, PLA);
    dim3 g2((256 * 1664 + 255) / 256, NLAY);
    k_combine2b<<<g2, 256, 0, stream>>>(PLA, Wct2A);
    dim3 gz(1, NLAY);
    k_zbias<<<gz, 128, 0, stream>>>(post_b, lin_w, lin_b, zbA);
  }

  float* outp = (float*)d_out;
  for (int l = 0; l < NLAY; ++l) {
    dim3 gpref(MAXB, 3);
    k_pre_fused<<<gpref, 256, 0, stream>>>(hbf, eids, srcA, dstA, rowptr, bstart, nblk,
        WctA + (size_t)l * 384 * 192, bcA + (size_t)l * 384, aggbf2, eoff_base);
    dim3 gpost((NN + 31) / 32, 2);
    k_post4<<<gpost, 256, 0, stream>>>(hbf, aggbf2, Wct2A + (size_t)l * 256 * 1664,
        zbA + (size_t)l * 80, scl, iscl, zerobuf, z, stat_all + (size_t)l * 160);
    float* wdst = (l == NLAY - 1) ? (outp + NGR) : nullptr;
    k_bnapply<<<(NN * FD + 255) / 256, 256, 0, stream>>>(z, stat_all + (size_t)l * 160,
        bn_g + (size_t)l * FD, bn_b + (size_t)l * FD, wdst, hbf, batch, gpool);
  }

  k_mlp2<<<NGR, 128, 0, stream>>>(gpool, w1, b1, w2, b2, w3, b3, outp);
}

// Round 20
// 492.389 us; speedup vs baseline: 1.1982x; 1.1527x over previous
//
#include <hip/hip_runtime.h>
#include <math.h>

#define NN 10000
#define NE 100000
#define NGR 64
#define NT 5
#define FD 75
#define FOUT 15
#define NLAY 4
#define MAXB 1792

typedef __bf16 bf16;
typedef __bf16 bf16x8 __attribute__((ext_vector_type(8)));
typedef float f32x4 __attribute__((ext_vector_type(4)));

__device__ inline unsigned pk2(float a, float b) {
  bf16 x = (bf16)a, y = (bf16)b;
  unsigned short ux, uy;
  __builtin_memcpy(&ux, &x, 2); __builtin_memcpy(&uy, &y, 2);
  return (unsigned)ux | ((unsigned)uy << 16);
}

// ---------------------------------------------------------------- small prep

__global__ __launch_bounds__(256) void k_node_emb(const float* __restrict__ x,
    const float* __restrict__ w, const float* __restrict__ b, bf16* __restrict__ hbf) {
  int idx = blockIdx.x * 256 + threadIdx.x;
  if (idx >= NN * FD) return;
  int n = idx / FD, f = idx - n * FD;
  float acc = b[f];
#pragma unroll
  for (int k = 0; k < 14; ++k) acc += x[n * 14 + k] * w[k * FD + f];
  hbf[n * 80 + f] = (bf16)acc;
}

__global__ __launch_bounds__(256) void k_hpad(bf16* __restrict__ hbf) {
  int idx = blockIdx.x * 256 + threadIdx.x;
  if (idx >= NN * 5) return;
  int n = idx / 5, f = 75 + idx % 5;
  hbf[n * 80 + f] = (bf16)0.f;
}

__global__ __launch_bounds__(256) void k_edge4(const float* __restrict__ eattr,
    bf16* __restrict__ eabf4) {
  int idx = blockIdx.x * 256 + threadIdx.x;
  if (idx >= NE * 8) return;
  int e = idx >> 3, c = idx & 7;
  eabf4[idx] = (c < 4) ? (bf16)eattr[e * 4 + c] : (bf16)0.f;
}

__global__ __launch_bounds__(256) void k_count(const int* __restrict__ dst, int* __restrict__ deg) {
  int e = blockIdx.x * 256 + threadIdx.x;
  if (e < NE) atomicAdd(&deg[dst[e]], 1);
}

__global__ __launch_bounds__(1024) void k_scan(const int* __restrict__ deg, int* __restrict__ rowptr) {
  __shared__ int buf[1024];
  __shared__ int carry;
  int tid = threadIdx.x;
  if (tid == 0) carry = 0;
  __syncthreads();
  for (int base = 0; base < NN; base += 1024) {
    int i = base + tid;
    int v = (i < NN) ? deg[i] : 0;
    buf[tid] = v;
    __syncthreads();
    for (int off = 1; off < 1024; off <<= 1) {
      int t = (tid >= off) ? buf[tid - off] : 0;
      __syncthreads();
      buf[tid] += t;
      __syncthreads();
    }
    int inc = buf[tid];
    int tot = buf[1023];
    if (i < NN) rowptr[i + 1] = carry + inc;
    __syncthreads();
    if (tid == 0) carry += tot;
    __syncthreads();
  }
  if (tid == 0) rowptr[0] = 0;
}

__global__ __launch_bounds__(256) void k_scl(const int* __restrict__ deg, float* __restrict__ scl,
                                             float* __restrict__ iscl, float inv_avg_log) {
  int n = blockIdx.x * 256 + threadIdx.x;
  if (n >= NN) return;
  float c1 = fmaxf((float)deg[n], 1.f);
  float s = logf(c1 + 1.f) * inv_avg_log;
  scl[n] = s;
  iscl[n] = 1.f / s;
}

__global__ __launch_bounds__(256) void k_scatter(const int* __restrict__ dst, const int* __restrict__ rowptr,
    int* __restrict__ cursor, int* __restrict__ eids) {
  int e = blockIdx.x * 256 + threadIdx.x;
  if (e >= NE) return;
  int d = dst[e];
  int pos = rowptr[d] + atomicAdd(&cursor[d], 1);
  eids[pos] = e;
}

__global__ __launch_bounds__(256) void k_next(const int* __restrict__ rowptr, int* __restrict__ nxt) {
  int n = blockIdx.x * 256 + threadIdx.x;
  if (n >= NN) return;
  int base = rowptr[n];
  int lo = n + 1, hi = min(n + 128, NN);
  while (lo < hi) {
    int mid = (lo + hi + 1) >> 1;
    if (rowptr[mid] - base <= 128) lo = mid; else hi = mid - 1;
  }
  nxt[n] = lo;
}

__global__ __launch_bounds__(1024) void k_walk(const int* __restrict__ nxt,
    int* __restrict__ bstart, int* __restrict__ nblk) {
  __shared__ int lnx[NN];
  int tid = threadIdx.x;
  for (int i = tid; i < NN; i += 1024) lnx[i] = nxt[i];
  __syncthreads();
  if (tid == 0) {
    int b = 0, n = 0;
    while (n < NN && b < MAXB) { bstart[b++] = n; n = lnx[n]; }
    bstart[b] = NN;
    nblk[0] = b;
  }
}

// ---------------------------------------------------------------- weight prep (batched across layers)

__global__ __launch_bounds__(256) void k_W12(const float* __restrict__ ew,
    const float* __restrict__ ebias, const float* __restrict__ ee_wA, const float* __restrict__ ee_bA,
    float* __restrict__ W12A, float* __restrict__ bcombA) {
  const int l = blockIdx.y;
  const float* ee_w = ee_wA + (size_t)l * 50 * FD;
  const float* ee_b = ee_bA + (size_t)l * FD;
  int idx = blockIdx.x * 256 + threadIdx.x;
  if (idx >= 375) return;
  if (idx < 300) {
    int d = idx / 75, o = idx - d * 75;
    float v = 0.f;
    for (int j = 0; j < 50; ++j) v += ew[d * 50 + j] * ee_w[j * 75 + o];
    W12A[(size_t)l * 300 + idx] = v;
  } else {
    int o = idx - 300;
    float v = ee_b[o];
    for (int j = 0; j < 50; ++j) v += ebias[j] * ee_w[j * 75 + o];
    bcombA[(size_t)l * 80 + o] = v;
  }
}

__global__ __launch_bounds__(256) void k_combine(const float* __restrict__ pre_wA,
    const float* __restrict__ pre_bA, const float* __restrict__ W12A, const float* __restrict__ bcombA,
    bf16* __restrict__ WctA, float* __restrict__ bcA) {
  const int l = blockIdx.y;
  const float* pre_w = pre_wA + (size_t)l * NT * 225 * FD;
  const float* pre_b = pre_bA + (size_t)l * NT * FD;
  const float* W12   = W12A + (size_t)l * 300;
  const float* bcomb = bcombA + (size_t)l * 80;
  bf16* Wct = WctA + (size_t)l * 384 * 192;
  float* bc = bcA + (size_t)l * 384;
  int idx = blockIdx.x * 256 + threadIdx.x;
  if (idx >= 384 * 192) return;
  int c = idx / 192, s = idx - c * 192;
  int t = c / 75, g = c - t * 75;
  int chunk = s >> 6, within = s & 63, sblk = within >> 3, elem = within & 7;
  int lb = sblk ^ (c & 7);
  int k = chunk * 64 + lb * 8 + elem;
  float v = 0.f;
  if (c < 375) {
    if (k < 75)                    v = pre_w[(t * 225 + k) * 75 + g];
    else if (k >= 80 && k < 155)   v = pre_w[(t * 225 + 75 + (k - 80)) * 75 + g];
    else if (k >= 160 && k < 164) {
      int d = k - 160;
      float a = 0.f;
      for (int f2 = 0; f2 < 75; ++f2) a += W12[d * 75 + f2] * pre_w[(t * 225 + 150 + f2) * 75 + g];
      v = a;
    }
  }
  Wct[c * 192 + s] = (bf16)v;
  if (s == 0) {
    float a = 0.f;
    if (c < 375) {
      a = pre_b[t * 75 + g];
      for (int f2 = 0; f2 < 75; ++f2) a += bcomb[f2] * pre_w[(t * 225 + 150 + f2) * 75 + g];
    }
    bc[c] = a;
  }
}

__global__ __launch_bounds__(256) void k_PL(const float* __restrict__ pwA,
    const float* __restrict__ lwA, float* __restrict__ PLA) {
  const int l = blockIdx.y;
  const float* pw = pwA + (size_t)l * NT * 975 * FOUT;
  const float* lw = lwA + (size_t)l * FD * FD;
  float* PL = PLA + (size_t)l * 5 * 975 * 80;
  int idx = blockIdx.x * 256 + threadIdx.x;
  if (idx >= 5 * 975 * 80) return;
  int t = idx / (975 * 80), rem = idx - t * 975 * 80;
  int row = rem / 80, o = rem - row * 80;
  float v = 0.f;
  if (o < 75) {
#pragma unroll
    for (int j = 0; j < 15; ++j)
      v += pw[((size_t)t * 975 + row) * 15 + j] * lw[(t * 15 + j) * 75 + o];
  }
  PL[idx] = v;
}

__global__ __launch_bounds__(256) void k_combine2b(const float* __restrict__ PLA,
    bf16* __restrict__ Wct2A) {
  const int l = blockIdx.y;
  const float* PL = PLA + (size_t)l * 5 * 975 * 80;
  bf16* Wct2 = Wct2A + (size_t)l * 256 * 1664;
  int idx = blockIdx.x * 256 + threadIdx.x;
  if (idx >= 256 * 1664) return;
  int c = idx / 1664, s = idx - c * 1664;
  int chunk = s >> 6, within = s & 63, sblk = within >> 3, elem = within & 7;
  int lb = sblk ^ (c & 7);
  int k = chunk * 64 + lb * 8 + elem;
  int g2 = c / 80, o = c - g2 * 80;
  float val = 0.f;
  if (c < 240 && o < 75) {
    if (k < 75) {
      if (g2 == 0) {
#pragma unroll
        for (int t = 0; t < 5; ++t) val += PL[(t * 975 + k) * 80 + o];
      }
    } else if (k >= 80 && k < 1616) {
      int q = k - 80;
      int si = q / 384, cc = q - si * 384;
      if (cc < 375) {
        int t = cc / 75, g = cc - t * 75;
        int row = 75 + g2 * 300 + si * 75 + g;
        val = PL[((size_t)t * 975 + row) * 80 + o];
      }
    }
  }
  Wct2[(size_t)c * 1664 + s] = (bf16)val;
}

__global__ __launch_bounds__(128) void k_zbias(const float* __restrict__ pbA,
    const float* __restrict__ lwA, const float* __restrict__ lbA, float* __restrict__ zbA) {
  const int l = blockIdx.y;
  const float* pb = pbA + (size_t)l * NT * FOUT;
  const float* lw = lwA + (size_t)l * FD * FD;
  const float* lb = lbA + (size_t)l * FD;
  float* zb = zbA + (size_t)l * 80;
  int o = threadIdx.x;
  if (o >= 80) return;
  float val = 0.f;
  if (o < 75) {
    val = lb[o];
    for (int t = 0; t < 5; ++t)
      for (int j = 0; j < 15; ++j)
        val += pb[t * 15 + j] * lw[(t * 15 + j) * 75 + o];
  }
  zb[o] = val;
}

// ---------------------------------------------------------------- fused pre-GEMM + aggregation
// A-operand DIRECT from global; B double-buffered in LDS. 6 barriers. K=192.

#define LOADB(ntb_, c_) do {                                                      \
    const bf16* wp_ = Wct + (size_t)((ntb_) + sr) * 192 + (c_) * 64 + slb * 8;    \
    pq0 = *(const uint4*)(wp_ + 0 * 6144);                                        \
    pq1 = *(const uint4*)(wp_ + 1 * 6144);                                        \
    pq2 = *(const uint4*)(wp_ + 2 * 6144);                                        \
    pq3 = *(const uint4*)(wp_ + 3 * 6144); } while (0)

#define STOREB(BS_) do {                                          \
    *(uint4*)((BS_) + (0 * 32 + sr) * 128 + (slb << 4)) = pq0;    \
    *(uint4*)((BS_) + (1 * 32 + sr) * 128 + (slb << 4)) = pq1;    \
    *(uint4*)((BS_) + (2 * 32 + sr) * 128 + (slb << 4)) = pq2;    \
    *(uint4*)((BS_) + (3 * 32 + sr) * 128 + (slb << 4)) = pq3; } while (0)

#define DO_KK(BS_, KB_, A0_, A1_, A2_, A3_) do {                         \
    bf16x8 af0 = *(const bf16x8*)(A0_);                                  \
    bf16x8 af1 = *(const bf16x8*)(A1_);                                  \
    bf16x8 af2 = *(const bf16x8*)(A2_);                                  \
    bf16x8 af3 = *(const bf16x8*)(A3_);                                  \
    const unsigned char* bp_ = (BS_) + (((KB_) ^ (l15 & 7)) << 4) + wc * 8192 + l15 * 128; \
    bf16x8 bv0 = *(const bf16x8*)(bp_ + 0 * 2048);                       \
    bf16x8 bv1 = *(const bf16x8*)(bp_ + 1 * 2048);                       \
    bf16x8 bv2 = *(const bf16x8*)(bp_ + 2 * 2048);                       \
    bf16x8 bv3 = *(const bf16x8*)(bp_ + 3 * 2048);                       \
    acc[0][0] = __builtin_amdgcn_mfma_f32_16x16x32_bf16(af0, bv0, acc[0][0], 0, 0, 0); \
    acc[1][0] = __builtin_amdgcn_mfma_f32_16x16x32_bf16(af1, bv0, acc[1][0], 0, 0, 0); \
    acc[2][0] = __builtin_amdgcn_mfma_f32_16x16x32_bf16(af2, bv0, acc[2][0], 0, 0, 0); \
    acc[3][0] = __builtin_amdgcn_mfma_f32_16x16x32_bf16(af3, bv0, acc[3][0], 0, 0, 0); \
    acc[0][1] = __builtin_amdgcn_mfma_f32_16x16x32_bf16(af0, bv1, acc[0][1], 0, 0, 0); \
    acc[1][1] = __builtin_amdgcn_mfma_f32_16x16x32_bf16(af1, bv1, acc[1][1], 0, 0, 0); \
    acc[2][1] = __builtin_amdgcn_mfma_f32_16x16x32_bf16(af2, bv1, acc[2][1], 0, 0, 0); \
    acc[3][1] = __builtin_amdgcn_mfma_f32_16x16x32_bf16(af3, bv1, acc[3][1], 0, 0, 0); \
    acc[0][2] = __builtin_amdgcn_mfma_f32_16x16x32_bf16(af0, bv2, acc[0][2], 0, 0, 0); \
    acc[1][2] = __builtin_amdgcn_mfma_f32_16x16x32_bf16(af1, bv2, acc[1][2], 0, 0, 0); \
    acc[2][2] = __builtin_amdgcn_mfma_f32_16x16x32_bf16(af2, bv2, acc[2][2], 0, 0, 0); \
    acc[3][2] = __builtin_amdgcn_mfma_f32_16x16x32_bf16(af3, bv2, acc[3][2], 0, 0, 0); \
    acc[0][3] = __builtin_amdgcn_mfma_f32_16x16x32_bf16(af0, bv3, acc[0][3], 0, 0, 0); \
    acc[1][3] = __builtin_amdgcn_mfma_f32_16x16x32_bf16(af1, bv3, acc[1][3], 0, 0, 0); \
    acc[2][3] = __builtin_amdgcn_mfma_f32_16x16x32_bf16(af2, bv3, acc[2][3], 0, 0, 0); \
    acc[3][3] = __builtin_amdgcn_mfma_f32_16x16x32_bf16(af3, bv3, acc[3][3], 0, 0, 0); \
  } while (0)

__global__ __launch_bounds__(256) void k_pre_fused(
    const bf16* __restrict__ hbf, const int* __restrict__ eids,
    const int* __restrict__ srcA, const int* __restrict__ dstA,
    const int* __restrict__ rowptr, const int* __restrict__ bstart, const int* __restrict__ nblk,
    const bf16* __restrict__ Wct, const float* __restrict__ bc,
    bf16* __restrict__ aggbf2, unsigned eoff_base) {
  __shared__ __align__(16) unsigned char smem[33792];   // Bs dbuf 32K; m_lds overlays
  unsigned char* Bs0 = smem;
  unsigned char* Bs1 = smem + 16384;
  bf16* m_lds = (bf16*)smem;                             // [128][132] bf16
  __shared__ unsigned dOffL[128], sOffL[128], eOffL[128];
  __shared__ int nodeRows[129];
  __shared__ int nq[5];

  const int b = blockIdx.x;
  if (b >= nblk[0]) return;
  const int ntb = blockIdx.y * 128;
  const int tid = threadIdx.x;
  const int n0b = bstart[b], n1b = bstart[b + 1];
  const int rbase = rowptr[n0b];
  const int nrows = rowptr[n1b] - rbase;     // <= 128
  const int nnod = n1b - n0b;                // <= 128

  if (tid == 0) { nq[0] = 0; nq[1] = 0; nq[2] = 0; nq[3] = 0; nq[4] = nnod; }
  if (tid < 128) {
    int e = (tid < nrows) ? eids[rbase + tid] : 0;
    dOffL[tid] = (unsigned)(dstA[e] * 160);
    sOffL[tid] = (unsigned)(srcA[e] * 160);
    eOffL[tid] = eoff_base + (unsigned)(e * 16);
  }
  if (tid <= nnod) nodeRows[tid] = rowptr[n0b + tid] - rbase;
  __syncthreads();
  if (tid < nnod) {
#pragma unroll
    for (int q = 1; q <= 3; ++q) {
      int target = (nrows * q) >> 2;
      if (nodeRows[tid] < target && nodeRows[tid + 1] >= target) nq[q] = tid + 1;
    }
  }

  const int lane = tid & 63;
  const int wave = tid >> 6;
  const int wr = wave >> 1, wc = wave & 1;
  const int l15 = lane & 15, l4 = lane >> 4;
  const int sr = tid >> 3, slb = tid & 7;

  const unsigned char* hb = (const unsigned char*)hbf;
  const int ar = wr * 64 + l15;
  const unsigned dof0 = dOffL[ar], dof1 = dOffL[ar + 16], dof2 = dOffL[ar + 32], dof3 = dOffL[ar + 48];
  const unsigned sof0 = sOffL[ar], sof1 = sOffL[ar + 16], sof2 = sOffL[ar + 32], sof3 = sOffL[ar + 48];
  const unsigned eof0 = eOffL[ar], eof1 = eOffL[ar + 16], eof2 = eOffL[ar + 32], eof3 = eOffL[ar + 48];

  f32x4 acc[4][4];
  f32x4 zv = {0.f, 0.f, 0.f, 0.f};
#pragma unroll
  for (int i = 0; i < 4; ++i)
#pragma unroll
    for (int j = 0; j < 4; ++j) acc[i][j] = zv;

  uint4 pq0, pq1, pq2, pq3;
  LOADB(ntb, 0);

  // ---- chunk 0: A = dst elems [0,64)
  STOREB(Bs0);
  __syncthreads();
  LOADB(ntb, 1);
  DO_KK(Bs0, l4,     hb + dof0 + l4 * 16, hb + dof1 + l4 * 16, hb + dof2 + l4 * 16, hb + dof3 + l4 * 16);
  DO_KK(Bs0, 4 + l4, hb + dof0 + 64 + l4 * 16, hb + dof1 + 64 + l4 * 16, hb + dof2 + 64 + l4 * 16, hb + dof3 + 64 + l4 * 16);

  // ---- chunk 1: A = dst tail [64,80) | src [0,48)
  STOREB(Bs1);
  __syncthreads();
  LOADB(ntb, 2);
  {
    unsigned o0 = (l4 < 2) ? (dof0 + 128 + l4 * 16) : (sof0 + (l4 - 2) * 16);
    unsigned o1 = (l4 < 2) ? (dof1 + 128 + l4 * 16) : (sof1 + (l4 - 2) * 16);
    unsigned o2 = (l4 < 2) ? (dof2 + 128 + l4 * 16) : (sof2 + (l4 - 2) * 16);
    unsigned o3 = (l4 < 2) ? (dof3 + 128 + l4 * 16) : (sof3 + (l4 - 2) * 16);
    DO_KK(Bs1, l4, hb + o0, hb + o1, hb + o2, hb + o3);
  }
  DO_KK(Bs1, 4 + l4, hb + sof0 + 32 + l4 * 16, hb + sof1 + 32 + l4 * 16, hb + sof2 + 32 + l4 * 16, hb + sof3 + 32 + l4 * 16);

  // ---- chunk 2: A = src tail [48,80) | eattr4
  STOREB(Bs0);
  __syncthreads();
  DO_KK(Bs0, l4, hb + sof0 + 96 + l4 * 16, hb + sof1 + 96 + l4 * 16, hb + sof2 + 96 + l4 * 16, hb + sof3 + 96 + l4 * 16);
  DO_KK(Bs0, 4 + l4, hb + eof0 + l4 * 16, hb + eof1 + l4 * 16, hb + eof2 + l4 * 16, hb + eof3 + l4 * 16);
  __syncthreads();

  // bias + write tile into the overlay
  float bcv[4];
#pragma unroll
  for (int j = 0; j < 4; ++j) bcv[j] = bc[ntb + wc * 64 + j * 16 + l15];
#pragma unroll
  for (int i = 0; i < 4; ++i) {
    int R = wr * 64 + i * 16 + l4 * 4;
#pragma unroll
    for (int j = 0; j < 4; ++j) {
      int col = wc * 64 + j * 16 + l15;
#pragma unroll
      for (int q = 0; q < 4; ++q)
        m_lds[(R + q) * 132 + col] = (bf16)(acc[i][j][q] + bcv[j]);
    }
  }
  __syncthreads();

  // aggregate: thread = (col-pair 0..63, row-quartile 0..3); u32 reads = 2 bf16 cols
  {
    const int cp = tid & 63;
    const int qq = tid >> 6;
    const unsigned char* mb = (const unsigned char*)m_lds;
    for (int i = nq[qq]; i < nq[qq + 1]; ++i) {
      int ra = nodeRows[i], rb2 = nodeRows[i + 1];
      float s0 = 0.f, q0 = 0.f, a0 = INFINITY, b0 = -INFINITY;
      float s1 = 0.f, q1 = 0.f, a1 = INFINITY, b1 = -INFINITY;
      for (int r = ra; r < rb2; ++r) {
        unsigned u = *(const unsigned*)(mb + r * 264 + cp * 4);
        float v0 = __uint_as_float(u << 16);
        float v1 = __uint_as_float(u & 0xffff0000u);
        s0 += v0; q0 += v0 * v0; a0 = fminf(a0, v0); b0 = fmaxf(b0, v0);
        s1 += v1; q1 += v1 * v1; a1 = fminf(a1, v1); b1 = fmaxf(b1, v1);
      }
      int d = rb2 - ra;
      float inv = 1.f / ((d > 0) ? (float)d : 1.f);
      float m0 = s0 * inv, m1 = s1 * inv;
      float sd0 = sqrtf(fmaxf(q0 * inv - m0 * m0, 0.f) + 1e-5f);
      float sd1 = sqrtf(fmaxf(q1 * inv - m1 * m1, 0.f) + 1e-5f);
      if (d == 0) { a0 = 0.f; b0 = 0.f; a1 = 0.f; b1 = 0.f; }
      bf16* ag = aggbf2 + (size_t)(n0b + i) * 1536 + ntb + cp * 2;
      *(unsigned*)(ag)        = pk2(m0, m1);
      *(unsigned*)(ag + 384)  = pk2(a0, a1);
      *(unsigned*)(ag + 768)  = pk2(b0, b1);
      *(unsigned*)(ag + 1152) = pk2(sd0, sd1);
    }
  }
}

// ---------------------------------------------------------------- post GEMM + epilogue + BN stats
// round-17 config: staged A (one-chunk-ahead reg prefetch), 32-row tiles, grid (313,2).

#define APG_(g_) ((nA >= NN || (g_) >= 202) ? zerobuf : \
    ((g_) < 10 ? hbf + nA * 80 + (g_) * 8 : aggbf2 + (size_t)nA * 1536 + ((g_) - 10) * 8))

#define LOADP4(c_) do {                                                 \
    int gA_ = (c_) * 16 + slb;                                          \
    pa0 = *(const uint4*)APG_(gA_);                                     \
    pa1 = *(const uint4*)APG_(gA_ + 8);                                 \
    int ko_ = (c_) * 128 + slb * 8;                                     \
    pb0 = *(const uint4*)(pc0 + ko_);                                   \
    pb1 = *(const uint4*)(pc0 + ko_ + 64);                              \
    pb2 = *(const uint4*)(pc1 + ko_);                                   \
    pb3 = *(const uint4*)(pc1 + ko_ + 64);                              \
    pb4 = *(const uint4*)(pc2 + ko_);                                   \
    pb5 = *(const uint4*)(pc2 + ko_ + 64);                              \
    pb6 = *(const uint4*)(pc3 + ko_);                                   \
    pb7 = *(const uint4*)(pc3 + ko_ + 64);                              \
  } while (0)

__global__ __launch_bounds__(256) void k_post4(const bf16* __restrict__ hbf,
    const bf16* __restrict__ aggbf2, const bf16* __restrict__ Wct2,
    const float* __restrict__ zb, const float* __restrict__ scl, const float* __restrict__ iscl,
    const bf16* __restrict__ zerobuf, float* __restrict__ z, float* __restrict__ stat_raw_l) {
  __shared__ __align__(16) unsigned char smem[40960];   // As 8K + Bs 32K; Ps overlays
  unsigned char* As = smem;
  unsigned char* Bs = smem + 8192;
  float* Ps = (float*)smem;                             // [32][132] f32
  __shared__ float sclS[32], isclS[32];
  const int n0 = blockIdx.x * 32;
  const int y  = blockIdx.y;
  const int tid = threadIdx.x;
  const int lane = tid & 63, wave = tid >> 6;
  const int l15 = lane & 15, l4 = lane >> 4;
  const int sr = tid >> 3, slb = tid & 7;
  const int nA = n0 + sr;

  const bf16 *pc0, *pc1, *pc2, *pc3;
  {
    int c0 = sr, c1 = sr + 32, c2 = sr + 64, c3 = sr + 96;
    int l0 = (c0 / 40) * 80 + y * 40 + (c0 % 40);
    int l1 = (c1 / 40) * 80 + y * 40 + (c1 % 40);
    int l2 = (c2 / 40) * 80 + y * 40 + (c2 % 40);
    int l3 = (c3 < 120) ? ((c3 / 40) * 80 + y * 40 + (c3 % 40)) : 0;
    pc0 = Wct2 + (size_t)l0 * 1664;
    pc1 = Wct2 + (size_t)l1 * 1664;
    pc2 = Wct2 + (size_t)l2 * 1664;
    pc3 = Wct2 + (size_t)l3 * 1664;
  }
  if (tid < 32) {
    int n = n0 + tid;
    sclS[tid] = (n < NN) ? scl[n] : 0.f;
    isclS[tid] = (n < NN) ? iscl[n] : 0.f;
  }

  f32x4 acc[2][2];
  f32x4 zvv = {0.f, 0.f, 0.f, 0.f};
#pragma unroll
  for (int i = 0; i < 2; ++i)
#pragma unroll
    for (int j = 0; j < 2; ++j) acc[i][j] = zvv;

  uint4 pa0, pa1, pb0, pb1, pb2, pb3, pb4, pb5, pb6, pb7;
  LOADP4(0);
  for (int c = 0; c < 13; ++c) {
    {
      int s1_ = (slb ^ (sr & 7)) << 4;
      *(uint4*)(As + sr * 256 + s1_) = pa0;
      *(uint4*)(As + sr * 256 + s1_ + 128) = pa1;
      *(uint4*)(Bs + (sr)      * 256 + (slb << 4)) = pb0;
      *(uint4*)(Bs + (sr)      * 256 + (slb << 4) + 128) = pb1;
      *(uint4*)(Bs + (sr + 32) * 256 + (slb << 4)) = pb2;
      *(uint4*)(Bs + (sr + 32) * 256 + (slb << 4) + 128) = pb3;
      *(uint4*)(Bs + (sr + 64) * 256 + (slb << 4)) = pb4;
      *(uint4*)(Bs + (sr + 64) * 256 + (slb << 4) + 128) = pb5;
      *(uint4*)(Bs + (sr + 96) * 256 + (slb << 4)) = pb6;
      *(uint4*)(Bs + (sr + 96) * 256 + (slb << 4) + 128) = pb7;
    }
    __syncthreads();
    if (c < 12) LOADP4(c + 1);
#pragma unroll
    for (int kk = 0; kk < 4; ++kk) {
      int kb = kk * 4 + l4;
      bf16x8 af[2], bv[2];
#pragma unroll
      for (int i = 0; i < 2; ++i) {
        int row = i * 16 + l15;
        af[i] = *(const bf16x8*)(As + row * 256 + (((kb & 8) | ((kb & 7) ^ (row & 7))) << 4));
      }
#pragma unroll
      for (int j = 0; j < 2; ++j) {
        int cidx = wave * 32 + j * 16 + l15;
        bv[j] = *(const bf16x8*)(Bs + cidx * 256 + (((kb & 8) | ((kb & 7) ^ (cidx & 7))) << 4));
      }
#pragma unroll
      for (int i = 0; i < 2; ++i)
#pragma unroll
        for (int j = 0; j < 2; ++j)
          acc[i][j] = __builtin_amdgcn_mfma_f32_16x16x32_bf16(af[i], bv[j], acc[i][j], 0, 0, 0);
    }
    __syncthreads();
  }

#pragma unroll
  for (int i = 0; i < 2; ++i) {
#pragma unroll
    for (int j = 0; j < 2; ++j) {
      int cidx = wave * 32 + j * 16 + l15;
#pragma unroll
      for (int q = 0; q < 4; ++q)
        Ps[(i * 16 + l4 * 4 + q) * 132 + cidx] = acc[i][j][q];
    }
  }
  __syncthreads();

  float v0_, v1_, v2_, v3_, v4_;
  int r0_, r1_, r2_, r3_, r4_, f0_, f1_, f2_, f3_, f4_;
#define EPI(t_, vv_, rr_, ff_) do {                                           \
    int idx_ = tid + (t_) * 256;                                              \
    rr_ = idx_ / 40; ff_ = idx_ - rr_ * 40;                                   \
    int n_ = n0 + rr_, zc_ = y * 40 + ff_;                                    \
    float v_ = 0.f;                                                           \
    if (n_ < NN && zc_ < 75) {                                                \
      v_ = Ps[rr_ * 132 + ff_] + sclS[rr_] * Ps[rr_ * 132 + 40 + ff_]         \
         + isclS[rr_] * Ps[rr_ * 132 + 80 + ff_] + zb[zc_];                   \
      z[n_ * 75 + zc_] = v_;                                                  \
    }                                                                         \
    vv_ = v_;                                                                 \
  } while (0)
  EPI(0, v0_, r0_, f0_); EPI(1, v1_, r1_, f1_); EPI(2, v2_, r2_, f2_);
  EPI(3, v3_, r3_, f3_); EPI(4, v4_, r4_, f4_);
#undef EPI
  __syncthreads();
  Ps[r0_ * 132 + f0_] = v0_;
  Ps[r1_ * 132 + f1_] = v1_;
  Ps[r2_ * 132 + f2_] = v2_;
  Ps[r3_ * 132 + f3_] = v3_;
  Ps[r4_ * 132 + f4_] = v4_;
  __syncthreads();
  if (tid < 40) {
    int zc = y * 40 + tid;
    if (zc < 75) {
      float s = 0.f, s2 = 0.f;
#pragma unroll
      for (int r = 0; r < 32; ++r) {
        float v = Ps[r * 132 + tid];
        s += v; s2 += v * v;
      }
      atomicAdd(&stat_raw_l[zc], s);
      atomicAdd(&stat_raw_l[75 + zc], s2);
    }
  }
}

// bnapply; on last layer (outF != null) also fused global_add_pool via atomics
__global__ __launch_bounds__(256) void k_bnapply(const float* __restrict__ z,
    const float* __restrict__ stat_raw, const float* __restrict__ g, const float* __restrict__ b,
    float* __restrict__ outF, bf16* __restrict__ hbf,
    const int* __restrict__ batch, float* __restrict__ gpool) {
  int idx = blockIdx.x * 256 + threadIdx.x;
  if (idx >= NN * FD) return;
  int n = idx / FD, f = idx - n * FD;
  float mu = stat_raw[f] * (1.f / NN);
  float var = stat_raw[75 + f] * (1.f / NN) - mu * mu;
  var = fmaxf(var, 0.f);
  float rs = 1.f / sqrtf(var + 1e-5f);
  float v = (z[idx] - mu) * rs * g[f] + b[f];
  v = fmaxf(v, 0.f);
  if (outF) {
    outF[idx] = v;
    atomicAdd(&gpool[batch[n] * FD + f], v);
  }
  hbf[n * 80 + f] = (bf16)v;
}

// parallel MLP head: one block per graph, 128 threads
__global__ __launch_bounds__(128) void k_mlp2(const float* __restrict__ gpool,
    const float* __restrict__ w1, const float* __restrict__ b1,
    const float* __restrict__ w2, const float* __restrict__ b2,
    const float* __restrict__ w3, const float* __restrict__ b3,
    float* __restrict__ out) {
  __shared__ float G[75];
  __shared__ float H1[50];
  __shared__ float H2[25];
  const int gr = blockIdx.x;
  const int tid = threadIdx.x;
  if (tid < 75) G[tid] = gpool[gr * FD + tid];
  __syncthreads();
  if (tid < 50) {
    float a = b1[tid];
    for (int k = 0; k < 75; ++k) a += G[k] * w1[k * 50 + tid];
    H1[tid] = fmaxf(a, 0.f);
  }
  __syncthreads();
  if (tid < 25) {
    float a = b2[tid];
    for (int k = 0; k < 50; ++k) a += H1[k] * w2[k * 25 + tid];
    H2[tid] = fmaxf(a, 0.f);
  }
  __syncthreads();
  if (tid == 0) {
    float a = b3[0];
    for (int k = 0; k < 25; ++k) a += H2[k] * w3[k];
    out[gr] = a;
  }
}

// ---------------------------------------------------------------- host

extern "C" void kernel_launch(void* const* d_in, const int* in_sizes, int n_in,
                              void* d_out, int out_size, void* d_ws, size_t ws_size,
                              hipStream_t stream) {
  (void)in_sizes; (void)n_in; (void)out_size; (void)ws_size;
  const float* x      = (const float*)d_in[0];
  const int*   eidx   = (const int*)  d_in[1];
  const float* eattr  = (const float*)d_in[2];
  const int*   batch  = (const int*)  d_in[3];
  const float* nw     = (const float*)d_in[4];
  const float* nb     = (const float*)d_in[5];
  const float* ew     = (const float*)d_in[6];
  const float* ebias  = (const float*)d_in[7];
  const float* ee_w   = (const float*)d_in[8];
  const float* ee_b   = (const float*)d_in[9];
  const float* pre_w  = (const float*)d_in[10];
  const float* pre_b  = (const float*)d_in[11];
  const float* post_w = (const float*)d_in[12];
  const float* post_b = (const float*)d_in[13];
  const float* lin_w  = (const float*)d_in[14];
  const float* lin_b  = (const float*)d_in[15];
  const float* bn_g   = (const float*)d_in[16];
  const float* bn_b   = (const float*)d_in[17];
  const float* w1 = (const float*)d_in[18];
  const float* b1 = (const float*)d_in[19];
  const float* w2 = (const float*)d_in[20];
  const float* b2 = (const float*)d_in[21];
  const float* w3 = (const float*)d_in[22];
  const float* b3 = (const float*)d_in[23];

  const int* srcA = eidx;
  const int* dstA = eidx + NE;

  char* base = (char*)d_ws;
  size_t off = 0;
  auto alloc = [&](size_t bytes) -> char* {
    char* p = base + off;
    off = (off + bytes + 255) & ~(size_t)255;
    return p;
  };
  bf16*  hbf    = (bf16*) alloc((size_t)NN * 80 * 2);
  bf16*  eabf4  = (bf16*) alloc((size_t)NE * 8 * 2 + 64);
  bf16*  aggbf2 = (bf16*) alloc((size_t)NN * 1536 * 2);
  float* z      = (float*)alloc((size_t)NN * FD * 4);
  bf16*  WctA   = (bf16*) alloc((size_t)NLAY * 384 * 192 * 2);
  float* bcA    = (float*)alloc((size_t)NLAY * 384 * 4);
  bf16*  Wct2A  = (bf16*) alloc((size_t)NLAY * 256 * 1664 * 2);
  float* zbA    = (float*)alloc((size_t)NLAY * 80 * 4);
  float* PLA    = (float*)alloc((size_t)NLAY * 5 * 975 * 80 * 4);
  float* W12A   = (float*)alloc((size_t)NLAY * 300 * 4);
  float* bcombA = (float*)alloc((size_t)NLAY * 80 * 4);
  float* scl    = (float*)alloc(NN * 4);
  float* iscl   = (float*)alloc(NN * 4);
  int*   deg    = (int*)alloc(NN * 4);
  int*   rowptr = (int*)alloc((NN + 1) * 4);
  int*   cursor = (int*)alloc(NN * 4);
  int*   eids   = (int*)alloc(NE * 4);
  int*   nxt    = (int*)alloc(NN * 4);
  int*   bstart = (int*)alloc((MAXB + 1) * 4);
  int*   nblk   = (int*)alloc(16);
  float* stat_all = (float*)alloc((size_t)NLAY * 160 * 4);
  float* gpool  = (float*)alloc(NGR * FD * 4);
  bf16*  zerobuf = (bf16*)alloc(256);

  const unsigned eoff_base = (unsigned)((char*)eabf4 - (char*)hbf);

  static const int DEG_TAB[71] = {1, 72, 201, 816, 1790, 3756, 6923, 12768, 20286, 31710,
    51623, 82296, 124280, 177576, 251115, 326064, 395760, 456840, 506179, 516200, 507003,
    493746, 489256, 453936, 420025, 411320, 427761, 420700, 420500, 426780, 414284, 407008,
    394053, 360910, 322245, 313704, 282902, 270940, 237783, 209000, 193766, 177870, 162110,
    144848, 121230, 112700, 93483, 88512, 72275, 80700, 68799, 56784, 42665, 30996, 25630,
    12936, 9804, 8584, 5251, 3480, 3111, 2728, 1890, 1472, 1235, 330, 201, 68, 69, 0, 71};
  double num = 0.0, den = 0.0;
  for (int i = 0; i < 71; ++i) { num += log((double)i + 1.0) * DEG_TAB[i]; den += DEG_TAB[i]; }
  float inv_avg_log = (float)(den / num);

  hipMemsetAsync(deg, 0, NN * 4, stream);
  hipMemsetAsync(cursor, 0, NN * 4, stream);
  hipMemsetAsync(gpool, 0, NGR * FD * 4, stream);
  hipMemsetAsync(stat_all, 0, (size_t)NLAY * 160 * 4, stream);
  hipMemsetAsync(zerobuf, 0, 256, stream);

  // graph prep
  k_node_emb<<<(NN * FD + 255) / 256, 256, 0, stream>>>(x, nw, nb, hbf);
  k_hpad<<<(NN * 5 + 255) / 256, 256, 0, stream>>>(hbf);
  k_edge4<<<(NE * 8 + 255) / 256, 256, 0, stream>>>(eattr, eabf4);
  k_count<<<(NE + 255) / 256, 256, 0, stream>>>(dstA, deg);
  k_scan<<<1, 1024, 0, stream>>>(deg, rowptr);
  k_scl<<<(NN + 255) / 256, 256, 0, stream>>>(deg, scl, iscl, inv_avg_log);
  k_scatter<<<(NE + 255) / 256, 256, 0, stream>>>(dstA, rowptr, cursor, eids);
  k_next<<<(NN + 255) / 256, 256, 0, stream>>>(rowptr, nxt);
  k_walk<<<1, 1024, 0, stream>>>(nxt, bstart, nblk);

  // weight prep, all layers batched
  {
    dim3 gw(2, NLAY);
    k_W12<<<gw, 256, 0, stream>>>(ew, ebias, ee_w, ee_b, W12A, bcombA);
    dim3 gc((384 * 192 + 255) / 256, NLAY);
    k_combine<<<gc, 256, 0, stream>>>(pre_w, pre_b, W12A, bcombA, WctA, bcA);
    dim3 gp((5 * 975 * 80 + 255) / 256, NLAY);
    k_PL<<<gp, 256, 0, stream>>>(post_w, lin_w, PLA);
    dim3 g2((256 * 1664 + 255) / 256, NLAY);
    k_combine2b<<<g2, 256, 0, stream>>>(PLA, Wct2A);
    dim3 gz(1, NLAY);
    k_zbias<<<gz, 128, 0, stream>>>(post_b, lin_w, lin_b, zbA);
  }

  float* outp = (float*)d_out;
  for (int l = 0; l < NLAY; ++l) {
    dim3 gpref(MAXB, 3);
    k_pre_fused<<<gpref, 256, 0, stream>>>(hbf, eids, srcA, dstA, rowptr, bstart, nblk,
        WctA + (size_t)l * 384 * 192, bcA + (size_t)l * 384, aggbf2, eoff_base);
    dim3 gpost((NN + 31) / 32, 2);
    k_post4<<<gpost, 256, 0, stream>>>(hbf, aggbf2, Wct2A + (size_t)l * 256 * 1664,
        zbA + (size_t)l * 80, scl, iscl, zerobuf, z, stat_all + (size_t)l * 160);
    float* wdst = (l == NLAY - 1) ? (outp + NGR) : nullptr;
    k_bnapply<<<(NN * FD + 255) / 256, 256, 0, stream>>>(z, stat_all + (size_t)l * 160,
        bn_g + (size_t)l * FD, bn_b + (size_t)l * FD, wdst, hbf, batch, gpool);
  }

  k_mlp2<<<NGR, 128, 0, stream>>>(gpool, w1, b1, w2, b2, w3, b3, outp);
}

// Round 21
// 489.169 us; speedup vs baseline: 1.2061x; 1.0066x over previous
//
#include <hip/hip_runtime.h>
#include <math.h>

#define NN 10000
#define NE 100000
#define NGR 64
#define NT 5
#define FD 75
#define FOUT 15
#define NLAY 4
#define MAXB 1792

typedef __bf16 bf16;
typedef __bf16 bf16x8 __attribute__((ext_vector_type(8)));
typedef float f32x4 __attribute__((ext_vector_type(4)));

__device__ inline unsigned pk2(float a, float b) {
  bf16 x = (bf16)a, y = (bf16)b;
  unsigned short ux, uy;
  __builtin_memcpy(&ux, &x, 2); __builtin_memcpy(&uy, &y, 2);
  return (unsigned)ux | ((unsigned)uy << 16);
}

// ---------------------------------------------------------------- small prep

// node embedding + pad columns in one pass (grid NN*80)
__global__ __launch_bounds__(256) void k_node_emb(const float* __restrict__ x,
    const float* __restrict__ w, const float* __restrict__ b, bf16* __restrict__ hbf) {
  int idx = blockIdx.x * 256 + threadIdx.x;
  if (idx >= NN * 80) return;
  int n = idx / 80, f = idx - n * 80;
  float acc = 0.f;
  if (f < 75) {
    acc = b[f];
#pragma unroll
    for (int k = 0; k < 14; ++k) acc += x[n * 14 + k] * w[k * FD + f];
  }
  hbf[idx] = (bf16)acc;
}

__global__ __launch_bounds__(256) void k_edge4(const float* __restrict__ eattr,
    bf16* __restrict__ eabf4) {
  int idx = blockIdx.x * 256 + threadIdx.x;
  if (idx >= NE * 8) return;
  int e = idx >> 3, c = idx & 7;
  eabf4[idx] = (c < 4) ? (bf16)eattr[e * 4 + c] : (bf16)0.f;
}

__global__ __launch_bounds__(256) void k_count(const int* __restrict__ dst, int* __restrict__ deg) {
  int e = blockIdx.x * 256 + threadIdx.x;
  if (e < NE) atomicAdd(&deg[dst[e]], 1);
}

__global__ __launch_bounds__(1024) void k_scan(const int* __restrict__ deg, int* __restrict__ rowptr) {
  __shared__ int buf[1024];
  __shared__ int carry;
  int tid = threadIdx.x;
  if (tid == 0) carry = 0;
  __syncthreads();
  for (int base = 0; base < NN; base += 1024) {
    int i = base + tid;
    int v = (i < NN) ? deg[i] : 0;
    buf[tid] = v;
    __syncthreads();
    for (int off = 1; off < 1024; off <<= 1) {
      int t = (tid >= off) ? buf[tid - off] : 0;
      __syncthreads();
      buf[tid] += t;
      __syncthreads();
    }
    int inc = buf[tid];
    int tot = buf[1023];
    if (i < NN) rowptr[i + 1] = carry + inc;
    __syncthreads();
    if (tid == 0) carry += tot;
    __syncthreads();
  }
  if (tid == 0) rowptr[0] = 0;
}

__global__ __launch_bounds__(256) void k_scatter(const int* __restrict__ dst, const int* __restrict__ rowptr,
    int* __restrict__ cursor, int* __restrict__ eids) {
  int e = blockIdx.x * 256 + threadIdx.x;
  if (e >= NE) return;
  int d = dst[e];
  int pos = rowptr[d] + atomicAdd(&cursor[d], 1);
  eids[pos] = e;
}

// next[n] + scl/iscl in one pass (deg = rowptr diff)
__global__ __launch_bounds__(256) void k_next(const int* __restrict__ rowptr, int* __restrict__ nxt,
    float* __restrict__ scl, float* __restrict__ iscl, float inv_avg_log) {
  int n = blockIdx.x * 256 + threadIdx.x;
  if (n >= NN) return;
  int base = rowptr[n];
  int lo = n + 1, hi = min(n + 128, NN);
  while (lo < hi) {
    int mid = (lo + hi + 1) >> 1;
    if (rowptr[mid] - base <= 128) lo = mid; else hi = mid - 1;
  }
  nxt[n] = lo;
  float c1 = fmaxf((float)(rowptr[n + 1] - base), 1.f);
  float s = logf(c1 + 1.f) * inv_avg_log;
  scl[n] = s;
  iscl[n] = 1.f / s;
}

__global__ __launch_bounds__(1024) void k_walk(const int* __restrict__ nxt,
    int* __restrict__ bstart, int* __restrict__ nblk) {
  __shared__ int lnx[NN];
  int tid = threadIdx.x;
  for (int i = tid; i < NN; i += 1024) lnx[i] = nxt[i];
  __syncthreads();
  if (tid == 0) {
    int b = 0, n = 0;
    while (n < NN && b < MAXB) { bstart[b++] = n; n = lnx[n]; }
    bstart[b] = NN;
    nblk[0] = b;
  }
}

// ---------------------------------------------------------------- weight prep (batched across layers)

__global__ __launch_bounds__(256) void k_W12(const float* __restrict__ ew,
    const float* __restrict__ ebias, const float* __restrict__ ee_wA, const float* __restrict__ ee_bA,
    float* __restrict__ W12A, float* __restrict__ bcombA) {
  const int l = blockIdx.y;
  const float* ee_w = ee_wA + (size_t)l * 50 * FD;
  const float* ee_b = ee_bA + (size_t)l * FD;
  int idx = blockIdx.x * 256 + threadIdx.x;
  if (idx >= 375) return;
  if (idx < 300) {
    int d = idx / 75, o = idx - d * 75;
    float v = 0.f;
    for (int j = 0; j < 50; ++j) v += ew[d * 50 + j] * ee_w[j * 75 + o];
    W12A[(size_t)l * 300 + idx] = v;
  } else {
    int o = idx - 300;
    float v = ee_b[o];
    for (int j = 0; j < 50; ++j) v += ebias[j] * ee_w[j * 75 + o];
    bcombA[(size_t)l * 80 + o] = v;
  }
}

__global__ __launch_bounds__(256) void k_combine(const float* __restrict__ pre_wA,
    const float* __restrict__ pre_bA, const float* __restrict__ W12A, const float* __restrict__ bcombA,
    bf16* __restrict__ WctA, float* __restrict__ bcA) {
  const int l = blockIdx.y;
  const float* pre_w = pre_wA + (size_t)l * NT * 225 * FD;
  const float* pre_b = pre_bA + (size_t)l * NT * FD;
  const float* W12   = W12A + (size_t)l * 300;
  const float* bcomb = bcombA + (size_t)l * 80;
  bf16* Wct = WctA + (size_t)l * 384 * 192;
  float* bc = bcA + (size_t)l * 384;
  int idx = blockIdx.x * 256 + threadIdx.x;
  if (idx >= 384 * 192) return;
  int c = idx / 192, s = idx - c * 192;
  int t = c / 75, g = c - t * 75;
  int chunk = s >> 6, within = s & 63, sblk = within >> 3, elem = within & 7;
  int lb = sblk ^ (c & 7);
  int k = chunk * 64 + lb * 8 + elem;
  float v = 0.f;
  if (c < 375) {
    if (k < 75)                    v = pre_w[(t * 225 + k) * 75 + g];
    else if (k >= 80 && k < 155)   v = pre_w[(t * 225 + 75 + (k - 80)) * 75 + g];
    else if (k >= 160 && k < 164) {
      int d = k - 160;
      float a = 0.f;
      for (int f2 = 0; f2 < 75; ++f2) a += W12[d * 75 + f2] * pre_w[(t * 225 + 150 + f2) * 75 + g];
      v = a;
    }
  }
  Wct[c * 192 + s] = (bf16)v;
  if (s == 0) {
    float a = 0.f;
    if (c < 375) {
      a = pre_b[t * 75 + g];
      for (int f2 = 0; f2 < 75; ++f2) a += bcomb[f2] * pre_w[(t * 225 + 150 + f2) * 75 + g];
    }
    bc[c] = a;
  }
}

__global__ __launch_bounds__(256) void k_PL(const float* __restrict__ pwA,
    const float* __restrict__ lwA, float* __restrict__ PLA) {
  const int l = blockIdx.y;
  const float* pw = pwA + (size_t)l * NT * 975 * FOUT;
  const float* lw = lwA + (size_t)l * FD * FD;
  float* PL = PLA + (size_t)l * 5 * 975 * 80;
  int idx = blockIdx.x * 256 + threadIdx.x;
  if (idx >= 5 * 975 * 80) return;
  int t = idx / (975 * 80), rem = idx - t * 975 * 80;
  int row = rem / 80, o = rem - row * 80;
  float v = 0.f;
  if (o < 75) {
#pragma unroll
    for (int j = 0; j < 15; ++j)
      v += pw[((size_t)t * 975 + row) * 15 + j] * lw[(t * 15 + j) * 75 + o];
  }
  PL[idx] = v;
}

__global__ __launch_bounds__(256) void k_combine2b(const float* __restrict__ PLA,
    bf16* __restrict__ Wct2A) {
  const int l = blockIdx.y;
  const float* PL = PLA + (size_t)l * 5 * 975 * 80;
  bf16* Wct2 = Wct2A + (size_t)l * 256 * 1664;
  int idx = blockIdx.x * 256 + threadIdx.x;
  if (idx >= 256 * 1664) return;
  int c = idx / 1664, s = idx - c * 1664;
  int chunk = s >> 6, within = s & 63, sblk = within >> 3, elem = within & 7;
  int lb = sblk ^ (c & 7);
  int k = chunk * 64 + lb * 8 + elem;
  int g2 = c / 80, o = c - g2 * 80;
  float val = 0.f;
  if (c < 240 && o < 75) {
    if (k < 75) {
      if (g2 == 0) {
#pragma unroll
        for (int t = 0; t < 5; ++t) val += PL[(t * 975 + k) * 80 + o];
      }
    } else if (k >= 80 && k < 1616) {
      int q = k - 80;
      int si = q / 384, cc = q - si * 384;
      if (cc < 375) {
        int t = cc / 75, g = cc - t * 75;
        int row = 75 + g2 * 300 + si * 75 + g;
        val = PL[((size_t)t * 975 + row) * 80 + o];
      }
    }
  }
  Wct2[(size_t)c * 1664 + s] = (bf16)val;
}

__global__ __launch_bounds__(128) void k_zbias(const float* __restrict__ pbA,
    const float* __restrict__ lwA, const float* __restrict__ lbA, float* __restrict__ zbA) {
  const int l = blockIdx.y;
  const float* pb = pbA + (size_t)l * NT * FOUT;
  const float* lw = lwA + (size_t)l * FD * FD;
  const float* lb = lbA + (size_t)l * FD;
  float* zb = zbA + (size_t)l * 80;
  int o = threadIdx.x;
  if (o >= 80) return;
  float val = 0.f;
  if (o < 75) {
    val = lb[o];
    for (int t = 0; t < 5; ++t)
      for (int j = 0; j < 15; ++j)
        val += pb[t * 15 + j] * lw[(t * 15 + j) * 75 + o];
  }
  zb[o] = val;
}

// ---------------------------------------------------------------- fused pre-GEMM + aggregation
// A-operand DIRECT from global; B double-buffered in LDS. 6 barriers. K=192.

#define LOADB(ntb_, c_) do {                                                      \
    const bf16* wp_ = Wct + (size_t)((ntb_) + sr) * 192 + (c_) * 64 + slb * 8;    \
    pq0 = *(const uint4*)(wp_ + 0 * 6144);                                        \
    pq1 = *(const uint4*)(wp_ + 1 * 6144);                                        \
    pq2 = *(const uint4*)(wp_ + 2 * 6144);                                        \
    pq3 = *(const uint4*)(wp_ + 3 * 6144); } while (0)

#define STOREB(BS_) do {                                          \
    *(uint4*)((BS_) + (0 * 32 + sr) * 128 + (slb << 4)) = pq0;    \
    *(uint4*)((BS_) + (1 * 32 + sr) * 128 + (slb << 4)) = pq1;    \
    *(uint4*)((BS_) + (2 * 32 + sr) * 128 + (slb << 4)) = pq2;    \
    *(uint4*)((BS_) + (3 * 32 + sr) * 128 + (slb << 4)) = pq3; } while (0)

#define DO_KK(BS_, KB_, A0_, A1_, A2_, A3_) do {                         \
    bf16x8 af0 = *(const bf16x8*)(A0_);                                  \
    bf16x8 af1 = *(const bf16x8*)(A1_);                                  \
    bf16x8 af2 = *(const bf16x8*)(A2_);                                  \
    bf16x8 af3 = *(const bf16x8*)(A3_);                                  \
    const unsigned char* bp_ = (BS_) + (((KB_) ^ (l15 & 7)) << 4) + wc * 8192 + l15 * 128; \
    bf16x8 bv0 = *(const bf16x8*)(bp_ + 0 * 2048);                       \
    bf16x8 bv1 = *(const bf16x8*)(bp_ + 1 * 2048);                       \
    bf16x8 bv2 = *(const bf16x8*)(bp_ + 2 * 2048);                       \
    bf16x8 bv3 = *(const bf16x8*)(bp_ + 3 * 2048);                       \
    acc[0][0] = __builtin_amdgcn_mfma_f32_16x16x32_bf16(af0, bv0, acc[0][0], 0, 0, 0); \
    acc[1][0] = __builtin_amdgcn_mfma_f32_16x16x32_bf16(af1, bv0, acc[1][0], 0, 0, 0); \
    acc[2][0] = __builtin_amdgcn_mfma_f32_16x16x32_bf16(af2, bv0, acc[2][0], 0, 0, 0); \
    acc[3][0] = __builtin_amdgcn_mfma_f32_16x16x32_bf16(af3, bv0, acc[3][0], 0, 0, 0); \
    acc[0][1] = __builtin_amdgcn_mfma_f32_16x16x32_bf16(af0, bv1, acc[0][1], 0, 0, 0); \
    acc[1][1] = __builtin_amdgcn_mfma_f32_16x16x32_bf16(af1, bv1, acc[1][1], 0, 0, 0); \
    acc[2][1] = __builtin_amdgcn_mfma_f32_16x16x32_bf16(af2, bv1, acc[2][1], 0, 0, 0); \
    acc[3][1] = __builtin_amdgcn_mfma_f32_16x16x32_bf16(af3, bv1, acc[3][1], 0, 0, 0); \
    acc[0][2] = __builtin_amdgcn_mfma_f32_16x16x32_bf16(af0, bv2, acc[0][2], 0, 0, 0); \
    acc[1][2] = __builtin_amdgcn_mfma_f32_16x16x32_bf16(af1, bv2, acc[1][2], 0, 0, 0); \
    acc[2][2] = __builtin_amdgcn_mfma_f32_16x16x32_bf16(af2, bv2, acc[2][2], 0, 0, 0); \
    acc[3][2] = __builtin_amdgcn_mfma_f32_16x16x32_bf16(af3, bv2, acc[3][2], 0, 0, 0); \
    acc[0][3] = __builtin_amdgcn_mfma_f32_16x16x32_bf16(af0, bv3, acc[0][3], 0, 0, 0); \
    acc[1][3] = __builtin_amdgcn_mfma_f32_16x16x32_bf16(af1, bv3, acc[1][3], 0, 0, 0); \
    acc[2][3] = __builtin_amdgcn_mfma_f32_16x16x32_bf16(af2, bv3, acc[2][3], 0, 0, 0); \
    acc[3][3] = __builtin_amdgcn_mfma_f32_16x16x32_bf16(af3, bv3, acc[3][3], 0, 0, 0); \
  } while (0)

__global__ __launch_bounds__(256) void k_pre_fused(
    const bf16* __restrict__ hbf, const int* __restrict__ eids,
    const int* __restrict__ srcA, const int* __restrict__ dstA,
    const int* __restrict__ rowptr, const int* __restrict__ bstart, const int* __restrict__ nblk,
    const bf16* __restrict__ Wct, const float* __restrict__ bc,
    bf16* __restrict__ aggbf2, unsigned eoff_base) {
  __shared__ __align__(16) unsigned char smem[33792];   // Bs dbuf 32K; m_lds overlays
  unsigned char* Bs0 = smem;
  unsigned char* Bs1 = smem + 16384;
  bf16* m_lds = (bf16*)smem;                             // [128][132] bf16
  __shared__ unsigned dOffL[128], sOffL[128], eOffL[128];
  __shared__ int nodeRows[129];
  __shared__ int nq[5];

  const int b = blockIdx.x;
  if (b >= nblk[0]) return;
  const int ntb = blockIdx.y * 128;
  const int tid = threadIdx.x;
  const int n0b = bstart[b], n1b = bstart[b + 1];
  const int rbase = rowptr[n0b];
  const int nrows = rowptr[n1b] - rbase;     // <= 128
  const int nnod = n1b - n0b;                // <= 128

  if (tid == 0) { nq[0] = 0; nq[1] = 0; nq[2] = 0; nq[3] = 0; nq[4] = nnod; }
  if (tid < 128) {
    int e = (tid < nrows) ? eids[rbase + tid] : 0;
    dOffL[tid] = (unsigned)(dstA[e] * 160);
    sOffL[tid] = (unsigned)(srcA[e] * 160);
    eOffL[tid] = eoff_base + (unsigned)(e * 16);
  }
  if (tid <= nnod) nodeRows[tid] = rowptr[n0b + tid] - rbase;
  __syncthreads();
  if (tid < nnod) {
#pragma unroll
    for (int q = 1; q <= 3; ++q) {
      int target = (nrows * q) >> 2;
      if (nodeRows[tid] < target && nodeRows[tid + 1] >= target) nq[q] = tid + 1;
    }
  }

  const int lane = tid & 63;
  const int wave = tid >> 6;
  const int wr = wave >> 1, wc = wave & 1;
  const int l15 = lane & 15, l4 = lane >> 4;
  const int sr = tid >> 3, slb = tid & 7;

  const unsigned char* hb = (const unsigned char*)hbf;
  const int ar = wr * 64 + l15;
  const unsigned dof0 = dOffL[ar], dof1 = dOffL[ar + 16], dof2 = dOffL[ar + 32], dof3 = dOffL[ar + 48];
  const unsigned sof0 = sOffL[ar], sof1 = sOffL[ar + 16], sof2 = sOffL[ar + 32], sof3 = sOffL[ar + 48];
  const unsigned eof0 = eOffL[ar], eof1 = eOffL[ar + 16], eof2 = eOffL[ar + 32], eof3 = eOffL[ar + 48];

  f32x4 acc[4][4];
  f32x4 zv = {0.f, 0.f, 0.f, 0.f};
#pragma unroll
  for (int i = 0; i < 4; ++i)
#pragma unroll
    for (int j = 0; j < 4; ++j) acc[i][j] = zv;

  uint4 pq0, pq1, pq2, pq3;
  LOADB(ntb, 0);

  // ---- chunk 0: A = dst elems [0,64)
  STOREB(Bs0);
  __syncthreads();
  LOADB(ntb, 1);
  DO_KK(Bs0, l4,     hb + dof0 + l4 * 16, hb + dof1 + l4 * 16, hb + dof2 + l4 * 16, hb + dof3 + l4 * 16);
  DO_KK(Bs0, 4 + l4, hb + dof0 + 64 + l4 * 16, hb + dof1 + 64 + l4 * 16, hb + dof2 + 64 + l4 * 16, hb + dof3 + 64 + l4 * 16);

  // ---- chunk 1: A = dst tail [64,80) | src [0,48)
  STOREB(Bs1);
  __syncthreads();
  LOADB(ntb, 2);
  {
    unsigned o0 = (l4 < 2) ? (dof0 + 128 + l4 * 16) : (sof0 + (l4 - 2) * 16);
    unsigned o1 = (l4 < 2) ? (dof1 + 128 + l4 * 16) : (sof1 + (l4 - 2) * 16);
    unsigned o2 = (l4 < 2) ? (dof2 + 128 + l4 * 16) : (sof2 + (l4 - 2) * 16);
    unsigned o3 = (l4 < 2) ? (dof3 + 128 + l4 * 16) : (sof3 + (l4 - 2) * 16);
    DO_KK(Bs1, l4, hb + o0, hb + o1, hb + o2, hb + o3);
  }
  DO_KK(Bs1, 4 + l4, hb + sof0 + 32 + l4 * 16, hb + sof1 + 32 + l4 * 16, hb + sof2 + 32 + l4 * 16, hb + sof3 + 32 + l4 * 16);

  // ---- chunk 2: A = src tail [48,80) | eattr4
  STOREB(Bs0);
  __syncthreads();
  DO_KK(Bs0, l4, hb + sof0 + 96 + l4 * 16, hb + sof1 + 96 + l4 * 16, hb + sof2 + 96 + l4 * 16, hb + sof3 + 96 + l4 * 16);
  DO_KK(Bs0, 4 + l4, hb + eof0 + l4 * 16, hb + eof1 + l4 * 16, hb + eof2 + l4 * 16, hb + eof3 + l4 * 16);
  __syncthreads();

  // bias + write tile into the overlay
  float bcv[4];
#pragma unroll
  for (int j = 0; j < 4; ++j) bcv[j] = bc[ntb + wc * 64 + j * 16 + l15];
#pragma unroll
  for (int i = 0; i < 4; ++i) {
    int R = wr * 64 + i * 16 + l4 * 4;
#pragma unroll
    for (int j = 0; j < 4; ++j) {
      int col = wc * 64 + j * 16 + l15;
#pragma unroll
      for (int q = 0; q < 4; ++q)
        m_lds[(R + q) * 132 + col] = (bf16)(acc[i][j][q] + bcv[j]);
    }
  }
  __syncthreads();

  // aggregate: thread = (col-pair 0..63, row-quartile 0..3); u32 reads = 2 bf16 cols
  {
    const int cp = tid & 63;
    const int qq = tid >> 6;
    const unsigned char* mb = (const unsigned char*)m_lds;
    for (int i = nq[qq]; i < nq[qq + 1]; ++i) {
      int ra = nodeRows[i], rb2 = nodeRows[i + 1];
      float s0 = 0.f, q0 = 0.f, a0 = INFINITY, b0 = -INFINITY;
      float s1 = 0.f, q1 = 0.f, a1 = INFINITY, b1 = -INFINITY;
      for (int r = ra; r < rb2; ++r) {
        unsigned u = *(const unsigned*)(mb + r * 264 + cp * 4);
        float v0 = __uint_as_float(u << 16);
        float v1 = __uint_as_float(u & 0xffff0000u);
        s0 += v0; q0 += v0 * v0; a0 = fminf(a0, v0); b0 = fmaxf(b0, v0);
        s1 += v1; q1 += v1 * v1; a1 = fminf(a1, v1); b1 = fmaxf(b1, v1);
      }
      int d = rb2 - ra;
      float inv = 1.f / ((d > 0) ? (float)d : 1.f);
      float m0 = s0 * inv, m1 = s1 * inv;
      float sd0 = sqrtf(fmaxf(q0 * inv - m0 * m0, 0.f) + 1e-5f);
      float sd1 = sqrtf(fmaxf(q1 * inv - m1 * m1, 0.f) + 1e-5f);
      if (d == 0) { a0 = 0.f; b0 = 0.f; a1 = 0.f; b1 = 0.f; }
      bf16* ag = aggbf2 + (size_t)(n0b + i) * 1536 + ntb + cp * 2;
      *(unsigned*)(ag)        = pk2(m0, m1);
      *(unsigned*)(ag + 384)  = pk2(a0, a1);
      *(unsigned*)(ag + 768)  = pk2(b0, b1);
      *(unsigned*)(ag + 1152) = pk2(sd0, sd1);
    }
  }
}

// ---------------------------------------------------------------- post GEMM + epilogue + BN stats
// staged A (one-chunk-ahead reg prefetch), 32-row tiles, grid (313,2).

#define APG_(g_) ((nA >= NN || (g_) >= 202) ? zerobuf : \
    ((g_) < 10 ? hbf + nA * 80 + (g_) * 8 : aggbf2 + (size_t)nA * 1536 + ((g_) - 10) * 8))

#define LOADP4(c_) do {                                                 \
    int gA_ = (c_) * 16 + slb;                                          \
    pa0 = *(const uint4*)APG_(gA_);                                     \
    pa1 = *(const uint4*)APG_(gA_ + 8);                                 \
    int ko_ = (c_) * 128 + slb * 8;                                     \
    pb0 = *(const uint4*)(pc0 + ko_);                                   \
    pb1 = *(const uint4*)(pc0 + ko_ + 64);                              \
    pb2 = *(const uint4*)(pc1 + ko_);                                   \
    pb3 = *(const uint4*)(pc1 + ko_ + 64);                              \
    pb4 = *(const uint4*)(pc2 + ko_);                                   \
    pb5 = *(const uint4*)(pc2 + ko_ + 64);                              \
    pb6 = *(const uint4*)(pc3 + ko_);                                   \
    pb7 = *(const uint4*)(pc3 + ko_ + 64);                              \
  } while (0)

__global__ __launch_bounds__(256) void k_post4(const bf16* __restrict__ hbf,
    const bf16* __restrict__ aggbf2, const bf16* __restrict__ Wct2,
    const float* __restrict__ zb, const float* __restrict__ scl, const float* __restrict__ iscl,
    const bf16* __restrict__ zerobuf, float* __restrict__ z, float* __restrict__ stat_raw_l) {
  __shared__ __align__(16) unsigned char smem[40960];   // As 8K + Bs 32K; Ps overlays
  unsigned char* As = smem;
  unsigned char* Bs = smem + 8192;
  float* Ps = (float*)smem;                             // [32][132] f32
  __shared__ float sclS[32], isclS[32];
  const int n0 = blockIdx.x * 32;
  const int y  = blockIdx.y;
  const int tid = threadIdx.x;
  const int lane = tid & 63, wave = tid >> 6;
  const int l15 = lane & 15, l4 = lane >> 4;
  const int sr = tid >> 3, slb = tid & 7;
  const int nA = n0 + sr;

  const bf16 *pc0, *pc1, *pc2, *pc3;
  {
    int c0 = sr, c1 = sr + 32, c2 = sr + 64, c3 = sr + 96;
    int l0 = (c0 / 40) * 80 + y * 40 + (c0 % 40);
    int l1 = (c1 / 40) * 80 + y * 40 + (c1 % 40);
    int l2 = (c2 / 40) * 80 + y * 40 + (c2 % 40);
    int l3 = (c3 < 120) ? ((c3 / 40) * 80 + y * 40 + (c3 % 40)) : 0;
    pc0 = Wct2 + (size_t)l0 * 1664;
    pc1 = Wct2 + (size_t)l1 * 1664;
    pc2 = Wct2 + (size_t)l2 * 1664;
    pc3 = Wct2 + (size_t)l3 * 1664;
  }
  if (tid < 32) {
    int n = n0 + tid;
    sclS[tid] = (n < NN) ? scl[n] : 0.f;
    isclS[tid] = (n < NN) ? iscl[n] : 0.f;
  }

  f32x4 acc[2][2];
  f32x4 zvv = {0.f, 0.f, 0.f, 0.f};
#pragma unroll
  for (int i = 0; i < 2; ++i)
#pragma unroll
    for (int j = 0; j < 2; ++j) acc[i][j] = zvv;

  uint4 pa0, pa1, pb0, pb1, pb2, pb3, pb4, pb5, pb6, pb7;
  LOADP4(0);
  for (int c = 0; c < 13; ++c) {
    {
      int s1_ = (slb ^ (sr & 7)) << 4;
      *(uint4*)(As + sr * 256 + s1_) = pa0;
      *(uint4*)(As + sr * 256 + s1_ + 128) = pa1;
      *(uint4*)(Bs + (sr)      * 256 + (slb << 4)) = pb0;
      *(uint4*)(Bs + (sr)      * 256 + (slb << 4) + 128) = pb1;
      *(uint4*)(Bs + (sr + 32) * 256 + (slb << 4)) = pb2;
      *(uint4*)(Bs + (sr + 32) * 256 + (slb << 4) + 128) = pb3;
      *(uint4*)(Bs + (sr + 64) * 256 + (slb << 4)) = pb4;
      *(uint4*)(Bs + (sr + 64) * 256 + (slb << 4) + 128) = pb5;
      *(uint4*)(Bs + (sr + 96) * 256 + (slb << 4)) = pb6;
      *(uint4*)(Bs + (sr + 96) * 256 + (slb << 4) + 128) = pb7;
    }
    __syncthreads();
    if (c < 12) LOADP4(c + 1);
#pragma unroll
    for (int kk = 0; kk < 4; ++kk) {
      int kb = kk * 4 + l4;
      bf16x8 af[2], bv[2];
#pragma unroll
      for (int i = 0; i < 2; ++i) {
        int row = i * 16 + l15;
        af[i] = *(const bf16x8*)(As + row * 256 + (((kb & 8) | ((kb & 7) ^ (row & 7))) << 4));
      }
#pragma unroll
      for (int j = 0; j < 2; ++j) {
        int cidx = wave * 32 + j * 16 + l15;
        bv[j] = *(const bf16x8*)(Bs + cidx * 256 + (((kb & 8) | ((kb & 7) ^ (cidx & 7))) << 4));
      }
#pragma unroll
      for (int i = 0; i < 2; ++i)
#pragma unroll
        for (int j = 0; j < 2; ++j)
          acc[i][j] = __builtin_amdgcn_mfma_f32_16x16x32_bf16(af[i], bv[j], acc[i][j], 0, 0, 0);
    }
    __syncthreads();
  }

#pragma unroll
  for (int i = 0; i < 2; ++i) {
#pragma unroll
    for (int j = 0; j < 2; ++j) {
      int cidx = wave * 32 + j * 16 + l15;
#pragma unroll
      for (int q = 0; q < 4; ++q)
        Ps[(i * 16 + l4 * 4 + q) * 132 + cidx] = acc[i][j][q];
    }
  }
  __syncthreads();

  float v0_, v1_, v2_, v3_, v4_;
  int r0_, r1_, r2_, r3_, r4_, f0_, f1_, f2_, f3_, f4_;
#define EPI(t_, vv_, rr_, ff_) do {                                           \
    int idx_ = tid + (t_) * 256;                                              \
    rr_ = idx_ / 40; ff_ = idx_ - rr_ * 40;                                   \
    int n_ = n0 + rr_, zc_ = y * 40 + ff_;                                    \
    float v_ = 0.f;                                                           \
    if (n_ < NN && zc_ < 75) {                                                \
      v_ = Ps[rr_ * 132 + ff_] + sclS[rr_] * Ps[rr_ * 132 + 40 + ff_]         \
         + isclS[rr_] * Ps[rr_ * 132 + 80 + ff_] + zb[zc_];                   \
      z[n_ * 75 + zc_] = v_;                                                  \
    }                                                                         \
    vv_ = v_;                                                                 \
  } while (0)
  EPI(0, v0_, r0_, f0_); EPI(1, v1_, r1_, f1_); EPI(2, v2_, r2_, f2_);
  EPI(3, v3_, r3_, f3_); EPI(4, v4_, r4_, f4_);
#undef EPI
  __syncthreads();
  Ps[r0_ * 132 + f0_] = v0_;
  Ps[r1_ * 132 + f1_] = v1_;
  Ps[r2_ * 132 + f2_] = v2_;
  Ps[r3_ * 132 + f3_] = v3_;
  Ps[r4_ * 132 + f4_] = v4_;
  __syncthreads();
  if (tid < 40) {
    int zc = y * 40 + tid;
    if (zc < 75) {
      float s = 0.f, s2 = 0.f;
#pragma unroll
      for (int r = 0; r < 32; ++r) {
        float v = Ps[r * 132 + tid];
        s += v; s2 += v * v;
      }
      atomicAdd(&stat_raw_l[zc], s);
      atomicAdd(&stat_raw_l[75 + zc], s2);
    }
  }
}

// bnapply, 4 elems/thread (float4 z read; float4 outF store); last layer fuses pool atomics
__global__ __launch_bounds__(256) void k_bnapply(const float* __restrict__ z,
    const float* __restrict__ stat_raw, const float* __restrict__ g, const float* __restrict__ b,
    float* __restrict__ outF, bf16* __restrict__ hbf,
    const int* __restrict__ batch, float* __restrict__ gpool) {
  int base = (blockIdx.x * 256 + threadIdx.x) * 4;
  if (base >= NN * FD) return;
  f32x4 zr = *(const f32x4*)(z + base);
  float vr[4];
#pragma unroll
  for (int t = 0; t < 4; ++t) {
    int idx = base + t;
    int n = idx / FD, f = idx - n * FD;
    float mu = stat_raw[f] * (1.f / NN);
    float var = stat_raw[75 + f] * (1.f / NN) - mu * mu;
    var = fmaxf(var, 0.f);
    float rs = 1.f / sqrtf(var + 1e-5f);
    float v = (zr[t] - mu) * rs * g[f] + b[f];
    v = fmaxf(v, 0.f);
    vr[t] = v;
    hbf[n * 80 + f] = (bf16)v;
    if (outF) atomicAdd(&gpool[batch[n] * FD + f], v);
  }
  if (outF) *(f32x4*)(outF + base) = *(f32x4*)vr;
}

// parallel MLP head: one block per graph, 128 threads
__global__ __launch_bounds__(128) void k_mlp2(const float* __restrict__ gpool,
    const float* __restrict__ w1, const float* __restrict__ b1,
    const float* __restrict__ w2, const float* __restrict__ b2,
    const float* __restrict__ w3, const float* __restrict__ b3,
    float* __restrict__ out) {
  __shared__ float G[75];
  __shared__ float H1[50];
  __shared__ float H2[25];
  const int gr = blockIdx.x;
  const int tid = threadIdx.x;
  if (tid < 75) G[tid] = gpool[gr * FD + tid];
  __syncthreads();
  if (tid < 50) {
    float a = b1[tid];
    for (int k = 0; k < 75; ++k) a += G[k] * w1[k * 50 + tid];
    H1[tid] = fmaxf(a, 0.f);
  }
  __syncthreads();
  if (tid < 25) {
    float a = b2[tid];
    for (int k = 0; k < 50; ++k) a += H1[k] * w2[k * 25 + tid];
    H2[tid] = fmaxf(a, 0.f);
  }
  __syncthreads();
  if (tid == 0) {
    float a = b3[0];
    for (int k = 0; k < 25; ++k) a += H2[k] * w3[k];
    out[gr] = a;
  }
}

// ---------------------------------------------------------------- host

extern "C" void kernel_launch(void* const* d_in, const int* in_sizes, int n_in,
                              void* d_out, int out_size, void* d_ws, size_t ws_size,
                              hipStream_t stream) {
  (void)in_sizes; (void)n_in; (void)out_size; (void)ws_size;
  const float* x      = (const float*)d_in[0];
  const int*   eidx   = (const int*)  d_in[1];
  const float* eattr  = (const float*)d_in[2];
  const int*   batch  = (const int*)  d_in[3];
  const float* nw     = (const float*)d_in[4];
  const float* nb     = (const float*)d_in[5];
  const float* ew     = (const float*)d_in[6];
  const float* ebias  = (const float*)d_in[7];
  const float* ee_w   = (const float*)d_in[8];
  const float* ee_b   = (const float*)d_in[9];
  const float* pre_w  = (const float*)d_in[10];
  const float* pre_b  = (const float*)d_in[11];
  const float* post_w = (const float*)d_in[12];
  const float* post_b = (const float*)d_in[13];
  const float* lin_w  = (const float*)d_in[14];
  const float* lin_b  = (const float*)d_in[15];
  const float* bn_g   = (const float*)d_in[16];
  const float* bn_b   = (const float*)d_in[17];
  const float* w1 = (const float*)d_in[18];
  const float* b1 = (const float*)d_in[19];
  const float* w2 = (const float*)d_in[20];
  const float* b2 = (const float*)d_in[21];
  const float* w3 = (const float*)d_in[22];
  const float* b3 = (const float*)d_in[23];

  const int* srcA = eidx;
  const int* dstA = eidx + NE;

  char* base = (char*)d_ws;
  size_t off = 0;
  auto alloc = [&](size_t bytes) -> char* {
    char* p = base + off;
    off = (off + bytes + 255) & ~(size_t)255;
    return p;
  };
  bf16*  hbf    = (bf16*) alloc((size_t)NN * 80 * 2);
  bf16*  eabf4  = (bf16*) alloc((size_t)NE * 8 * 2 + 64);
  bf16*  aggbf2 = (bf16*) alloc((size_t)NN * 1536 * 2);
  float* z      = (float*)alloc((size_t)NN * FD * 4 + 16);
  bf16*  WctA   = (bf16*) alloc((size_t)NLAY * 384 * 192 * 2);
  float* bcA    = (float*)alloc((size_t)NLAY * 384 * 4);
  bf16*  Wct2A  = (bf16*) alloc((size_t)NLAY * 256 * 1664 * 2);
  float* zbA    = (float*)alloc((size_t)NLAY * 80 * 4);
  float* PLA    = (float*)alloc((size_t)NLAY * 5 * 975 * 80 * 4);
  float* W12A   = (float*)alloc((size_t)NLAY * 300 * 4);
  float* bcombA = (float*)alloc((size_t)NLAY * 80 * 4);
  float* scl    = (float*)alloc(NN * 4);
  float* iscl   = (float*)alloc(NN * 4);
  int*   deg    = (int*)alloc(NN * 4);
  int*   rowptr = (int*)alloc((NN + 1) * 4);
  int*   cursor = (int*)alloc(NN * 4);
  int*   eids   = (int*)alloc(NE * 4);
  int*   nxt    = (int*)alloc(NN * 4);
  int*   bstart = (int*)alloc((MAXB + 1) * 4);
  int*   nblk   = (int*)alloc(16);
  float* stat_all = (float*)alloc((size_t)NLAY * 160 * 4);
  float* gpool  = (float*)alloc(NGR * FD * 4);
  bf16*  zerobuf = (bf16*)alloc(256);

  const unsigned eoff_base = (unsigned)((char*)eabf4 - (char*)hbf);

  static const int DEG_TAB[71] = {1, 72, 201, 816, 1790, 3756, 6923, 12768, 20286, 31710,
    51623, 82296, 124280, 177576, 251115, 326064, 395760, 456840, 506179, 516200, 507003,
    493746, 489256, 453936, 420025, 411320, 427761, 420700, 420500, 426780, 414284, 407008,
    394053, 360910, 322245, 313704, 282902, 270940, 237783, 209000, 193766, 177870, 162110,
    144848, 121230, 112700, 93483, 88512, 72275, 80700, 68799, 56784, 42665, 30996, 25630,
    12936, 9804, 8584, 5251, 3480, 3111, 2728, 1890, 1472, 1235, 330, 201, 68, 69, 0, 71};
  double num = 0.0, den = 0.0;
  for (int i = 0; i < 71; ++i) { num += log((double)i + 1.0) * DEG_TAB[i]; den += DEG_TAB[i]; }
  float inv_avg_log = (float)(den / num);

  hipMemsetAsync(deg, 0, NN * 4, stream);
  hipMemsetAsync(cursor, 0, NN * 4, stream);
  hipMemsetAsync(gpool, 0, NGR * FD * 4, stream);
  hipMemsetAsync(stat_all, 0, (size_t)NLAY * 160 * 4, stream);
  hipMemsetAsync(zerobuf, 0, 256, stream);

  // graph prep
  k_node_emb<<<(NN * 80 + 255) / 256, 256, 0, stream>>>(x, nw, nb, hbf);
  k_edge4<<<(NE * 8 + 255) / 256, 256, 0, stream>>>(eattr, eabf4);
  k_count<<<(NE + 255) / 256, 256, 0, stream>>>(dstA, deg);
  k_scan<<<1, 1024, 0, stream>>>(deg, rowptr);
  k_scatter<<<(NE + 255) / 256, 256, 0, stream>>>(dstA, rowptr, cursor, eids);
  k_next<<<(NN + 255) / 256, 256, 0, stream>>>(rowptr, nxt, scl, iscl, inv_avg_log);
  k_walk<<<1, 1024, 0, stream>>>(nxt, bstart, nblk);

  // weight prep, all layers batched
  {
    dim3 gw(2, NLAY);
    k_W12<<<gw, 256, 0, stream>>>(ew, ebias, ee_w, ee_b, W12A, bcombA);
    dim3 gc((384 * 192 + 255) / 256, NLAY);
    k_combine<<<gc, 256, 0, stream>>>(pre_w, pre_b, W12A, bcombA, WctA, bcA);
    dim3 gp((5 * 975 * 80 + 255) / 256, NLAY);
    k_PL<<<gp, 256, 0, stream>>>(post_w, lin_w, PLA);
    dim3 g2((256 * 1664 + 255) / 256, NLAY);
    k_combine2b<<<g2, 256, 0, stream>>>(PLA, Wct2A);
    dim3 gz(1, NLAY);
    k_zbias<<<gz, 128, 0, stream>>>(post_b, lin_w, lin_b, zbA);
  }

  float* outp = (float*)d_out;
  for (int l = 0; l < NLAY; ++l) {
    dim3 gpref(MAXB, 3);
    k_pre_fused<<<gpref, 256, 0, stream>>>(hbf, eids, srcA, dstA, rowptr, bstart, nblk,
        WctA + (size_t)l * 384 * 192, bcA + (size_t)l * 384, aggbf2, eoff_base);
    dim3 gpost((NN + 31) / 32, 2);
    k_post4<<<gpost, 256, 0, stream>>>(hbf, aggbf2, Wct2A + (size_t)l * 256 * 1664,
        zbA + (size_t)l * 80, scl, iscl, zerobuf, z, stat_all + (size_t)l * 160);
    float* wdst = (l == NLAY - 1) ? (outp + NGR) : nullptr;
    k_bnapply<<<(NN * FD / 4 + 255) / 256, 256, 0, stream>>>(z, stat_all + (size_t)l * 160,
        bn_g + (size_t)l * FD, bn_b + (size_t)l * FD, wdst, hbf, batch, gpool);
  }

  k_mlp2<<<NGR, 128, 0, stream>>>(gpool, w1, b1, w2, b2, w3, b3, outp);
}

// Round 22
// 483.901 us; speedup vs baseline: 1.2192x; 1.0109x over previous
//
#include <hip/hip_runtime.h>
#include <math.h>

#define NN 10000
#define NE 100000
#define NGR 64
#define NT 5
#define FD 75
#define FOUT 15
#define NLAY 4
#define MAXB 1792

typedef __bf16 bf16;
typedef __bf16 bf16x8 __attribute__((ext_vector_type(8)));
typedef float f32x4 __attribute__((ext_vector_type(4)));

__device__ inline unsigned pk2(float a, float b) {
  bf16 x = (bf16)a, y = (bf16)b;
  unsigned short ux, uy;
  __builtin_memcpy(&ux, &x, 2); __builtin_memcpy(&uy, &y, 2);
  return (unsigned)ux | ((unsigned)uy << 16);
}

// ---------------------------------------------------------------- small prep

__global__ __launch_bounds__(256) void k_node_emb(const float* __restrict__ x,
    const float* __restrict__ w, const float* __restrict__ b, bf16* __restrict__ hbf) {
  int idx = blockIdx.x * 256 + threadIdx.x;
  if (idx >= NN * 80) return;
  int n = idx / 80, f = idx - n * 80;
  float acc = 0.f;
  if (f < 75) {
    acc = b[f];
#pragma unroll
    for (int k = 0; k < 14; ++k) acc += x[n * 14 + k] * w[k * FD + f];
  }
  hbf[idx] = (bf16)acc;
}

__global__ __launch_bounds__(256) void k_edge4(const float* __restrict__ eattr,
    bf16* __restrict__ eabf4) {
  int idx = blockIdx.x * 256 + threadIdx.x;
  if (idx >= NE * 8) return;
  int e = idx >> 3, c = idx & 7;
  eabf4[idx] = (c < 4) ? (bf16)eattr[e * 4 + c] : (bf16)0.f;
}

__global__ __launch_bounds__(256) void k_count(const int* __restrict__ dst, int* __restrict__ deg) {
  int e = blockIdx.x * 256 + threadIdx.x;
  if (e < NE) atomicAdd(&deg[dst[e]], 1);
}

__global__ __launch_bounds__(1024) void k_scan(const int* __restrict__ deg, int* __restrict__ rowptr) {
  __shared__ int buf[1024];
  __shared__ int carry;
  int tid = threadIdx.x;
  if (tid == 0) carry = 0;
  __syncthreads();
  for (int base = 0; base < NN; base += 1024) {
    int i = base + tid;
    int v = (i < NN) ? deg[i] : 0;
    buf[tid] = v;
    __syncthreads();
    for (int off = 1; off < 1024; off <<= 1) {
      int t = (tid >= off) ? buf[tid - off] : 0;
      __syncthreads();
      buf[tid] += t;
      __syncthreads();
    }
    int inc = buf[tid];
    int tot = buf[1023];
    if (i < NN) rowptr[i + 1] = carry + inc;
    __syncthreads();
    if (tid == 0) carry += tot;
    __syncthreads();
  }
  if (tid == 0) rowptr[0] = 0;
}

__global__ __launch_bounds__(256) void k_scatter(const int* __restrict__ dst, const int* __restrict__ rowptr,
    int* __restrict__ cursor, int* __restrict__ eids) {
  int e = blockIdx.x * 256 + threadIdx.x;
  if (e >= NE) return;
  int d = dst[e];
  int pos = rowptr[d] + atomicAdd(&cursor[d], 1);
  eids[pos] = e;
}

__global__ __launch_bounds__(256) void k_next(const int* __restrict__ rowptr, int* __restrict__ nxt,
    float* __restrict__ scl, float* __restrict__ iscl, float inv_avg_log) {
  int n = blockIdx.x * 256 + threadIdx.x;
  if (n >= NN) return;
  int base = rowptr[n];
  int lo = n + 1, hi = min(n + 128, NN);
  while (lo < hi) {
    int mid = (lo + hi + 1) >> 1;
    if (rowptr[mid] - base <= 128) lo = mid; else hi = mid - 1;
  }
  nxt[n] = lo;
  float c1 = fmaxf((float)(rowptr[n + 1] - base), 1.f);
  float s = logf(c1 + 1.f) * inv_avg_log;
  scl[n] = s;
  iscl[n] = 1.f / s;
}

__global__ __launch_bounds__(1024) void k_walk(const int* __restrict__ nxt,
    int* __restrict__ bstart, int* __restrict__ nblk) {
  __shared__ int lnx[NN];
  int tid = threadIdx.x;
  for (int i = tid; i < NN; i += 1024) lnx[i] = nxt[i];
  __syncthreads();
  if (tid == 0) {
    int b = 0, n = 0;
    while (n < NN && b < MAXB) { bstart[b++] = n; n = lnx[n]; }
    bstart[b] = NN;
    nblk[0] = b;
  }
}

// ---------------------------------------------------------------- weight prep (batched across layers)

__global__ __launch_bounds__(256) void k_W12(const float* __restrict__ ew,
    const float* __restrict__ ebias, const float* __restrict__ ee_wA, const float* __restrict__ ee_bA,
    float* __restrict__ W12A, float* __restrict__ bcombA) {
  const int l = blockIdx.y;
  const float* ee_w = ee_wA + (size_t)l * 50 * FD;
  const float* ee_b = ee_bA + (size_t)l * FD;
  int idx = blockIdx.x * 256 + threadIdx.x;
  if (idx >= 375) return;
  if (idx < 300) {
    int d = idx / 75, o = idx - d * 75;
    float v = 0.f;
    for (int j = 0; j < 50; ++j) v += ew[d * 50 + j] * ee_w[j * 75 + o];
    W12A[(size_t)l * 300 + idx] = v;
  } else {
    int o = idx - 300;
    float v = ee_b[o];
    for (int j = 0; j < 50; ++j) v += ebias[j] * ee_w[j * 75 + o];
    bcombA[(size_t)l * 80 + o] = v;
  }
}

__global__ __launch_bounds__(256) void k_combine(const float* __restrict__ pre_wA,
    const float* __restrict__ pre_bA, const float* __restrict__ W12A, const float* __restrict__ bcombA,
    bf16* __restrict__ WctA, float* __restrict__ bcA) {
  const int l = blockIdx.y;
  const float* pre_w = pre_wA + (size_t)l * NT * 225 * FD;
  const float* pre_b = pre_bA + (size_t)l * NT * FD;
  const float* W12   = W12A + (size_t)l * 300;
  const float* bcomb = bcombA + (size_t)l * 80;
  bf16* Wct = WctA + (size_t)l * 384 * 192;
  float* bc = bcA + (size_t)l * 384;
  int idx = blockIdx.x * 256 + threadIdx.x;
  if (idx >= 384 * 192) return;
  int c = idx / 192, s = idx - c * 192;
  int t = c / 75, g = c - t * 75;
  int chunk = s >> 6, within = s & 63, sblk = within >> 3, elem = within & 7;
  int lb = sblk ^ (c & 7);
  int k = chunk * 64 + lb * 8 + elem;
  float v = 0.f;
  if (c < 375) {
    if (k < 75)                    v = pre_w[(t * 225 + k) * 75 + g];
    else if (k >= 80 && k < 155)   v = pre_w[(t * 225 + 75 + (k - 80)) * 75 + g];
    else if (k >= 160 && k < 164) {
      int d = k - 160;
      float a = 0.f;
      for (int f2 = 0; f2 < 75; ++f2) a += W12[d * 75 + f2] * pre_w[(t * 225 + 150 + f2) * 75 + g];
      v = a;
    }
  }
  Wct[c * 192 + s] = (bf16)v;
  if (s == 0) {
    float a = 0.f;
    if (c < 375) {
      a = pre_b[t * 75 + g];
      for (int f2 = 0; f2 < 75; ++f2) a += bcomb[f2] * pre_w[(t * 225 + 150 + f2) * 75 + g];
    }
    bc[c] = a;
  }
}

__global__ __launch_bounds__(256) void k_PL(const float* __restrict__ pwA,
    const float* __restrict__ lwA, float* __restrict__ PLA) {
  const int l = blockIdx.y;
  const float* pw = pwA + (size_t)l * NT * 975 * FOUT;
  const float* lw = lwA + (size_t)l * FD * FD;
  float* PL = PLA + (size_t)l * 5 * 975 * 80;
  int idx = blockIdx.x * 256 + threadIdx.x;
  if (idx >= 5 * 975 * 80) return;
  int t = idx / (975 * 80), rem = idx - t * 975 * 80;
  int row = rem / 80, o = rem - row * 80;
  float v = 0.f;
  if (o < 75) {
#pragma unroll
    for (int j = 0; j < 15; ++j)
      v += pw[((size_t)t * 975 + row) * 15 + j] * lw[(t * 15 + j) * 75 + o];
  }
  PL[idx] = v;
}

__global__ __launch_bounds__(256) void k_combine2b(const float* __restrict__ PLA,
    bf16* __restrict__ Wct2A) {
  const int l = blockIdx.y;
  const float* PL = PLA + (size_t)l * 5 * 975 * 80;
  bf16* Wct2 = Wct2A + (size_t)l * 256 * 1664;
  int idx = blockIdx.x * 256 + threadIdx.x;
  if (idx >= 256 * 1664) return;
  int c = idx / 1664, s = idx - c * 1664;
  int chunk = s >> 6, within = s & 63, sblk = within >> 3, elem = within & 7;
  int lb = sblk ^ (c & 7);
  int k = chunk * 64 + lb * 8 + elem;
  int g2 = c / 80, o = c - g2 * 80;
  float val = 0.f;
  if (c < 240 && o < 75) {
    if (k < 75) {
      if (g2 == 0) {
#pragma unroll
        for (int t = 0; t < 5; ++t) val += PL[(t * 975 + k) * 80 + o];
      }
    } else if (k >= 80 && k < 1616) {
      int q = k - 80;
      int si = q / 384, cc = q - si * 384;
      if (cc < 375) {
        int t = cc / 75, g = cc - t * 75;
        int row = 75 + g2 * 300 + si * 75 + g;
        val = PL[((size_t)t * 975 + row) * 80 + o];
      }
    }
  }
  Wct2[(size_t)c * 1664 + s] = (bf16)val;
}

__global__ __launch_bounds__(128) void k_zbias(const float* __restrict__ pbA,
    const float* __restrict__ lwA, const float* __restrict__ lbA, float* __restrict__ zbA) {
  const int l = blockIdx.y;
  const float* pb = pbA + (size_t)l * NT * FOUT;
  const float* lw = lwA + (size_t)l * FD * FD;
  const float* lb = lbA + (size_t)l * FD;
  float* zb = zbA + (size_t)l * 80;
  int o = threadIdx.x;
  if (o >= 80) return;
  float val = 0.f;
  if (o < 75) {
    val = lb[o];
    for (int t = 0; t < 5; ++t)
      for (int j = 0; j < 15; ++j)
        val += pb[t * 15 + j] * lw[(t * 15 + j) * 75 + o];
  }
  zb[o] = val;
}

// ---------------------------------------------------------------- fused pre-GEMM + aggregation
// A-fragments prefetched one phase ahead into named registers; B double-buffered in LDS.

#define LOADB(ntb_, c_) do {                                                      \
    const bf16* wp_ = Wct + (size_t)((ntb_) + sr) * 192 + (c_) * 64 + slb * 8;    \
    pq0 = *(const uint4*)(wp_ + 0 * 6144);                                        \
    pq1 = *(const uint4*)(wp_ + 1 * 6144);                                        \
    pq2 = *(const uint4*)(wp_ + 2 * 6144);                                        \
    pq3 = *(const uint4*)(wp_ + 3 * 6144); } while (0)

#define STOREB(BS_) do {                                          \
    *(uint4*)((BS_) + (0 * 32 + sr) * 128 + (slb << 4)) = pq0;    \
    *(uint4*)((BS_) + (1 * 32 + sr) * 128 + (slb << 4)) = pq1;    \
    *(uint4*)((BS_) + (2 * 32 + sr) * 128 + (slb << 4)) = pq2;    \
    *(uint4*)((BS_) + (3 * 32 + sr) * 128 + (slb << 4)) = pq3; } while (0)

#define LOADA_SET(F0_, F1_, F2_, F3_, A0_, A1_, A2_, A3_) do {  \
    F0_ = *(const bf16x8*)(A0_);                                 \
    F1_ = *(const bf16x8*)(A1_);                                 \
    F2_ = *(const bf16x8*)(A2_);                                 \
    F3_ = *(const bf16x8*)(A3_); } while (0)

#define DO_KK_USE(BS_, KB_, F0_, F1_, F2_, F3_) do {                     \
    const unsigned char* bp_ = (BS_) + (((KB_) ^ (l15 & 7)) << 4) + wc * 8192 + l15 * 128; \
    bf16x8 bv0 = *(const bf16x8*)(bp_ + 0 * 2048);                       \
    bf16x8 bv1 = *(const bf16x8*)(bp_ + 1 * 2048);                       \
    bf16x8 bv2 = *(const bf16x8*)(bp_ + 2 * 2048);                       \
    bf16x8 bv3 = *(const bf16x8*)(bp_ + 3 * 2048);                       \
    acc[0][0] = __builtin_amdgcn_mfma_f32_16x16x32_bf16(F0_, bv0, acc[0][0], 0, 0, 0); \
    acc[1][0] = __builtin_amdgcn_mfma_f32_16x16x32_bf16(F1_, bv0, acc[1][0], 0, 0, 0); \
    acc[2][0] = __builtin_amdgcn_mfma_f32_16x16x32_bf16(F2_, bv0, acc[2][0], 0, 0, 0); \
    acc[3][0] = __builtin_amdgcn_mfma_f32_16x16x32_bf16(F3_, bv0, acc[3][0], 0, 0, 0); \
    acc[0][1] = __builtin_amdgcn_mfma_f32_16x16x32_bf16(F0_, bv1, acc[0][1], 0, 0, 0); \
    acc[1][1] = __builtin_amdgcn_mfma_f32_16x16x32_bf16(F1_, bv1, acc[1][1], 0, 0, 0); \
    acc[2][1] = __builtin_amdgcn_mfma_f32_16x16x32_bf16(F2_, bv1, acc[2][1], 0, 0, 0); \
    acc[3][1] = __builtin_amdgcn_mfma_f32_16x16x32_bf16(F3_, bv1, acc[3][1], 0, 0, 0); \
    acc[0][2] = __builtin_amdgcn_mfma_f32_16x16x32_bf16(F0_, bv2, acc[0][2], 0, 0, 0); \
    acc[1][2] = __builtin_amdgcn_mfma_f32_16x16x32_bf16(F1_, bv2, acc[1][2], 0, 0, 0); \
    acc[2][2] = __builtin_amdgcn_mfma_f32_16x16x32_bf16(F2_, bv2, acc[2][2], 0, 0, 0); \
    acc[3][2] = __builtin_amdgcn_mfma_f32_16x16x32_bf16(F3_, bv2, acc[3][2], 0, 0, 0); \
    acc[0][3] = __builtin_amdgcn_mfma_f32_16x16x32_bf16(F0_, bv3, acc[0][3], 0, 0, 0); \
    acc[1][3] = __builtin_amdgcn_mfma_f32_16x16x32_bf16(F1_, bv3, acc[1][3], 0, 0, 0); \
    acc[2][3] = __builtin_amdgcn_mfma_f32_16x16x32_bf16(F2_, bv3, acc[2][3], 0, 0, 0); \
    acc[3][3] = __builtin_amdgcn_mfma_f32_16x16x32_bf16(F3_, bv3, acc[3][3], 0, 0, 0); \
  } while (0)

__global__ __launch_bounds__(256) void k_pre_fused(
    const bf16* __restrict__ hbf, const int* __restrict__ eids,
    const int* __restrict__ srcA, const int* __restrict__ dstA,
    const int* __restrict__ rowptr, const int* __restrict__ bstart, const int* __restrict__ nblk,
    const bf16* __restrict__ Wct, const float* __restrict__ bc,
    bf16* __restrict__ aggbf2, unsigned eoff_base) {
  __shared__ __align__(16) unsigned char smem[33792];   // Bs dbuf 32K; m_lds overlays
  unsigned char* Bs0 = smem;
  unsigned char* Bs1 = smem + 16384;
  bf16* m_lds = (bf16*)smem;                             // [128][132] bf16
  __shared__ unsigned dOffL[128], sOffL[128], eOffL[128];
  __shared__ int nodeRows[129];
  __shared__ int nq[5];

  const int b = blockIdx.x;
  if (b >= nblk[0]) return;
  const int ntb = blockIdx.y * 128;
  const int tid = threadIdx.x;
  const int n0b = bstart[b], n1b = bstart[b + 1];
  const int rbase = rowptr[n0b];
  const int nrows = rowptr[n1b] - rbase;     // <= 128
  const int nnod = n1b - n0b;                // <= 128

  if (tid == 0) { nq[0] = 0; nq[1] = 0; nq[2] = 0; nq[3] = 0; nq[4] = nnod; }
  if (tid < 128) {
    int e = (tid < nrows) ? eids[rbase + tid] : 0;
    dOffL[tid] = (unsigned)(dstA[e] * 160);
    sOffL[tid] = (unsigned)(srcA[e] * 160);
    eOffL[tid] = eoff_base + (unsigned)(e * 16);
  }
  if (tid <= nnod) nodeRows[tid] = rowptr[n0b + tid] - rbase;
  __syncthreads();
  if (tid < nnod) {
#pragma unroll
    for (int q = 1; q <= 3; ++q) {
      int target = (nrows * q) >> 2;
      if (nodeRows[tid] < target && nodeRows[tid + 1] >= target) nq[q] = tid + 1;
    }
  }

  const int lane = tid & 63;
  const int wave = tid >> 6;
  const int wr = wave >> 1, wc = wave & 1;
  const int l15 = lane & 15, l4 = lane >> 4;
  const int sr = tid >> 3, slb = tid & 7;

  const unsigned char* hb = (const unsigned char*)hbf;
  const int ar = wr * 64 + l15;
  const unsigned dof0 = dOffL[ar], dof1 = dOffL[ar + 16], dof2 = dOffL[ar + 32], dof3 = dOffL[ar + 48];
  const unsigned sof0 = sOffL[ar], sof1 = sOffL[ar + 16], sof2 = sOffL[ar + 32], sof3 = sOffL[ar + 48];
  const unsigned eof0 = eOffL[ar], eof1 = eOffL[ar + 16], eof2 = eOffL[ar + 32], eof3 = eOffL[ar + 48];

  f32x4 acc[4][4];
  f32x4 zv = {0.f, 0.f, 0.f, 0.f};
#pragma unroll
  for (int i = 0; i < 4; ++i)
#pragma unroll
    for (int j = 0; j < 4; ++j) acc[i][j] = zv;

  uint4 pq0, pq1, pq2, pq3;
  bf16x8 fA0, fA1, fA2, fA3, fB0, fB1, fB2, fB3;

  LOADB(ntb, 0);
  STOREB(Bs0);
  // prefetch phase-0 A while barrier drains
  LOADA_SET(fA0, fA1, fA2, fA3,
      hb + dof0 + l4 * 16, hb + dof1 + l4 * 16, hb + dof2 + l4 * 16, hb + dof3 + l4 * 16);
  __syncthreads();
  LOADB(ntb, 1);
  // prefetch phase-1 A; then run phase-0 MFMAs (hides the loads)
  LOADA_SET(fB0, fB1, fB2, fB3,
      hb + dof0 + 64 + l4 * 16, hb + dof1 + 64 + l4 * 16, hb + dof2 + 64 + l4 * 16, hb + dof3 + 64 + l4 * 16);
  DO_KK_USE(Bs0, l4, fA0, fA1, fA2, fA3);
  // prefetch phase-2 A (mixed dst-tail/src)
  {
    unsigned o0 = (l4 < 2) ? (dof0 + 128 + l4 * 16) : (sof0 + (l4 - 2) * 16);
    unsigned o1 = (l4 < 2) ? (dof1 + 128 + l4 * 16) : (sof1 + (l4 - 2) * 16);
    unsigned o2 = (l4 < 2) ? (dof2 + 128 + l4 * 16) : (sof2 + (l4 - 2) * 16);
    unsigned o3 = (l4 < 2) ? (dof3 + 128 + l4 * 16) : (sof3 + (l4 - 2) * 16);
    LOADA_SET(fA0, fA1, fA2, fA3, hb + o0, hb + o1, hb + o2, hb + o3);
  }
  DO_KK_USE(Bs0, 4 + l4, fB0, fB1, fB2, fB3);

  STOREB(Bs1);
  __syncthreads();
  LOADB(ntb, 2);
  // prefetch phase-3 A; run phase-2
  LOADA_SET(fB0, fB1, fB2, fB3,
      hb + sof0 + 32 + l4 * 16, hb + sof1 + 32 + l4 * 16, hb + sof2 + 32 + l4 * 16, hb + sof3 + 32 + l4 * 16);
  DO_KK_USE(Bs1, l4, fA0, fA1, fA2, fA3);
  // prefetch phase-4 A; run phase-3
  LOADA_SET(fA0, fA1, fA2, fA3,
      hb + sof0 + 96 + l4 * 16, hb + sof1 + 96 + l4 * 16, hb + sof2 + 96 + l4 * 16, hb + sof3 + 96 + l4 * 16);
  DO_KK_USE(Bs1, 4 + l4, fB0, fB1, fB2, fB3);

  STOREB(Bs0);
  __syncthreads();
  // prefetch phase-5 A (eattr); run phase-4
  LOADA_SET(fB0, fB1, fB2, fB3,
      hb + eof0 + l4 * 16, hb + eof1 + l4 * 16, hb + eof2 + l4 * 16, hb + eof3 + l4 * 16);
  DO_KK_USE(Bs0, l4, fA0, fA1, fA2, fA3);
  DO_KK_USE(Bs0, 4 + l4, fB0, fB1, fB2, fB3);
  __syncthreads();

  // bias + write tile into the overlay
  float bcv[4];
#pragma unroll
  for (int j = 0; j < 4; ++j) bcv[j] = bc[ntb + wc * 64 + j * 16 + l15];
#pragma unroll
  for (int i = 0; i < 4; ++i) {
    int R = wr * 64 + i * 16 + l4 * 4;
#pragma unroll
    for (int j = 0; j < 4; ++j) {
      int col = wc * 64 + j * 16 + l15;
#pragma unroll
      for (int q = 0; q < 4; ++q)
        m_lds[(R + q) * 132 + col] = (bf16)(acc[i][j][q] + bcv[j]);
    }
  }
  __syncthreads();

  // aggregate: thread = (col-pair 0..63, row-quartile 0..3); u32 reads = 2 bf16 cols
  {
    const int cp = tid & 63;
    const int qq = tid >> 6;
    const unsigned char* mb = (const unsigned char*)m_lds;
    for (int i = nq[qq]; i < nq[qq + 1]; ++i) {
      int ra = nodeRows[i], rb2 = nodeRows[i + 1];
      float s0 = 0.f, q0 = 0.f, a0 = INFINITY, b0 = -INFINITY;
      float s1 = 0.f, q1 = 0.f, a1 = INFINITY, b1 = -INFINITY;
      for (int r = ra; r < rb2; ++r) {
        unsigned u = *(const unsigned*)(mb + r * 264 + cp * 4);
        float v0 = __uint_as_float(u << 16);
        float v1 = __uint_as_float(u & 0xffff0000u);
        s0 += v0; q0 += v0 * v0; a0 = fminf(a0, v0); b0 = fmaxf(b0, v0);
        s1 += v1; q1 += v1 * v1; a1 = fminf(a1, v1); b1 = fmaxf(b1, v1);
      }
      int d = rb2 - ra;
      float inv = 1.f / ((d > 0) ? (float)d : 1.f);
      float m0 = s0 * inv, m1 = s1 * inv;
      float sd0 = sqrtf(fmaxf(q0 * inv - m0 * m0, 0.f) + 1e-5f);
      float sd1 = sqrtf(fmaxf(q1 * inv - m1 * m1, 0.f) + 1e-5f);
      if (d == 0) { a0 = 0.f; b0 = 0.f; a1 = 0.f; b1 = 0.f; }
      bf16* ag = aggbf2 + (size_t)(n0b + i) * 1536 + ntb + cp * 2;
      *(unsigned*)(ag)        = pk2(m0, m1);
      *(unsigned*)(ag + 384)  = pk2(a0, a1);
      *(unsigned*)(ag + 768)  = pk2(b0, b1);
      *(unsigned*)(ag + 1152) = pk2(sd0, sd1);
    }
  }
}

// ---------------------------------------------------------------- post GEMM + epilogue + BN stats
// staged A (one-chunk-ahead reg prefetch), 32-row tiles, grid (313,2).

#define APG_(g_) ((nA >= NN || (g_) >= 202) ? zerobuf : \
    ((g_) < 10 ? hbf + nA * 80 + (g_) * 8 : aggbf2 + (size_t)nA * 1536 + ((g_) - 10) * 8))

#define LOADP4(c_) do {                                                 \
    int gA_ = (c_) * 16 + slb;                                          \
    pa0 = *(const uint4*)APG_(gA_);                                     \
    pa1 = *(const uint4*)APG_(gA_ + 8);                                 \
    int ko_ = (c_) * 128 + slb * 8;                                     \
    pb0 = *(const uint4*)(pc0 + ko_);                                   \
    pb1 = *(const uint4*)(pc0 + ko_ + 64);                              \
    pb2 = *(const uint4*)(pc1 + ko_);                                   \
    pb3 = *(const uint4*)(pc1 + ko_ + 64);                              \
    pb4 = *(const uint4*)(pc2 + ko_);                                   \
    pb5 = *(const uint4*)(pc2 + ko_ + 64);                              \
    pb6 = *(const uint4*)(pc3 + ko_);                                   \
    pb7 = *(const uint4*)(pc3 + ko_ + 64);                              \
  } while (0)

__global__ __launch_bounds__(256) void k_post4(const bf16* __restrict__ hbf,
    const bf16* __restrict__ aggbf2, const bf16* __restrict__ Wct2,
    const float* __restrict__ zb, const float* __restrict__ scl, const float* __restrict__ iscl,
    const bf16* __restrict__ zerobuf, float* __restrict__ z, float* __restrict__ stat_raw_l) {
  __shared__ __align__(16) unsigned char smem[40960];   // As 8K + Bs 32K; Ps overlays
  unsigned char* As = smem;
  unsigned char* Bs = smem + 8192;
  float* Ps = (float*)smem;                             // [32][132] f32
  __shared__ float sclS[32], isclS[32];
  const int n0 = blockIdx.x * 32;
  const int y  = blockIdx.y;
  const int tid = threadIdx.x;
  const int lane = tid & 63, wave = tid >> 6;
  const int l15 = lane & 15, l4 = lane >> 4;
  const int sr = tid >> 3, slb = tid & 7;
  const int nA = n0 + sr;

  const bf16 *pc0, *pc1, *pc2, *pc3;
  {
    int c0 = sr, c1 = sr + 32, c2 = sr + 64, c3 = sr + 96;
    int l0 = (c0 / 40) * 80 + y * 40 + (c0 % 40);
    int l1 = (c1 / 40) * 80 + y * 40 + (c1 % 40);
    int l2 = (c2 / 40) * 80 + y * 40 + (c2 % 40);
    int l3 = (c3 < 120) ? ((c3 / 40) * 80 + y * 40 + (c3 % 40)) : 0;
    pc0 = Wct2 + (size_t)l0 * 1664;
    pc1 = Wct2 + (size_t)l1 * 1664;
    pc2 = Wct2 + (size_t)l2 * 1664;
    pc3 = Wct2 + (size_t)l3 * 1664;
  }
  if (tid < 32) {
    int n = n0 + tid;
    sclS[tid] = (n < NN) ? scl[n] : 0.f;
    isclS[tid] = (n < NN) ? iscl[n] : 0.f;
  }

  f32x4 acc[2][2];
  f32x4 zvv = {0.f, 0.f, 0.f, 0.f};
#pragma unroll
  for (int i = 0; i < 2; ++i)
#pragma unroll
    for (int j = 0; j < 2; ++j) acc[i][j] = zvv;

  uint4 pa0, pa1, pb0, pb1, pb2, pb3, pb4, pb5, pb6, pb7;
  LOADP4(0);
  for (int c = 0; c < 13; ++c) {
    {
      int s1_ = (slb ^ (sr & 7)) << 4;
      *(uint4*)(As + sr * 256 + s1_) = pa0;
      *(uint4*)(As + sr * 256 + s1_ + 128) = pa1;
      *(uint4*)(Bs + (sr)      * 256 + (slb << 4)) = pb0;
      *(uint4*)(Bs + (sr)      * 256 + (slb << 4) + 128) = pb1;
      *(uint4*)(Bs + (sr + 32) * 256 + (slb << 4)) = pb2;
      *(uint4*)(Bs + (sr + 32) * 256 + (slb << 4) + 128) = pb3;
      *(uint4*)(Bs + (sr + 64) * 256 + (slb << 4)) = pb4;
      *(uint4*)(Bs + (sr + 64) * 256 + (slb << 4) + 128) = pb5;
      *(uint4*)(Bs + (sr + 96) * 256 + (slb << 4)) = pb6;
      *(uint4*)(Bs + (sr + 96) * 256 + (slb << 4) + 128) = pb7;
    }
    __syncthreads();
    if (c < 12) LOADP4(c + 1);
#pragma unroll
    for (int kk = 0; kk < 4; ++kk) {
      int kb = kk * 4 + l4;
      bf16x8 af[2], bv[2];
#pragma unroll
      for (int i = 0; i < 2; ++i) {
        int row = i * 16 + l15;
        af[i] = *(const bf16x8*)(As + row * 256 + (((kb & 8) | ((kb & 7) ^ (row & 7))) << 4));
      }
#pragma unroll
      for (int j = 0; j < 2; ++j) {
        int cidx = wave * 32 + j * 16 + l15;
        bv[j] = *(const bf16x8*)(Bs + cidx * 256 + (((kb & 8) | ((kb & 7) ^ (cidx & 7))) << 4));
      }
#pragma unroll
      for (int i = 0; i < 2; ++i)
#pragma unroll
        for (int j = 0; j < 2; ++j)
          acc[i][j] = __builtin_amdgcn_mfma_f32_16x16x32_bf16(af[i], bv[j], acc[i][j], 0, 0, 0);
    }
    __syncthreads();
  }

#pragma unroll
  for (int i = 0; i < 2; ++i) {
#pragma unroll
    for (int j = 0; j < 2; ++j) {
      int cidx = wave * 32 + j * 16 + l15;
#pragma unroll
      for (int q = 0; q < 4; ++q)
        Ps[(i * 16 + l4 * 4 + q) * 132 + cidx] = acc[i][j][q];
    }
  }
  __syncthreads();

  float v0_, v1_, v2_, v3_, v4_;
  int r0_, r1_, r2_, r3_, r4_, f0_, f1_, f2_, f3_, f4_;
#define EPI(t_, vv_, rr_, ff_) do {                                           \
    int idx_ = tid + (t_) * 256;                                              \
    rr_ = idx_ / 40; ff_ = idx_ - rr_ * 40;                                   \
    int n_ = n0 + rr_, zc_ = y * 40 + ff_;                                    \
    float v_ = 0.f;                                                           \
    if (n_ < NN && zc_ < 75) {                                                \
      v_ = Ps[rr_ * 132 + ff_] + sclS[rr_] * Ps[rr_ * 132 + 40 + ff_]         \
         + isclS[rr_] * Ps[rr_ * 132 + 80 + ff_] + zb[zc_];                   \
      z[n_ * 75 + zc_] = v_;                                                  \
    }                                                                         \
    vv_ = v_;                                                                 \
  } while (0)
  EPI(0, v0_, r0_, f0_); EPI(1, v1_, r1_, f1_); EPI(2, v2_, r2_, f2_);
  EPI(3, v3_, r3_, f3_); EPI(4, v4_, r4_, f4_);
#undef EPI
  __syncthreads();
  Ps[r0_ * 132 + f0_] = v0_;
  Ps[r1_ * 132 + f1_] = v1_;
  Ps[r2_ * 132 + f2_] = v2_;
  Ps[r3_ * 132 + f3_] = v3_;
  Ps[r4_ * 132 + f4_] = v4_;
  __syncthreads();
  if (tid < 40) {
    int zc = y * 40 + tid;
    if (zc < 75) {
      float s = 0.f, s2 = 0.f;
#pragma unroll
      for (int r = 0; r < 32; ++r) {
        float v = Ps[r * 132 + tid];
        s += v; s2 += v * v;
      }
      atomicAdd(&stat_raw_l[zc], s);
      atomicAdd(&stat_raw_l[75 + zc], s2);
    }
  }
}

// bnapply, 4 elems/thread; last layer fuses pool atomics
__global__ __launch_bounds__(256) void k_bnapply(const float* __restrict__ z,
    const float* __restrict__ stat_raw, const float* __restrict__ g, const float* __restrict__ b,
    float* __restrict__ outF, bf16* __restrict__ hbf,
    const int* __restrict__ batch, float* __restrict__ gpool) {
  int base = (blockIdx.x * 256 + threadIdx.x) * 4;
  if (base >= NN * FD) return;
  f32x4 zr = *(const f32x4*)(z + base);
  float vr[4];
#pragma unroll
  for (int t = 0; t < 4; ++t) {
    int idx = base + t;
    int n = idx / FD, f = idx - n * FD;
    float mu = stat_raw[f] * (1.f / NN);
    float var = stat_raw[75 + f] * (1.f / NN) - mu * mu;
    var = fmaxf(var, 0.f);
    float rs = 1.f / sqrtf(var + 1e-5f);
    float v = (zr[t] - mu) * rs * g[f] + b[f];
    v = fmaxf(v, 0.f);
    vr[t] = v;
    hbf[n * 80 + f] = (bf16)v;
    if (outF) atomicAdd(&gpool[batch[n] * FD + f], v);
  }
  if (outF) *(f32x4*)(outF + base) = *(f32x4*)vr;
}

// parallel MLP head: one block per graph, 128 threads
__global__ __launch_bounds__(128) void k_mlp2(const float* __restrict__ gpool,
    const float* __restrict__ w1, const float* __restrict__ b1,
    const float* __restrict__ w2, const float* __restrict__ b2,
    const float* __restrict__ w3, const float* __restrict__ b3,
    float* __restrict__ out) {
  __shared__ float G[75];
  __shared__ float H1[50];
  __shared__ float H2[25];
  const int gr = blockIdx.x;
  const int tid = threadIdx.x;
  if (tid < 75) G[tid] = gpool[gr * FD + tid];
  __syncthreads();
  if (tid < 50) {
    float a = b1[tid];
    for (int k = 0; k < 75; ++k) a += G[k] * w1[k * 50 + tid];
    H1[tid] = fmaxf(a, 0.f);
  }
  __syncthreads();
  if (tid < 25) {
    float a = b2[tid];
    for (int k = 0; k < 50; ++k) a += H1[k] * w2[k * 25 + tid];
    H2[tid] = fmaxf(a, 0.f);
  }
  __syncthreads();
  if (tid == 0) {
    float a = b3[0];
    for (int k = 0; k < 25; ++k) a += H2[k] * w3[k];
    out[gr] = a;
  }
}

// ---------------------------------------------------------------- host

extern "C" void kernel_launch(void* const* d_in, const int* in_sizes, int n_in,
                              void* d_out, int out_size, void* d_ws, size_t ws_size,
                              hipStream_t stream) {
  (void)in_sizes; (void)n_in; (void)out_size; (void)ws_size;
  const float* x      = (const float*)d_in[0];
  const int*   eidx   = (const int*)  d_in[1];
  const float* eattr  = (const float*)d_in[2];
  const int*   batch  = (const int*)  d_in[3];
  const float* nw     = (const float*)d_in[4];
  const float* nb     = (const float*)d_in[5];
  const float* ew     = (const float*)d_in[6];
  const float* ebias  = (const float*)d_in[7];
  const float* ee_w   = (const float*)d_in[8];
  const float* ee_b   = (const float*)d_in[9];
  const float* pre_w  = (const float*)d_in[10];
  const float* pre_b  = (const float*)d_in[11];
  const float* post_w = (const float*)d_in[12];
  const float* post_b = (const float*)d_in[13];
  const float* lin_w  = (const float*)d_in[14];
  const float* lin_b  = (const float*)d_in[15];
  const float* bn_g   = (const float*)d_in[16];
  const float* bn_b   = (const float*)d_in[17];
  const float* w1 = (const float*)d_in[18];
  const float* b1 = (const float*)d_in[19];
  const float* w2 = (const float*)d_in[20];
  const float* b2 = (const float*)d_in[21];
  const float* w3 = (const float*)d_in[22];
  const float* b3 = (const float*)d_in[23];

  const int* srcA = eidx;
  const int* dstA = eidx + NE;

  char* base = (char*)d_ws;
  size_t off = 0;
  auto alloc = [&](size_t bytes) -> char* {
    char* p = base + off;
    off = (off + bytes + 255) & ~(size_t)255;
    return p;
  };
  bf16*  hbf    = (bf16*) alloc((size_t)NN * 80 * 2);
  bf16*  eabf4  = (bf16*) alloc((size_t)NE * 8 * 2 + 64);
  bf16*  aggbf2 = (bf16*) alloc((size_t)NN * 1536 * 2);
  float* z      = (float*)alloc((size_t)NN * FD * 4 + 16);
  bf16*  WctA   = (bf16*) alloc((size_t)NLAY * 384 * 192 * 2);
  float* bcA    = (float*)alloc((size_t)NLAY * 384 * 4);
  bf16*  Wct2A  = (bf16*) alloc((size_t)NLAY * 256 * 1664 * 2);
  float* zbA    = (float*)alloc((size_t)NLAY * 80 * 4);
  float* PLA    = (float*)alloc((size_t)NLAY * 5 * 975 * 80 * 4);
  float* W12A   = (float*)alloc((size_t)NLAY * 300 * 4);
  float* bcombA = (float*)alloc((size_t)NLAY * 80 * 4);
  float* scl    = (float*)alloc(NN * 4);
  float* iscl   = (float*)alloc(NN * 4);
  int*   deg    = (int*)alloc(NN * 4);
  int*   rowptr = (int*)alloc((NN + 1) * 4);
  int*   cursor = (int*)alloc(NN * 4);
  int*   eids   = (int*)alloc(NE * 4);
  int*   nxt    = (int*)alloc(NN * 4);
  int*   bstart = (int*)alloc((MAXB + 1) * 4);
  int*   nblk   = (int*)alloc(16);
  float* stat_all = (float*)alloc((size_t)NLAY * 160 * 4);
  float* gpool  = (float*)alloc(NGR * FD * 4);
  bf16*  zerobuf = (bf16*)alloc(256);

  const unsigned eoff_base = (unsigned)((char*)eabf4 - (char*)hbf);

  static const int DEG_TAB[71] = {1, 72, 201, 816, 1790, 3756, 6923, 12768, 20286, 31710,
    51623, 82296, 124280, 177576, 251115, 326064, 395760, 456840, 506179, 516200, 507003,
    493746, 489256, 453936, 420025, 411320, 427761, 420700, 420500, 426780, 414284, 407008,
    394053, 360910, 322245, 313704, 282902, 270940, 237783, 209000, 193766, 177870, 162110,
    144848, 121230, 112700, 93483, 88512, 72275, 80700, 68799, 56784, 42665, 30996, 25630,
    12936, 9804, 8584, 5251, 3480, 3111, 2728, 1890, 1472, 1235, 330, 201, 68, 69, 0, 71};
  double num = 0.0, den = 0.0;
  for (int i = 0; i < 71; ++i) { num += log((double)i + 1.0) * DEG_TAB[i]; den += DEG_TAB[i]; }
  float inv_avg_log = (float)(den / num);

  hipMemsetAsync(deg, 0, NN * 4, stream);
  hipMemsetAsync(cursor, 0, NN * 4, stream);
  hipMemsetAsync(gpool, 0, NGR * FD * 4, stream);
  hipMemsetAsync(stat_all, 0, (size_t)NLAY * 160 * 4, stream);
  hipMemsetAsync(zerobuf, 0, 256, stream);

  // graph prep
  k_node_emb<<<(NN * 80 + 255) / 256, 256, 0, stream>>>(x, nw, nb, hbf);
  k_edge4<<<(NE * 8 + 255) / 256, 256, 0, stream>>>(eattr, eabf4);
  k_count<<<(NE + 255) / 256, 256, 0, stream>>>(dstA, deg);
  k_scan<<<1, 1024, 0, stream>>>(deg, rowptr);
  k_scatter<<<(NE + 255) / 256, 256, 0, stream>>>(dstA, rowptr, cursor, eids);
  k_next<<<(NN + 255) / 256, 256, 0, stream>>>(rowptr, nxt, scl, iscl, inv_avg_log);
  k_walk<<<1, 1024, 0, stream>>>(nxt, bstart, nblk);

  // weight prep, all layers batched
  {
    dim3 gw(2, NLAY);
    k_W12<<<gw, 256, 0, stream>>>(ew, ebias, ee_w, ee_b, W12A, bcombA);
    dim3 gc((384 * 192 + 255) / 256, NLAY);
    k_combine<<<gc, 256, 0, stream>>>(pre_w, pre_b, W12A, bcombA, WctA, bcA);
    dim3 gp((5 * 975 * 80 + 255) / 256, NLAY);
    k_PL<<<gp, 256, 0, stream>>>(post_w, lin_w, PLA);
    dim3 g2((256 * 1664 + 255) / 256, NLAY);
    k_combine2b<<<g2, 256, 0, stream>>>(PLA, Wct2A);
    dim3 gz(1, NLAY);
    k_zbias<<<gz, 128, 0, stream>>>(post_b, lin_w, lin_b, zbA);
  }

  float* outp = (float*)d_out;
  for (int l = 0; l < NLAY; ++l) {
    dim3 gpref(MAXB, 3);
    k_pre_fused<<<gpref, 256, 0, stream>>>(hbf, eids, srcA, dstA, rowptr, bstart, nblk,
        WctA + (size_t)l * 384 * 192, bcA + (size_t)l * 384, aggbf2, eoff_base);
    dim3 gpost((NN + 31) / 32, 2);
    k_post4<<<gpost, 256, 0, stream>>>(hbf, aggbf2, Wct2A + (size_t)l * 256 * 1664,
        zbA + (size_t)l * 80, scl, iscl, zerobuf, z, stat_all + (size_t)l * 160);
    float* wdst = (l == NLAY - 1) ? (outp + NGR) : nullptr;
    k_bnapply<<<(NN * FD / 4 + 255) / 256, 256, 0, stream>>>(z, stat_all + (size_t)l * 160,
        bn_g + (size_t)l * FD, bn_b + (size_t)l * FD, wdst, hbf, batch, gpool);
  }

  k_mlp2<<<NGR, 128, 0, stream>>>(gpool, w1, b1, w2, b2, w3, b3, outp);
}